// Round 3
// baseline (6529.824 us; speedup 1.0000x reference)
//
#include <hip/hip_runtime.h>

// ---------------- constants ----------------
constexpr int S = 197;
constexpr int B = 64;
constexpr int E = 768;
constexpr int H = 12;
constexpr int D = 64;
constexpr int M = S * B;                  // 12608 rows, qkv GEMM order m = s*B+b
constexpr size_t SBE = (size_t)M * E;     // floats in one [*,768] buffer (9,682,944)

// ---------------- block reductions (ln) ----------------
__device__ __forceinline__ float bsum(float v, float* sm, int tid) {
#pragma unroll
  for (int off = 32; off > 0; off >>= 1) v += __shfl_down(v, off, 64);
  if ((tid & 63) == 0) sm[tid >> 6] = v;
  __syncthreads();
  float r = sm[0] + sm[1] + sm[2] + sm[3];
  __syncthreads();
  return r;
}

// ---------------- R[s,t] = rel[196+s] . rel[196+t] ----------------
__global__ __launch_bounds__(256) void mha_relR(const float* __restrict__ rel,
                                                float* __restrict__ Rb) {
  int idx = blockIdx.x * 256 + threadIdx.x;
  if (idx >= S * S) return;
  int s = idx / S, t = idx - s * S;
  const float* a = rel + (size_t)(S - 1 + s) * D;
  const float* b = rel + (size_t)(S - 1 + t) * D;
  float acc = 0.f;
#pragma unroll 8
  for (int d = 0; d < D; ++d) acc = fmaf(a[d], b[d], acc);
  Rb[idx] = acc;
}

// ---------------- QKV grouped GEMM, pass A: y[m][p] natural (coalesced) --------
__global__ __launch_bounds__(256) void mha_qkv_gemm(const float* __restrict__ x,
                                                    const float* __restrict__ w,
                                                    const float* __restrict__ bias,
                                                    float* __restrict__ y,
                                                    int mbase, int rows) {
  __shared__ float Xt[96][68];   // [k][m], float4-aligned a-loads
  __shared__ float Ws[96][98];   // [k][n], float2-aligned b-loads
  const int m0 = mbase + blockIdx.x * 64;
  const int n0 = blockIdx.y * 96;
  const int g = n0 / 288;
  const int tid = threadIdx.x;
  for (int idx = tid; idx < 64 * 96; idx += 256) {
    int mm = idx / 96, k = idx - mm * 96;
    Xt[k][mm] = x[(size_t)(m0 + mm) * E + g * 96 + k];
  }
  for (int idx = tid; idx < 96 * 96; idx += 256) {
    int n = idx / 96, k = idx - n * 96;
    Ws[k][n] = w[(size_t)(n0 + n) * 96 + k];
  }
  __syncthreads();
  const int tx = tid & 15, ty = tid >> 4;
  float acc[4][6] = {};
  for (int k = 0; k < 96; ++k) {
    float4 a = *reinterpret_cast<const float4*>(&Xt[k][ty * 4]);
    float2 w0 = *reinterpret_cast<const float2*>(&Ws[k][tx * 6]);
    float2 w1 = *reinterpret_cast<const float2*>(&Ws[k][tx * 6 + 2]);
    float2 w2 = *reinterpret_cast<const float2*>(&Ws[k][tx * 6 + 4]);
    float av[4] = {a.x, a.y, a.z, a.w};
    float bv[6] = {w0.x, w0.y, w1.x, w1.y, w2.x, w2.y};
#pragma unroll
    for (int r = 0; r < 4; ++r)
#pragma unroll
      for (int c = 0; c < 6; ++c) acc[r][c] = fmaf(av[r], bv[c], acc[r][c]);
  }
  const int mloc = m0 - mbase + ty * 4;
#pragma unroll
  for (int r = 0; r < 4; ++r) {
#pragma unroll
    for (int c = 0; c < 6; ++c) {
      int p = n0 + tx * 6 + c;
      y[(size_t)(mloc + r) * 2304 + p] = acc[r][c] + bias[p];
    }
  }
}

// ---------------- QKV pass B: shuffle + head scatter + rel fold ----------------
__global__ __launch_bounds__(256) void mha_qkv_shuffle(const float* __restrict__ y,
                                                       const float* __restrict__ rel,
                                                       float* __restrict__ qhat,
                                                       float* __restrict__ khat,
                                                       float* __restrict__ vbuf,
                                                       int mbase, int rows) {
  const int wh = blockIdx.y;
  const int which = wh / H, h = wh - which * H;
  const int basep = which * 96 + h * 8;
  const int tid = threadIdx.x;
  const int lane = tid & 63;
  const int g = lane >> 3, j = lane & 7;
  const int d = j * 8 + g;
  const int rbase = blockIdx.x * 32;
  float* dst = (which == 0) ? qhat : (which == 1) ? khat : vbuf;
#pragma unroll
  for (int r8 = 0; r8 < 8; ++r8) {
    int rowl = rbase + r8 * 4 + (tid >> 6);
    if (rowl >= rows) continue;
    int m = mbase + rowl;
    int s = m >> 6, b = m & 63;
    float val = y[(size_t)rowl * 2304 + g * 288 + basep + j];
    size_t o = (((size_t)b * H + h) * S + s) * D + d;
    if (which == 0)
      dst[o] = 0.125f * val + rel[(size_t)(S - 1 + s) * D + d];
    else if (which == 1)
      dst[o] = val + rel[(size_t)(S - 1 + s) * D + d];
    else
      dst[o] = val;
  }
}

// ---------------- fused attention, 12 heads per block, no atomics --------------
// block: (b, s-tile of 32). Loops h=0..11; avg accumulated in registers.
__global__ __launch_bounds__(256, 2) void mha_fattn(const float* __restrict__ qhat,
                                                    const float* __restrict__ khat,
                                                    const float* __restrict__ vbuf,
                                                    const float* __restrict__ Rb,
                                                    float* __restrict__ context,
                                                    float* __restrict__ avg) {
  __shared__ float Ls[32 * 260];   // logits/probs, stride 260 (16B-aligned rows)
  __shared__ float QsT[64 * 34];   // Q^T [d][s]
  __shared__ float KV[64 * 68];    // K^T [d][t] then V [t][d]
  const int b_ = blockIdx.x;
  const int s0 = blockIdx.y * 32;
  const int tid = threadIdx.x;
  const int tx = tid & 15, ty = tid >> 4;
  const int row = tid >> 3, l8 = tid & 7;  // softmax mapping: 8 lanes per row

  float avgacc[25];
#pragma unroll
  for (int k = 0; k < 25; ++k) avgacc[k] = 0.f;

  for (int h = 0; h < H; ++h) {
    const size_t bh = (size_t)b_ * H + h;

    // stage Q^T [d][s]
    for (int idx = tid; idx < 64 * 32; idx += 256) {
      int dd = idx & 63, ss = idx >> 6;
      int sg = s0 + ss;
      QsT[dd * 34 + ss] = (sg < S) ? qhat[(bh * S + sg) * D + dd] : 0.f;
    }

    // ---- QK^T phase ----
    for (int tc = 0; tc < 4; ++tc) {
      const int t0 = tc * 64;
      __syncthreads();
      for (int idx = tid; idx < 64 * 64; idx += 256) {
        int dd = idx & 63, tt = idx >> 6;
        int tg = t0 + tt;
        KV[dd * 68 + tt] = (tg < S) ? khat[(bh * S + tg) * D + dd] : 0.f;
      }
      __syncthreads();
      float acc[2][4] = {};
      for (int dd = 0; dd < 64; ++dd) {
        float2 a = *reinterpret_cast<const float2*>(&QsT[dd * 34 + ty * 2]);
        float4 bb4 = *reinterpret_cast<const float4*>(&KV[dd * 68 + tx * 4]);
        float av[2] = {a.x, a.y};
        float bv[4] = {bb4.x, bb4.y, bb4.z, bb4.w};
#pragma unroll
        for (int r = 0; r < 2; ++r)
#pragma unroll
          for (int c = 0; c < 4; ++c) acc[r][c] = fmaf(av[r], bv[c], acc[r][c]);
      }
#pragma unroll
      for (int r = 0; r < 2; ++r) {
        int sl = ty * 2 + r, sg = s0 + sl;
#pragma unroll
        for (int c = 0; c < 4; ++c) {
          int tl = tx * 4 + c, tg = t0 + tl;
          float rv = (sg < S && tg < S) ? Rb[sg * S + tg] : 0.f;
          Ls[sl * 260 + t0 + tl] = acc[r][c] - rv;
        }
      }
    }
    __syncthreads();

    // ---- softmax (8 lanes per row) + avg register accumulation ----
    {
      float mx = -3.0e38f;
#pragma unroll
      for (int k = 0; k < 25; ++k) {
        int t = l8 + 8 * k;
        if (t < S) mx = fmaxf(mx, Ls[row * 260 + t]);
      }
#pragma unroll
      for (int off = 1; off < 8; off <<= 1) mx = fmaxf(mx, __shfl_xor(mx, off, 64));
      float sum = 0.f;
#pragma unroll
      for (int k = 0; k < 25; ++k) {
        int t = l8 + 8 * k;
        if (t < S) sum += __expf(Ls[row * 260 + t] - mx);
      }
#pragma unroll
      for (int off = 1; off < 8; off <<= 1) sum += __shfl_xor(sum, off, 64);
      float inv = 1.f / sum;
#pragma unroll
      for (int k = 0; k < 32; ++k) {
        int t = l8 + 8 * k;
        if (t < S) {
          float p = __expf(Ls[row * 260 + t] - mx) * inv;
          Ls[row * 260 + t] = p;
          avgacc[k] += p;
        } else if (t < 256) {
          Ls[row * 260 + t] = 0.f;
        }
      }
    }

    // ---- PV phase ----
    float acc2[2][4] = {};
    for (int tc = 0; tc < 4; ++tc) {
      const int t0 = tc * 64;
      __syncthreads();
      for (int idx = tid; idx < 64 * 64; idx += 256) {
        int dd = idx & 63, tt = idx >> 6;
        int tg = t0 + tt;
        KV[tt * 68 + dd] = (tg < S) ? vbuf[(bh * S + tg) * D + dd] : 0.f;
      }
      __syncthreads();
      for (int k4 = 0; k4 < 64; k4 += 4) {
        float4 a0 = *reinterpret_cast<const float4*>(&Ls[(ty * 2 + 0) * 260 + t0 + k4]);
        float4 a1 = *reinterpret_cast<const float4*>(&Ls[(ty * 2 + 1) * 260 + t0 + k4]);
        float a0v[4] = {a0.x, a0.y, a0.z, a0.w};
        float a1v[4] = {a1.x, a1.y, a1.z, a1.w};
#pragma unroll
        for (int kk = 0; kk < 4; ++kk) {
          float4 bb = *reinterpret_cast<const float4*>(&KV[(k4 + kk) * 68 + tx * 4]);
          float bv[4] = {bb.x, bb.y, bb.z, bb.w};
#pragma unroll
          for (int c = 0; c < 4; ++c) {
            acc2[0][c] = fmaf(a0v[kk], bv[c], acc2[0][c]);
            acc2[1][c] = fmaf(a1v[kk], bv[c], acc2[1][c]);
          }
        }
      }
    }
#pragma unroll
    for (int r = 0; r < 2; ++r) {
      int sg = s0 + ty * 2 + r;
      if (sg >= S) continue;
#pragma unroll
      for (int c = 0; c < 4; ++c) {
        int dd = tx * 4 + c;
        context[((size_t)b_ * S + sg) * E + h * D + dd] = acc2[r][c];
      }
    }
  }

  // ---- write avg (non-atomic, each thread owns its (row, l8+8k) slots) ----
  {
    int sg = s0 + row;
    if (sg < S) {
#pragma unroll
      for (int k = 0; k < 25; ++k) {
        int t = l8 + 8 * k;
        if (t < S) avg[((size_t)b_ * S + sg) * S + t] = avgacc[k] * (1.f / H);
      }
    }
  }
}

// ---------------- LayerNorm over E -------------------------------------------
__global__ __launch_bounds__(256) void mha_ln(const float* __restrict__ x,
                                              const float* __restrict__ g,
                                              const float* __restrict__ bb,
                                              float* __restrict__ y) {
  __shared__ float sm[4];
  const size_t r = blockIdx.x;
  const float* xr = x + r * E;
  const int tid = threadIdx.x;
  float s1 = 0.f, s2 = 0.f;
  for (int i = tid; i < E; i += 256) {
    float v = xr[i];
    s1 += v;
    s2 += v * v;
  }
  s1 = bsum(s1, sm, tid);
  s2 = bsum(s2, sm, tid);
  float mu = s1 * (1.f / E);
  float var = s2 * (1.f / E) - mu * mu;
  float inv = rsqrtf(var + 1e-5f);
  float* yr = y + r * E;
  for (int i = tid; i < E; i += 256) yr[i] = (xr[i] - mu) * inv * g[i] + bb[i];
}

// ---------------- fc1 (768->96) + tanh-gelu ------------------------------------
__global__ __launch_bounds__(256) void mha_fc1(const float* __restrict__ ln,
                                               const float* __restrict__ w,
                                               const float* __restrict__ bias,
                                               float* __restrict__ h1) {
  __shared__ float Ls2[64][33];
  __shared__ float Ws[32][97];
  const int m0 = blockIdx.x * 64;
  const int tid = threadIdx.x;
  const int tx = tid & 15, ty = tid >> 4;
  float acc[4][6] = {};
  for (int k0 = 0; k0 < E; k0 += 32) {
    for (int idx = tid; idx < 64 * 32; idx += 256) {
      int m = idx >> 5, k = idx & 31;
      Ls2[m][k] = ln[(size_t)(m0 + m) * E + k0 + k];
    }
    for (int idx = tid; idx < 32 * 96; idx += 256) {
      int k = idx / 96, n = idx - k * 96;
      Ws[k][n] = w[(size_t)(k0 + k) * 96 + n];
    }
    __syncthreads();
    for (int k = 0; k < 32; ++k) {
      float a[4], bb[6];
#pragma unroll
      for (int r = 0; r < 4; ++r) a[r] = Ls2[ty * 4 + r][k];
#pragma unroll
      for (int c = 0; c < 6; ++c) bb[c] = Ws[k][tx * 6 + c];
#pragma unroll
      for (int r = 0; r < 4; ++r)
#pragma unroll
        for (int c = 0; c < 6; ++c) acc[r][c] = fmaf(a[r], bb[c], acc[r][c]);
    }
    __syncthreads();
  }
#pragma unroll
  for (int r = 0; r < 4; ++r) {
    int m = m0 + ty * 4 + r;
#pragma unroll
    for (int c = 0; c < 6; ++c) {
      int n = tx * 6 + c;
      float u = acc[r][c] + bias[n];
      float gl = 0.5f * u * (1.f + tanhf(0.7978845608028654f * (u + 0.044715f * u * u * u)));
      h1[(size_t)m * 96 + n] = gl;
    }
  }
}

// ---------------- fc2 (96->768) + sigmoid, scale context -----------------------
__global__ __launch_bounds__(256) void mha_fc2(const float* __restrict__ h1,
                                               const float* __restrict__ w,
                                               const float* __restrict__ bias,
                                               const float* __restrict__ context,
                                               float* __restrict__ attn2) {
  __shared__ float Hs[64][97];
  __shared__ float Ws[96][65];
  const int m0 = blockIdx.x * 64;
  const int n0 = blockIdx.y * 64;
  const int tid = threadIdx.x;
  for (int idx = tid; idx < 64 * 96; idx += 256) {
    int m = idx / 96, k = idx - m * 96;
    Hs[m][k] = h1[(size_t)(m0 + m) * 96 + k];
  }
  for (int idx = tid; idx < 96 * 64; idx += 256) {
    int k = idx >> 6, n = idx & 63;
    Ws[k][n] = w[(size_t)k * E + n0 + n];
  }
  __syncthreads();
  const int tx = tid & 15, ty = tid >> 4;
  float acc[4][4] = {};
  for (int k = 0; k < 96; ++k) {
    float a[4], bb[4];
#pragma unroll
    for (int r = 0; r < 4; ++r) a[r] = Hs[ty * 4 + r][k];
#pragma unroll
    for (int c = 0; c < 4; ++c) bb[c] = Ws[k][tx * 4 + c];
#pragma unroll
    for (int r = 0; r < 4; ++r)
#pragma unroll
      for (int c = 0; c < 4; ++c) acc[r][c] = fmaf(a[r], bb[c], acc[r][c]);
  }
#pragma unroll
  for (int r = 0; r < 4; ++r) {
    int m = m0 + ty * 4 + r;
#pragma unroll
    for (int c = 0; c < 4; ++c) {
      int e = n0 + tx * 4 + c;
      float val = acc[r][c] + bias[e];
      float sg = 1.f / (1.f + __expf(-val));
      attn2[(size_t)m * E + e] = context[(size_t)m * E + e] * sg;
    }
  }
}

// ---------------- grouped out projection + bias + transpose to [S,B,E] ---------
__global__ __launch_bounds__(256) void mha_out(const float* __restrict__ attn2,
                                               const float* __restrict__ w,
                                               const float* __restrict__ bias,
                                               float* __restrict__ outp) {
  __shared__ float As[64][97];
  __shared__ float Ws[96][97];
  const int m0 = blockIdx.x * 64;
  const int g = blockIdx.y;
  const int n0 = g * 96;
  const int tid = threadIdx.x;
  for (int idx = tid; idx < 64 * 96; idx += 256) {
    int m = idx / 96, j = idx - m * 96;
    As[m][j] = attn2[(size_t)(m0 + m) * E + g * 96 + j];
  }
  for (int idx = tid; idx < 96 * 96; idx += 256) {
    int n = idx / 96, j = idx - n * 96;
    Ws[n][j] = w[(size_t)(n0 + n) * 96 + j];
  }
  __syncthreads();
  const int tx = tid & 15, ty = tid >> 4;
  float acc[4][6] = {};
  for (int j = 0; j < 96; ++j) {
    float a[4], bb[6];
#pragma unroll
    for (int r = 0; r < 4; ++r) a[r] = As[ty * 4 + r][j];
#pragma unroll
    for (int c = 0; c < 6; ++c) bb[c] = Ws[tx * 6 + c][j];
#pragma unroll
    for (int r = 0; r < 4; ++r)
#pragma unroll
      for (int c = 0; c < 6; ++c) acc[r][c] = fmaf(a[r], bb[c], acc[r][c]);
  }
#pragma unroll
  for (int r = 0; r < 4; ++r) {
    int m = m0 + ty * 4 + r;
    int b = m / S, s = m - b * S;  // rows here are r = b*S + s
#pragma unroll
    for (int c = 0; c < 6; ++c) {
      int p = n0 + tx * 6 + c;
      outp[((size_t)s * B + b) * E + p] = acc[r][c] + bias[p];
    }
  }
}

// ---------------- host launcher ------------------------------------------------
extern "C" void kernel_launch(void* const* d_in, const int* in_sizes, int n_in,
                              void* d_out, int out_size, void* d_ws, size_t ws_size,
                              hipStream_t stream) {
  const float* query = (const float*)d_in[0];
  const float* qkv_w = (const float*)d_in[3];
  const float* qkv_b = (const float*)d_in[4];
  const float* out_w = (const float*)d_in[5];
  const float* out_b = (const float*)d_in[6];
  const float* rel   = (const float*)d_in[7];
  const float* ln_g  = (const float*)d_in[8];
  const float* ln_b  = (const float*)d_in[9];
  const float* fc1_w = (const float*)d_in[10];
  const float* fc1_b = (const float*)d_in[11];
  const float* fc2_w = (const float*)d_in[12];
  const float* fc2_b = (const float*)d_in[13];

  float* ws = (float*)d_ws;
  float* qhat    = ws;                 // [B,H,S,D]
  float* khat    = ws + SBE;           // [B,H,S,D]
  float* vbuf    = ws + 2 * SBE;       // [B,H,S,D]
  float* ybuf    = ws + 3 * SBE;       // y chunk (<=3200*2304 fl) / later context
  float* context = ws + 3 * SBE;       // rows b*S+s, [.,768] (aliases ybuf)
  float* Rbuf    = ws + 4 * SBE;       // 197*197
  float* lnbuf = qhat;   // reuse after attention
  float* h1    = khat;   // reuse
  float* attn2 = vbuf;   // reuse
  float* outp  = (float*)d_out;
  float* avgp  = outp + SBE;

  mha_relR<<<(S * S + 255) / 256, 256, 0, stream>>>(rel, Rbuf);

  // qkv two-pass, chunked over m (ybuf aliases context region)
  const int CH = 3200;  // multiple of 64 and 32
  for (int mbase = 0; mbase < M; mbase += CH) {
    int rows = (M - mbase < CH) ? (M - mbase) : CH;
    mha_qkv_gemm<<<dim3(rows / 64, 24), 256, 0, stream>>>(query, qkv_w, qkv_b, ybuf,
                                                          mbase, rows);
    mha_qkv_shuffle<<<dim3(rows / 32, 36), 256, 0, stream>>>(ybuf, rel, qhat, khat,
                                                             vbuf, mbase, rows);
  }

  mha_fattn<<<dim3(B, (S + 31) / 32), 256, 0, stream>>>(qhat, khat, vbuf, Rbuf,
                                                        context, avgp);

  mha_ln<<<M, 256, 0, stream>>>(context, ln_g, ln_b, lnbuf);
  mha_fc1<<<M / 64, 256, 0, stream>>>(lnbuf, fc1_w, fc1_b, h1);
  mha_fc2<<<dim3(M / 64, 12), 256, 0, stream>>>(h1, fc2_w, fc2_b, context, attn2);
  mha_out<<<dim3(M / 64, 8), 256, 0, stream>>>(attn2, out_w, out_b, outp);
}

// Round 4
// 2342.044 us; speedup vs baseline: 2.7881x; 2.7881x over previous
//
#include <hip/hip_runtime.h>

// ---------------- constants ----------------
constexpr int S = 197;
constexpr int B = 64;
constexpr int E = 768;
constexpr int H = 12;
constexpr int D = 64;
constexpr int M = S * B;                  // 12608 rows, qkv GEMM order m = s*B+b
constexpr size_t SBE = (size_t)M * E;     // floats in one [*,768] buffer (9,682,944)

// ---------------- block reductions (ln) ----------------
__device__ __forceinline__ float bsum(float v, float* sm, int tid) {
#pragma unroll
  for (int off = 32; off > 0; off >>= 1) v += __shfl_down(v, off, 64);
  if ((tid & 63) == 0) sm[tid >> 6] = v;
  __syncthreads();
  float r = sm[0] + sm[1] + sm[2] + sm[3];
  __syncthreads();
  return r;
}

// ---------------- R[s,t] = rel[196+s] . rel[196+t] ----------------
__global__ __launch_bounds__(256) void mha_relR(const float* __restrict__ rel,
                                                float* __restrict__ Rb) {
  int idx = blockIdx.x * 256 + threadIdx.x;
  if (idx >= S * S) return;
  int s = idx / S, t = idx - s * S;
  const float* a = rel + (size_t)(S - 1 + s) * D;
  const float* b = rel + (size_t)(S - 1 + t) * D;
  float acc = 0.f;
#pragma unroll 8
  for (int d = 0; d < D; ++d) acc = fmaf(a[d], b[d], acc);
  Rb[idx] = acc;
}

// ---------------- QKV grouped GEMM, pass A: y[m][p] natural (coalesced) --------
__global__ __launch_bounds__(256) void mha_qkv_gemm(const float* __restrict__ x,
                                                    const float* __restrict__ w,
                                                    const float* __restrict__ bias,
                                                    float* __restrict__ y,
                                                    int mbase, int rows) {
  __shared__ float Xt[96][68];   // [k][m], float4-aligned a-loads
  __shared__ float Ws[96][98];   // [k][n], float2-aligned b-loads
  const int m0 = mbase + blockIdx.x * 64;
  const int n0 = blockIdx.y * 96;
  const int g = n0 / 288;
  const int tid = threadIdx.x;
  for (int idx = tid; idx < 64 * 96; idx += 256) {
    int mm = idx / 96, k = idx - mm * 96;
    Xt[k][mm] = x[(size_t)(m0 + mm) * E + g * 96 + k];
  }
  for (int idx = tid; idx < 96 * 96; idx += 256) {
    int n = idx / 96, k = idx - n * 96;
    Ws[k][n] = w[(size_t)(n0 + n) * 96 + k];
  }
  __syncthreads();
  const int tx = tid & 15, ty = tid >> 4;
  float acc[4][6] = {};
  for (int k = 0; k < 96; ++k) {
    float4 a = *reinterpret_cast<const float4*>(&Xt[k][ty * 4]);
    float2 w0 = *reinterpret_cast<const float2*>(&Ws[k][tx * 6]);
    float2 w1 = *reinterpret_cast<const float2*>(&Ws[k][tx * 6 + 2]);
    float2 w2 = *reinterpret_cast<const float2*>(&Ws[k][tx * 6 + 4]);
    float av[4] = {a.x, a.y, a.z, a.w};
    float bv[6] = {w0.x, w0.y, w1.x, w1.y, w2.x, w2.y};
#pragma unroll
    for (int r = 0; r < 4; ++r)
#pragma unroll
      for (int c = 0; c < 6; ++c) acc[r][c] = fmaf(av[r], bv[c], acc[r][c]);
  }
  const int mloc = m0 - mbase + ty * 4;
#pragma unroll
  for (int r = 0; r < 4; ++r) {
#pragma unroll
    for (int c = 0; c < 6; ++c) {
      int p = n0 + tx * 6 + c;
      y[(size_t)(mloc + r) * 2304 + p] = acc[r][c] + bias[p];
    }
  }
}

// ---------------- QKV pass B: shuffle + head scatter + rel fold ----------------
__global__ __launch_bounds__(256) void mha_qkv_shuffle(const float* __restrict__ y,
                                                       const float* __restrict__ rel,
                                                       float* __restrict__ qhat,
                                                       float* __restrict__ khat,
                                                       float* __restrict__ vbuf,
                                                       int mbase, int rows) {
  const int wh = blockIdx.y;
  const int which = wh / H, h = wh - which * H;
  const int basep = which * 96 + h * 8;
  const int tid = threadIdx.x;
  const int lane = tid & 63;
  const int g = lane >> 3, j = lane & 7;
  const int d = j * 8 + g;
  const int rbase = blockIdx.x * 32;
  float* dst = (which == 0) ? qhat : (which == 1) ? khat : vbuf;
#pragma unroll
  for (int r8 = 0; r8 < 8; ++r8) {
    int rowl = rbase + r8 * 4 + (tid >> 6);
    if (rowl >= rows) continue;
    int m = mbase + rowl;
    int s = m >> 6, b = m & 63;
    float val = y[(size_t)rowl * 2304 + g * 288 + basep + j];
    size_t o = (((size_t)b * H + h) * S + s) * D + d;
    if (which == 0)
      dst[o] = 0.125f * val + rel[(size_t)(S - 1 + s) * D + d];
    else if (which == 1)
      dst[o] = val + rel[(size_t)(S - 1 + s) * D + d];
    else
      dst[o] = val;
  }
}

// ---------------- fused attention (R2 shape): one head per block, no atomics ---
// grid (bh, stile). Writes context + (mx,sum) sidecar; avg handled separately.
__global__ __launch_bounds__(256) void mha_fattn(const float* __restrict__ qhat,
                                                 const float* __restrict__ khat,
                                                 const float* __restrict__ vbuf,
                                                 const float* __restrict__ Rb,
                                                 float* __restrict__ context,
                                                 float* __restrict__ mxbuf,
                                                 float* __restrict__ smbuf) {
  __shared__ float Ls[32 * 260];
  __shared__ float QsT[64 * 34];
  __shared__ float KV[64 * 68];
  const int bh = blockIdx.x;
  const int b_ = bh / H, h_ = bh - b_ * H;
  const int s0 = blockIdx.y * 32;
  const int tid = threadIdx.x;
  const int tx = tid & 15, ty = tid >> 4;

  // stage Q^T [d][s]
  for (int idx = tid; idx < 64 * 32; idx += 256) {
    int dd = idx & 63, ss = idx >> 6;
    int sg = s0 + ss;
    QsT[dd * 34 + ss] = (sg < S) ? qhat[((size_t)bh * S + sg) * D + dd] : 0.f;
  }

  // ---- QK^T phase ----
  for (int tc = 0; tc < 4; ++tc) {
    const int t0 = tc * 64;
    __syncthreads();
    for (int idx = tid; idx < 64 * 64; idx += 256) {
      int dd = idx & 63, tt = idx >> 6;
      int tg = t0 + tt;
      KV[dd * 68 + tt] = (tg < S) ? khat[((size_t)bh * S + tg) * D + dd] : 0.f;
    }
    __syncthreads();
    float acc[2][4] = {};
    for (int dd = 0; dd < 64; ++dd) {
      float2 a = *reinterpret_cast<const float2*>(&QsT[dd * 34 + ty * 2]);
      float4 bb4 = *reinterpret_cast<const float4*>(&KV[dd * 68 + tx * 4]);
      float av[2] = {a.x, a.y};
      float bv[4] = {bb4.x, bb4.y, bb4.z, bb4.w};
#pragma unroll
      for (int r = 0; r < 2; ++r)
#pragma unroll
        for (int c = 0; c < 4; ++c) acc[r][c] = fmaf(av[r], bv[c], acc[r][c]);
    }
#pragma unroll
    for (int r = 0; r < 2; ++r) {
      int sl = ty * 2 + r, sg = s0 + sl;
#pragma unroll
      for (int c = 0; c < 4; ++c) {
        int tl = tx * 4 + c, tg = t0 + tl;
        float rv = (sg < S && tg < S) ? Rb[sg * S + tg] : 0.f;
        Ls[sl * 260 + t0 + tl] = acc[r][c] - rv;
      }
    }
  }
  __syncthreads();

  // ---- softmax (8 lanes per row) + sidecar ----
  {
    const int row = tid >> 3, l8 = tid & 7;
    const int sg = s0 + row;
    float mx = -3.0e38f;
#pragma unroll
    for (int k = 0; k < 25; ++k) {
      int t = l8 + 8 * k;
      if (t < S) mx = fmaxf(mx, Ls[row * 260 + t]);
    }
#pragma unroll
    for (int off = 1; off < 8; off <<= 1) mx = fmaxf(mx, __shfl_xor(mx, off, 64));
    float sum = 0.f;
#pragma unroll
    for (int k = 0; k < 25; ++k) {
      int t = l8 + 8 * k;
      if (t < S) sum += __expf(Ls[row * 260 + t] - mx);
    }
#pragma unroll
    for (int off = 1; off < 8; off <<= 1) sum += __shfl_xor(sum, off, 64);
    float inv = 1.f / sum;
    if (l8 == 0 && sg < S) {
      mxbuf[(size_t)bh * S + sg] = mx;
      smbuf[(size_t)bh * S + sg] = sum;
    }
#pragma unroll
    for (int k = 0; k < 32; ++k) {
      int t = l8 + 8 * k;
      if (t < S) {
        Ls[row * 260 + t] = __expf(Ls[row * 260 + t] - mx) * inv;
      } else if (t < 256) {
        Ls[row * 260 + t] = 0.f;
      }
    }
  }

  // ---- PV phase ----
  float acc2[2][4] = {};
  for (int tc = 0; tc < 4; ++tc) {
    const int t0 = tc * 64;
    __syncthreads();
    for (int idx = tid; idx < 64 * 64; idx += 256) {
      int dd = idx & 63, tt = idx >> 6;
      int tg = t0 + tt;
      KV[tt * 68 + dd] = (tg < S) ? vbuf[((size_t)bh * S + tg) * D + dd] : 0.f;
    }
    __syncthreads();
    for (int k4 = 0; k4 < 64; k4 += 4) {
      float4 a0 = *reinterpret_cast<const float4*>(&Ls[(ty * 2 + 0) * 260 + t0 + k4]);
      float4 a1 = *reinterpret_cast<const float4*>(&Ls[(ty * 2 + 1) * 260 + t0 + k4]);
      float a0v[4] = {a0.x, a0.y, a0.z, a0.w};
      float a1v[4] = {a1.x, a1.y, a1.z, a1.w};
#pragma unroll
      for (int kk = 0; kk < 4; ++kk) {
        float4 bb = *reinterpret_cast<const float4*>(&KV[(k4 + kk) * 68 + tx * 4]);
        float bv[4] = {bb.x, bb.y, bb.z, bb.w};
#pragma unroll
        for (int c = 0; c < 4; ++c) {
          acc2[0][c] = fmaf(a0v[kk], bv[c], acc2[0][c]);
          acc2[1][c] = fmaf(a1v[kk], bv[c], acc2[1][c]);
        }
      }
    }
  }
#pragma unroll
  for (int r = 0; r < 2; ++r) {
    int sg = s0 + ty * 2 + r;
    if (sg >= S) continue;
#pragma unroll
    for (int c = 0; c < 4; ++c) {
      int dd = tx * 4 + c;
      context[((size_t)b_ * S + sg) * E + h_ * D + dd] = acc2[r][c];
    }
  }
}

// ---------------- avg recompute: QK per head, probs from sidecar, reg accum ----
// grid (b, stile). LDS only QsT + KT (26 KB). Disjoint per-thread avg ownership.
__global__ __launch_bounds__(256) void mha_avg(const float* __restrict__ qhat,
                                               const float* __restrict__ khat,
                                               const float* __restrict__ Rb,
                                               const float* __restrict__ mxbuf,
                                               const float* __restrict__ smbuf,
                                               float* __restrict__ avg) {
  __shared__ float QsT[64 * 34];
  __shared__ float KT[64 * 68];
  const int b_ = blockIdx.x;
  const int s0 = blockIdx.y * 32;
  const int tid = threadIdx.x;
  const int tx = tid & 15, ty = tid >> 4;
  const int sg0 = s0 + ty * 2, sg1 = sg0 + 1;

  float aacc[2][16];
#pragma unroll
  for (int r = 0; r < 2; ++r)
#pragma unroll
    for (int c = 0; c < 16; ++c) aacc[r][c] = 0.f;

  for (int h = 0; h < H; ++h) {
    const size_t bh = (size_t)b_ * H + h;
    __syncthreads();  // protect QsT/KT from previous iteration's readers
    // per-row softmax params
    float mx0 = 0.f, iv0 = 0.f, mx1 = 0.f, iv1 = 0.f;
    if (sg0 < S) { mx0 = mxbuf[bh * S + sg0]; iv0 = 1.f / smbuf[bh * S + sg0]; }
    if (sg1 < S) { mx1 = mxbuf[bh * S + sg1]; iv1 = 1.f / smbuf[bh * S + sg1]; }
    // stage Q^T
    for (int idx = tid; idx < 64 * 32; idx += 256) {
      int dd = idx & 63, ss = idx >> 6;
      int sg = s0 + ss;
      QsT[dd * 34 + ss] = (sg < S) ? qhat[(bh * S + sg) * D + dd] : 0.f;
    }
    for (int tc = 0; tc < 4; ++tc) {
      const int t0 = tc * 64;
      __syncthreads();
      for (int idx = tid; idx < 64 * 64; idx += 256) {
        int dd = idx & 63, tt = idx >> 6;
        int tg = t0 + tt;
        KT[dd * 68 + tt] = (tg < S) ? khat[(bh * S + tg) * D + dd] : 0.f;
      }
      __syncthreads();
      float acc[2][4] = {};
      for (int dd = 0; dd < 64; ++dd) {
        float2 a = *reinterpret_cast<const float2*>(&QsT[dd * 34 + ty * 2]);
        float4 bb4 = *reinterpret_cast<const float4*>(&KT[dd * 68 + tx * 4]);
        float av[2] = {a.x, a.y};
        float bv[4] = {bb4.x, bb4.y, bb4.z, bb4.w};
#pragma unroll
        for (int r = 0; r < 2; ++r)
#pragma unroll
          for (int c = 0; c < 4; ++c) acc[r][c] = fmaf(av[r], bv[c], acc[r][c]);
      }
#pragma unroll
      for (int c = 0; c < 4; ++c) {
        int tg = t0 + tx * 4 + c;
        if (tg < S) {
          if (sg0 < S)
            aacc[0][tc * 4 + c] += __expf(acc[0][c] - Rb[sg0 * S + tg] - mx0) * iv0;
          if (sg1 < S)
            aacc[1][tc * 4 + c] += __expf(acc[1][c] - Rb[sg1 * S + tg] - mx1) * iv1;
        }
      }
    }
  }

  // write avg (disjoint ownership)
#pragma unroll
  for (int r = 0; r < 2; ++r) {
    int sg = s0 + ty * 2 + r;
    if (sg >= S) continue;
#pragma unroll
    for (int tc = 0; tc < 4; ++tc) {
#pragma unroll
      for (int c = 0; c < 4; ++c) {
        int tg = tc * 64 + tx * 4 + c;
        if (tg < S)
          avg[((size_t)b_ * S + sg) * S + tg] = aacc[r][tc * 4 + c] * (1.f / H);
      }
    }
  }
}

// ---------------- LayerNorm over E -------------------------------------------
__global__ __launch_bounds__(256) void mha_ln(const float* __restrict__ x,
                                              const float* __restrict__ g,
                                              const float* __restrict__ bb,
                                              float* __restrict__ y) {
  __shared__ float sm[4];
  const size_t r = blockIdx.x;
  const float* xr = x + r * E;
  const int tid = threadIdx.x;
  float s1 = 0.f, s2 = 0.f;
  for (int i = tid; i < E; i += 256) {
    float v = xr[i];
    s1 += v;
    s2 += v * v;
  }
  s1 = bsum(s1, sm, tid);
  s2 = bsum(s2, sm, tid);
  float mu = s1 * (1.f / E);
  float var = s2 * (1.f / E) - mu * mu;
  float inv = rsqrtf(var + 1e-5f);
  float* yr = y + r * E;
  for (int i = tid; i < E; i += 256) yr[i] = (xr[i] - mu) * inv * g[i] + bb[i];
}

// ---------------- fc1 (768->96) + tanh-gelu ------------------------------------
__global__ __launch_bounds__(256) void mha_fc1(const float* __restrict__ ln,
                                               const float* __restrict__ w,
                                               const float* __restrict__ bias,
                                               float* __restrict__ h1) {
  __shared__ float Ls2[64][33];
  __shared__ float Ws[32][97];
  const int m0 = blockIdx.x * 64;
  const int tid = threadIdx.x;
  const int tx = tid & 15, ty = tid >> 4;
  float acc[4][6] = {};
  for (int k0 = 0; k0 < E; k0 += 32) {
    for (int idx = tid; idx < 64 * 32; idx += 256) {
      int m = idx >> 5, k = idx & 31;
      Ls2[m][k] = ln[(size_t)(m0 + m) * E + k0 + k];
    }
    for (int idx = tid; idx < 32 * 96; idx += 256) {
      int k = idx / 96, n = idx - k * 96;
      Ws[k][n] = w[(size_t)(k0 + k) * 96 + n];
    }
    __syncthreads();
    for (int k = 0; k < 32; ++k) {
      float a[4], bb[6];
#pragma unroll
      for (int r = 0; r < 4; ++r) a[r] = Ls2[ty * 4 + r][k];
#pragma unroll
      for (int c = 0; c < 6; ++c) bb[c] = Ws[k][tx * 6 + c];
#pragma unroll
      for (int r = 0; r < 4; ++r)
#pragma unroll
        for (int c = 0; c < 6; ++c) acc[r][c] = fmaf(a[r], bb[c], acc[r][c]);
    }
    __syncthreads();
  }
#pragma unroll
  for (int r = 0; r < 4; ++r) {
    int m = m0 + ty * 4 + r;
#pragma unroll
    for (int c = 0; c < 6; ++c) {
      int n = tx * 6 + c;
      float u = acc[r][c] + bias[n];
      float gl = 0.5f * u * (1.f + tanhf(0.7978845608028654f * (u + 0.044715f * u * u * u)));
      h1[(size_t)m * 96 + n] = gl;
    }
  }
}

// ---------------- fc2 (96->768) + sigmoid, scale context -----------------------
__global__ __launch_bounds__(256) void mha_fc2(const float* __restrict__ h1,
                                               const float* __restrict__ w,
                                               const float* __restrict__ bias,
                                               const float* __restrict__ context,
                                               float* __restrict__ attn2) {
  __shared__ float Hs[64][97];
  __shared__ float Ws[96][65];
  const int m0 = blockIdx.x * 64;
  const int n0 = blockIdx.y * 64;
  const int tid = threadIdx.x;
  for (int idx = tid; idx < 64 * 96; idx += 256) {
    int m = idx / 96, k = idx - m * 96;
    Hs[m][k] = h1[(size_t)(m0 + m) * 96 + k];
  }
  for (int idx = tid; idx < 96 * 64; idx += 256) {
    int k = idx >> 6, n = idx & 63;
    Ws[k][n] = w[(size_t)k * E + n0 + n];
  }
  __syncthreads();
  const int tx = tid & 15, ty = tid >> 4;
  float acc[4][4] = {};
  for (int k = 0; k < 96; ++k) {
    float a[4], bb[4];
#pragma unroll
    for (int r = 0; r < 4; ++r) a[r] = Hs[ty * 4 + r][k];
#pragma unroll
    for (int c = 0; c < 4; ++c) bb[c] = Ws[k][tx * 4 + c];
#pragma unroll
    for (int r = 0; r < 4; ++r)
#pragma unroll
      for (int c = 0; c < 4; ++c) acc[r][c] = fmaf(a[r], bb[c], acc[r][c]);
  }
#pragma unroll
  for (int r = 0; r < 4; ++r) {
    int m = m0 + ty * 4 + r;
#pragma unroll
    for (int c = 0; c < 4; ++c) {
      int e = n0 + tx * 4 + c;
      float val = acc[r][c] + bias[e];
      float sg = 1.f / (1.f + __expf(-val));
      attn2[(size_t)m * E + e] = context[(size_t)m * E + e] * sg;
    }
  }
}

// ---------------- grouped out projection + bias + transpose to [S,B,E] ---------
__global__ __launch_bounds__(256) void mha_out(const float* __restrict__ attn2,
                                               const float* __restrict__ w,
                                               const float* __restrict__ bias,
                                               float* __restrict__ outp) {
  __shared__ float As[64][97];
  __shared__ float Ws[96][97];
  const int m0 = blockIdx.x * 64;
  const int g = blockIdx.y;
  const int n0 = g * 96;
  const int tid = threadIdx.x;
  for (int idx = tid; idx < 64 * 96; idx += 256) {
    int m = idx / 96, j = idx - m * 96;
    As[m][j] = attn2[(size_t)(m0 + m) * E + g * 96 + j];
  }
  for (int idx = tid; idx < 96 * 96; idx += 256) {
    int n = idx / 96, j = idx - n * 96;
    Ws[n][j] = w[(size_t)(n0 + n) * 96 + j];
  }
  __syncthreads();
  const int tx = tid & 15, ty = tid >> 4;
  float acc[4][6] = {};
  for (int j = 0; j < 96; ++j) {
    float a[4], bb[6];
#pragma unroll
    for (int r = 0; r < 4; ++r) a[r] = As[ty * 4 + r][j];
#pragma unroll
    for (int c = 0; c < 6; ++c) bb[c] = Ws[tx * 6 + c][j];
#pragma unroll
    for (int r = 0; r < 4; ++r)
#pragma unroll
      for (int c = 0; c < 6; ++c) acc[r][c] = fmaf(a[r], bb[c], acc[r][c]);
  }
#pragma unroll
  for (int r = 0; r < 4; ++r) {
    int m = m0 + ty * 4 + r;
    int b = m / S, s = m - b * S;  // rows here are r = b*S + s
#pragma unroll
    for (int c = 0; c < 6; ++c) {
      int p = n0 + tx * 6 + c;
      outp[((size_t)s * B + b) * E + p] = acc[r][c] + bias[p];
    }
  }
}

// ---------------- host launcher ------------------------------------------------
extern "C" void kernel_launch(void* const* d_in, const int* in_sizes, int n_in,
                              void* d_out, int out_size, void* d_ws, size_t ws_size,
                              hipStream_t stream) {
  const float* query = (const float*)d_in[0];
  const float* qkv_w = (const float*)d_in[3];
  const float* qkv_b = (const float*)d_in[4];
  const float* out_w = (const float*)d_in[5];
  const float* out_b = (const float*)d_in[6];
  const float* rel   = (const float*)d_in[7];
  const float* ln_g  = (const float*)d_in[8];
  const float* ln_b  = (const float*)d_in[9];
  const float* fc1_w = (const float*)d_in[10];
  const float* fc1_b = (const float*)d_in[11];
  const float* fc2_w = (const float*)d_in[12];
  const float* fc2_b = (const float*)d_in[13];

  float* ws = (float*)d_ws;
  float* qhat    = ws;                 // [B,H,S,D]
  float* khat    = ws + SBE;           // [B,H,S,D]
  float* vbuf    = ws + 2 * SBE;       // [B,H,S,D]
  float* ybuf    = ws + 3 * SBE;       // y chunk / later context
  float* context = ws + 3 * SBE;       // rows b*S+s, [.,768] (aliases ybuf)
  float* Rbuf    = ws + 4 * SBE;       // 197*197
  float* mxbuf   = ws + 4 * SBE + 38816;            // B*H*S
  float* smbuf   = ws + 4 * SBE + 38816 + 151296;   // B*H*S
  float* lnbuf = qhat;   // reuse after attention+avg
  float* h1    = khat;   // reuse
  float* attn2 = vbuf;   // reuse
  float* outp  = (float*)d_out;
  float* avgp  = outp + SBE;

  mha_relR<<<(S * S + 255) / 256, 256, 0, stream>>>(rel, Rbuf);

  // qkv two-pass, chunked over m (ybuf aliases context region)
  const int CH = 3200;  // multiple of 64 and 32
  for (int mbase = 0; mbase < M; mbase += CH) {
    int rows = (M - mbase < CH) ? (M - mbase) : CH;
    mha_qkv_gemm<<<dim3(rows / 64, 24), 256, 0, stream>>>(query, qkv_w, qkv_b, ybuf,
                                                          mbase, rows);
    mha_qkv_shuffle<<<dim3(rows / 32, 36), 256, 0, stream>>>(ybuf, rel, qhat, khat,
                                                             vbuf, mbase, rows);
  }

  mha_fattn<<<dim3(B * H, (S + 31) / 32), 256, 0, stream>>>(qhat, khat, vbuf, Rbuf,
                                                            context, mxbuf, smbuf);
  mha_avg<<<dim3(B, (S + 31) / 32), 256, 0, stream>>>(qhat, khat, Rbuf, mxbuf,
                                                      smbuf, avgp);

  mha_ln<<<M, 256, 0, stream>>>(context, ln_g, ln_b, lnbuf);
  mha_fc1<<<M / 64, 256, 0, stream>>>(lnbuf, fc1_w, fc1_b, h1);
  mha_fc2<<<dim3(M / 64, 12), 256, 0, stream>>>(h1, fc2_w, fc2_b, context, attn2);
  mha_out<<<dim3(M / 64, 8), 256, 0, stream>>>(attn2, out_w, out_b, outp);
}

// Round 5
// 1495.142 us; speedup vs baseline: 4.3674x; 1.5664x over previous
//
#include <hip/hip_runtime.h>
#include <hip/hip_bf16.h>

// ---------------- constants ----------------
constexpr int S = 197;
constexpr int B = 64;
constexpr int E = 768;
constexpr int H = 12;
constexpr int D = 64;
constexpr int M = S * B;                  // 12608 rows, qkv GEMM order m = s*B+b
constexpr size_t SBE = (size_t)M * E;     // floats in one [*,768] buffer (9,682,944)

// ---------------- block reductions (ln) ----------------
__device__ __forceinline__ float bsum(float v, float* sm, int tid) {
#pragma unroll
  for (int off = 32; off > 0; off >>= 1) v += __shfl_down(v, off, 64);
  if ((tid & 63) == 0) sm[tid >> 6] = v;
  __syncthreads();
  float r = sm[0] + sm[1] + sm[2] + sm[3];
  __syncthreads();
  return r;
}

// ---------------- R[s,t] = rel[196+s] . rel[196+t] ----------------
__global__ __launch_bounds__(256) void mha_relR(const float* __restrict__ rel,
                                                float* __restrict__ Rb) {
  int idx = blockIdx.x * 256 + threadIdx.x;
  if (idx >= S * S) return;
  int s = idx / S, t = idx - s * S;
  const float* a = rel + (size_t)(S - 1 + s) * D;
  const float* b = rel + (size_t)(S - 1 + t) * D;
  float acc = 0.f;
#pragma unroll 8
  for (int d = 0; d < D; ++d) acc = fmaf(a[d], b[d], acc);
  Rb[idx] = acc;
}

// ---------------- QKV grouped GEMM, pass A: y[m][p] natural (coalesced) --------
__global__ __launch_bounds__(256) void mha_qkv_gemm(const float* __restrict__ x,
                                                    const float* __restrict__ w,
                                                    const float* __restrict__ bias,
                                                    float* __restrict__ y,
                                                    int mbase, int rows) {
  __shared__ float Xt[96][68];   // [k][m], float4-aligned a-loads
  __shared__ float Ws[96][98];   // [k][n], float2-aligned b-loads
  const int m0 = mbase + blockIdx.x * 64;
  const int n0 = blockIdx.y * 96;
  const int g = n0 / 288;
  const int tid = threadIdx.x;
  for (int idx = tid; idx < 64 * 96; idx += 256) {
    int mm = idx / 96, k = idx - mm * 96;
    Xt[k][mm] = x[(size_t)(m0 + mm) * E + g * 96 + k];
  }
  for (int idx = tid; idx < 96 * 96; idx += 256) {
    int n = idx / 96, k = idx - n * 96;
    Ws[k][n] = w[(size_t)(n0 + n) * 96 + k];
  }
  __syncthreads();
  const int tx = tid & 15, ty = tid >> 4;
  float acc[4][6] = {};
  for (int k = 0; k < 96; ++k) {
    float4 a = *reinterpret_cast<const float4*>(&Xt[k][ty * 4]);
    float2 w0 = *reinterpret_cast<const float2*>(&Ws[k][tx * 6]);
    float2 w1 = *reinterpret_cast<const float2*>(&Ws[k][tx * 6 + 2]);
    float2 w2 = *reinterpret_cast<const float2*>(&Ws[k][tx * 6 + 4]);
    float av[4] = {a.x, a.y, a.z, a.w};
    float bv[6] = {w0.x, w0.y, w1.x, w1.y, w2.x, w2.y};
#pragma unroll
    for (int r = 0; r < 4; ++r)
#pragma unroll
      for (int c = 0; c < 6; ++c) acc[r][c] = fmaf(av[r], bv[c], acc[r][c]);
  }
  const int mloc = m0 - mbase + ty * 4;
#pragma unroll
  for (int r = 0; r < 4; ++r) {
#pragma unroll
    for (int c = 0; c < 6; ++c) {
      int p = n0 + tx * 6 + c;
      y[(size_t)(mloc + r) * 2304 + p] = acc[r][c] + bias[p];
    }
  }
}

// ---------------- QKV pass B: shuffle + head scatter + rel fold ----------------
__global__ __launch_bounds__(256) void mha_qkv_shuffle(const float* __restrict__ y,
                                                       const float* __restrict__ rel,
                                                       float* __restrict__ qhat,
                                                       float* __restrict__ khat,
                                                       float* __restrict__ vbuf,
                                                       int mbase, int rows) {
  const int wh = blockIdx.y;
  const int which = wh / H, h = wh - which * H;
  const int basep = which * 96 + h * 8;
  const int tid = threadIdx.x;
  const int lane = tid & 63;
  const int g = lane >> 3, j = lane & 7;
  const int d = j * 8 + g;
  const int rbase = blockIdx.x * 32;
  float* dst = (which == 0) ? qhat : (which == 1) ? khat : vbuf;
#pragma unroll
  for (int r8 = 0; r8 < 8; ++r8) {
    int rowl = rbase + r8 * 4 + (tid >> 6);
    if (rowl >= rows) continue;
    int m = mbase + rowl;
    int s = m >> 6, b = m & 63;
    float val = y[(size_t)rowl * 2304 + g * 288 + basep + j];
    size_t o = (((size_t)b * H + h) * S + s) * D + d;
    if (which == 0)
      dst[o] = 0.125f * val + rel[(size_t)(S - 1 + s) * D + d];
    else if (which == 1)
      dst[o] = val + rel[(size_t)(S - 1 + s) * D + d];
    else
      dst[o] = val;
  }
}

// ---------------- fused attention: one head per block, XCD-swizzled grid -------
// 1-D grid of 7*nbh blocks (nbh multiple of 8). Decode keeps the 7 s-tiles of a
// head consecutive on one XCD so K/V staging hits L2. Writes context + bf16
// probs tile (chunk-local) for the avg reduction.
__global__ __launch_bounds__(256) void mha_fattn(const float* __restrict__ qhat,
                                                 const float* __restrict__ khat,
                                                 const float* __restrict__ vbuf,
                                                 const float* __restrict__ Rb,
                                                 float* __restrict__ context,
                                                 __hip_bfloat16* __restrict__ probs,
                                                 int bh0) {
  __shared__ float Ls[32 * 260];
  __shared__ float QsT[64 * 34];
  __shared__ float KV[64 * 68];
  const int id = blockIdx.x;
  const int xcd = id & 7;
  const int rr_ = id >> 3;
  const int stile = rr_ % 7;
  const int bhl = xcd + 8 * (rr_ / 7);     // chunk-local bh
  const int bh = bh0 + bhl;                // global bh
  const int b_ = bh / H, h_ = bh - b_ * H;
  const int s0 = stile * 32;
  const int tid = threadIdx.x;
  const int tx = tid & 15, ty = tid >> 4;

  // stage Q^T [d][s]
  for (int idx = tid; idx < 64 * 32; idx += 256) {
    int dd = idx & 63, ss = idx >> 6;
    int sg = s0 + ss;
    QsT[dd * 34 + ss] = (sg < S) ? qhat[((size_t)bh * S + sg) * D + dd] : 0.f;
  }

  // ---- QK^T phase ----
  for (int tc = 0; tc < 4; ++tc) {
    const int t0 = tc * 64;
    __syncthreads();
    for (int idx = tid; idx < 64 * 64; idx += 256) {
      int dd = idx & 63, tt = idx >> 6;
      int tg = t0 + tt;
      KV[dd * 68 + tt] = (tg < S) ? khat[((size_t)bh * S + tg) * D + dd] : 0.f;
    }
    __syncthreads();
    float acc[2][4] = {};
    for (int dd = 0; dd < 64; ++dd) {
      float2 a = *reinterpret_cast<const float2*>(&QsT[dd * 34 + ty * 2]);
      float4 bb4 = *reinterpret_cast<const float4*>(&KV[dd * 68 + tx * 4]);
      float av[2] = {a.x, a.y};
      float bv[4] = {bb4.x, bb4.y, bb4.z, bb4.w};
#pragma unroll
      for (int r = 0; r < 2; ++r)
#pragma unroll
        for (int c = 0; c < 4; ++c) acc[r][c] = fmaf(av[r], bv[c], acc[r][c]);
    }
#pragma unroll
    for (int r = 0; r < 2; ++r) {
      int sl = ty * 2 + r, sg = s0 + sl;
#pragma unroll
      for (int c = 0; c < 4; ++c) {
        int tl = tx * 4 + c, tg = t0 + tl;
        float rv = (sg < S && tg < S) ? Rb[sg * S + tg] : 0.f;
        Ls[sl * 260 + t0 + tl] = acc[r][c] - rv;
      }
    }
  }
  __syncthreads();

  // ---- softmax (8 lanes per row), store e then scale ----
  {
    const int row = tid >> 3, l8 = tid & 7;
    float mx = -3.0e38f;
#pragma unroll
    for (int k = 0; k < 25; ++k) {
      int t = l8 + 8 * k;
      if (t < S) mx = fmaxf(mx, Ls[row * 260 + t]);
    }
#pragma unroll
    for (int off = 1; off < 8; off <<= 1) mx = fmaxf(mx, __shfl_xor(mx, off, 64));
    float sum = 0.f;
#pragma unroll
    for (int k = 0; k < 32; ++k) {
      int t = l8 + 8 * k;
      if (t < S) {
        float e = __expf(Ls[row * 260 + t] - mx);
        Ls[row * 260 + t] = e;
        sum += e;
      } else if (t < 256) {
        Ls[row * 260 + t] = 0.f;
      }
    }
#pragma unroll
    for (int off = 1; off < 8; off <<= 1) sum += __shfl_xor(sum, off, 64);
    float inv = 1.f / sum;
#pragma unroll
    for (int k = 0; k < 25; ++k) {
      int t = l8 + 8 * k;
      if (t < S) Ls[row * 260 + t] *= inv;
    }
  }
  __syncthreads();

  // ---- dump probs tile as bf16 (coalesced, disjoint ownership) ----
  if (tid < 197) {
    for (int rr2 = 0; rr2 < 32; ++rr2) {
      int sg = s0 + rr2;
      if (sg >= S) break;
      probs[((size_t)bhl * S + sg) * S + tid] =
          __float2bfloat16(Ls[rr2 * 260 + tid]);
    }
  }

  // ---- PV phase ----
  float acc2[2][4] = {};
  for (int tc = 0; tc < 4; ++tc) {
    const int t0 = tc * 64;
    __syncthreads();
    for (int idx = tid; idx < 64 * 64; idx += 256) {
      int dd = idx & 63, tt = idx >> 6;
      int tg = t0 + tt;
      KV[tt * 68 + dd] = (tg < S) ? vbuf[((size_t)bh * S + tg) * D + dd] : 0.f;
    }
    __syncthreads();
    for (int k4 = 0; k4 < 64; k4 += 4) {
      float4 a0 = *reinterpret_cast<const float4*>(&Ls[(ty * 2 + 0) * 260 + t0 + k4]);
      float4 a1 = *reinterpret_cast<const float4*>(&Ls[(ty * 2 + 1) * 260 + t0 + k4]);
      float a0v[4] = {a0.x, a0.y, a0.z, a0.w};
      float a1v[4] = {a1.x, a1.y, a1.z, a1.w};
#pragma unroll
      for (int kk = 0; kk < 4; ++kk) {
        float4 bb = *reinterpret_cast<const float4*>(&KV[(k4 + kk) * 68 + tx * 4]);
        float bv[4] = {bb.x, bb.y, bb.z, bb.w};
#pragma unroll
        for (int c = 0; c < 4; ++c) {
          acc2[0][c] = fmaf(a0v[kk], bv[c], acc2[0][c]);
          acc2[1][c] = fmaf(a1v[kk], bv[c], acc2[1][c]);
        }
      }
    }
  }
#pragma unroll
  for (int r = 0; r < 2; ++r) {
    int sg = s0 + ty * 2 + r;
    if (sg >= S) continue;
#pragma unroll
    for (int c = 0; c < 4; ++c) {
      int dd = tx * 4 + c;
      context[((size_t)b_ * S + sg) * E + h_ * D + dd] = acc2[r][c];
    }
  }
}

// ---------------- avg reduction over heads (streaming) -------------------------
// grid: bc*S blocks; block = one (bl, s) row; thread t sums 12 heads.
__global__ __launch_bounds__(256) void mha_avgred(const __hip_bfloat16* __restrict__ probs,
                                                  float* __restrict__ avg,
                                                  int b0) {
  const int bs = blockIdx.x;
  const int bl = bs / S, s = bs - bl * S;
  const int t = threadIdx.x;
  if (t >= S) return;
  float acc = 0.f;
#pragma unroll
  for (int h = 0; h < H; ++h)
    acc += __bfloat162float(probs[(((size_t)bl * H + h) * S + s) * S + t]);
  avg[(((size_t)(b0 + bl)) * S + s) * S + t] = acc * (1.f / H);
}

// ---------------- LayerNorm over E -------------------------------------------
__global__ __launch_bounds__(256) void mha_ln(const float* __restrict__ x,
                                              const float* __restrict__ g,
                                              const float* __restrict__ bb,
                                              float* __restrict__ y) {
  __shared__ float sm[4];
  const size_t r = blockIdx.x;
  const float* xr = x + r * E;
  const int tid = threadIdx.x;
  float s1 = 0.f, s2 = 0.f;
  for (int i = tid; i < E; i += 256) {
    float v = xr[i];
    s1 += v;
    s2 += v * v;
  }
  s1 = bsum(s1, sm, tid);
  s2 = bsum(s2, sm, tid);
  float mu = s1 * (1.f / E);
  float var = s2 * (1.f / E) - mu * mu;
  float inv = rsqrtf(var + 1e-5f);
  float* yr = y + r * E;
  for (int i = tid; i < E; i += 256) yr[i] = (xr[i] - mu) * inv * g[i] + bb[i];
}

// ---------------- fc1 (768->96) + tanh-gelu ------------------------------------
__global__ __launch_bounds__(256) void mha_fc1(const float* __restrict__ ln,
                                               const float* __restrict__ w,
                                               const float* __restrict__ bias,
                                               float* __restrict__ h1) {
  __shared__ float Ls2[64][33];
  __shared__ float Ws[32][97];
  const int m0 = blockIdx.x * 64;
  const int tid = threadIdx.x;
  const int tx = tid & 15, ty = tid >> 4;
  float acc[4][6] = {};
  for (int k0 = 0; k0 < E; k0 += 32) {
    for (int idx = tid; idx < 64 * 32; idx += 256) {
      int m = idx >> 5, k = idx & 31;
      Ls2[m][k] = ln[(size_t)(m0 + m) * E + k0 + k];
    }
    for (int idx = tid; idx < 32 * 96; idx += 256) {
      int k = idx / 96, n = idx - k * 96;
      Ws[k][n] = w[(size_t)(k0 + k) * 96 + n];
    }
    __syncthreads();
    for (int k = 0; k < 32; ++k) {
      float a[4], bb[6];
#pragma unroll
      for (int r = 0; r < 4; ++r) a[r] = Ls2[ty * 4 + r][k];
#pragma unroll
      for (int c = 0; c < 6; ++c) bb[c] = Ws[k][tx * 6 + c];
#pragma unroll
      for (int r = 0; r < 4; ++r)
#pragma unroll
        for (int c = 0; c < 6; ++c) acc[r][c] = fmaf(a[r], bb[c], acc[r][c]);
    }
    __syncthreads();
  }
#pragma unroll
  for (int r = 0; r < 4; ++r) {
    int m = m0 + ty * 4 + r;
#pragma unroll
    for (int c = 0; c < 6; ++c) {
      int n = tx * 6 + c;
      float u = acc[r][c] + bias[n];
      float gl = 0.5f * u * (1.f + tanhf(0.7978845608028654f * (u + 0.044715f * u * u * u)));
      h1[(size_t)m * 96 + n] = gl;
    }
  }
}

// ---------------- fc2 (96->768) + sigmoid, scale context -----------------------
__global__ __launch_bounds__(256) void mha_fc2(const float* __restrict__ h1,
                                               const float* __restrict__ w,
                                               const float* __restrict__ bias,
                                               const float* __restrict__ context,
                                               float* __restrict__ attn2) {
  __shared__ float Hs[64][97];
  __shared__ float Ws[96][65];
  const int m0 = blockIdx.x * 64;
  const int n0 = blockIdx.y * 64;
  const int tid = threadIdx.x;
  for (int idx = tid; idx < 64 * 96; idx += 256) {
    int m = idx / 96, k = idx - m * 96;
    Hs[m][k] = h1[(size_t)(m0 + m) * 96 + k];
  }
  for (int idx = tid; idx < 96 * 64; idx += 256) {
    int k = idx >> 6, n = idx & 63;
    Ws[k][n] = w[(size_t)k * E + n0 + n];
  }
  __syncthreads();
  const int tx = tid & 15, ty = tid >> 4;
  float acc[4][4] = {};
  for (int k = 0; k < 96; ++k) {
    float a[4], bb[4];
#pragma unroll
    for (int r = 0; r < 4; ++r) a[r] = Hs[ty * 4 + r][k];
#pragma unroll
    for (int c = 0; c < 4; ++c) bb[c] = Ws[k][tx * 4 + c];
#pragma unroll
    for (int r = 0; r < 4; ++r)
#pragma unroll
      for (int c = 0; c < 4; ++c) acc[r][c] = fmaf(a[r], bb[c], acc[r][c]);
  }
#pragma unroll
  for (int r = 0; r < 4; ++r) {
    int m = m0 + ty * 4 + r;
#pragma unroll
    for (int c = 0; c < 4; ++c) {
      int e = n0 + tx * 4 + c;
      float val = acc[r][c] + bias[e];
      float sg = 1.f / (1.f + __expf(-val));
      attn2[(size_t)m * E + e] = context[(size_t)m * E + e] * sg;
    }
  }
}

// ---------------- grouped out projection + bias + transpose to [S,B,E] ---------
__global__ __launch_bounds__(256) void mha_out(const float* __restrict__ attn2,
                                               const float* __restrict__ w,
                                               const float* __restrict__ bias,
                                               float* __restrict__ outp) {
  __shared__ float As[64][97];
  __shared__ float Ws[96][97];
  const int m0 = blockIdx.x * 64;
  const int g = blockIdx.y;
  const int n0 = g * 96;
  const int tid = threadIdx.x;
  for (int idx = tid; idx < 64 * 96; idx += 256) {
    int m = idx / 96, j = idx - m * 96;
    As[m][j] = attn2[(size_t)(m0 + m) * E + g * 96 + j];
  }
  for (int idx = tid; idx < 96 * 96; idx += 256) {
    int n = idx / 96, j = idx - n * 96;
    Ws[n][j] = w[(size_t)(n0 + n) * 96 + j];
  }
  __syncthreads();
  const int tx = tid & 15, ty = tid >> 4;
  float acc[4][6] = {};
  for (int j = 0; j < 96; ++j) {
    float a[4], bb[6];
#pragma unroll
    for (int r = 0; r < 4; ++r) a[r] = As[ty * 4 + r][j];
#pragma unroll
    for (int c = 0; c < 6; ++c) bb[c] = Ws[tx * 6 + c][j];
#pragma unroll
    for (int r = 0; r < 4; ++r)
#pragma unroll
      for (int c = 0; c < 6; ++c) acc[r][c] = fmaf(a[r], bb[c], acc[r][c]);
  }
#pragma unroll
  for (int r = 0; r < 4; ++r) {
    int m = m0 + ty * 4 + r;
    int b = m / S, s = m - b * S;  // rows here are r = b*S + s
#pragma unroll
    for (int c = 0; c < 6; ++c) {
      int p = n0 + tx * 6 + c;
      outp[((size_t)s * B + b) * E + p] = acc[r][c] + bias[p];
    }
  }
}

// ---------------- host launcher ------------------------------------------------
extern "C" void kernel_launch(void* const* d_in, const int* in_sizes, int n_in,
                              void* d_out, int out_size, void* d_ws, size_t ws_size,
                              hipStream_t stream) {
  const float* query = (const float*)d_in[0];
  const float* qkv_w = (const float*)d_in[3];
  const float* qkv_b = (const float*)d_in[4];
  const float* out_w = (const float*)d_in[5];
  const float* out_b = (const float*)d_in[6];
  const float* rel   = (const float*)d_in[7];
  const float* ln_g  = (const float*)d_in[8];
  const float* ln_b  = (const float*)d_in[9];
  const float* fc1_w = (const float*)d_in[10];
  const float* fc1_b = (const float*)d_in[11];
  const float* fc2_w = (const float*)d_in[12];
  const float* fc2_b = (const float*)d_in[13];

  float* ws = (float*)d_ws;
  float* qhat    = ws;                 // [B,H,S,D]
  float* khat    = ws + SBE;           // [B,H,S,D]
  float* vbuf    = ws + 2 * SBE;       // [B,H,S,D]
  float* ybuf    = ws + 3 * SBE;       // y chunk / later context
  float* context = ws + 3 * SBE;       // rows b*S+s, [.,768] (aliases ybuf)
  float* Rbuf    = ws + 4 * SBE;       // 197*197
  __hip_bfloat16* probsb = (__hip_bfloat16*)(ws + 4 * SBE + 38816);
  float* lnbuf = qhat;   // reuse after attention
  float* h1    = khat;   // reuse
  float* attn2 = vbuf;   // reuse
  float* outp  = (float*)d_out;
  float* avgp  = outp + SBE;

  // probs chunk size (bf16): pick largest even divisor of B that fits ws
  size_t used_bytes = (4 * SBE + 38816) * sizeof(float);
  size_t avail = (ws_size > used_bytes) ? ws_size - used_bytes : 0;
  int Bc = 2;
  const int cand[5] = {64, 32, 16, 8, 4};
  for (int i = 0; i < 5; ++i) {
    size_t need = (size_t)cand[i] * H * S * S * sizeof(__hip_bfloat16);
    if (need <= avail) { Bc = cand[i]; break; }
  }

  mha_relR<<<(S * S + 255) / 256, 256, 0, stream>>>(rel, Rbuf);

  // qkv two-pass, chunked over m (ybuf aliases context region)
  const int CH = 3200;  // multiple of 64 and 32
  for (int mbase = 0; mbase < M; mbase += CH) {
    int rows = (M - mbase < CH) ? (M - mbase) : CH;
    mha_qkv_gemm<<<dim3(rows / 64, 24), 256, 0, stream>>>(query, qkv_w, qkv_b, ybuf,
                                                          mbase, rows);
    mha_qkv_shuffle<<<dim3(rows / 32, 36), 256, 0, stream>>>(ybuf, rel, qhat, khat,
                                                             vbuf, mbase, rows);
  }

  for (int b0 = 0; b0 < B; b0 += Bc) {
    int bc = (B - b0 < Bc) ? (B - b0) : Bc;
    int nbh = bc * H;  // multiple of 8 for even bc
    mha_fattn<<<7 * nbh, 256, 0, stream>>>(qhat, khat, vbuf, Rbuf, context, probsb,
                                           b0 * H);
    mha_avgred<<<bc * S, 256, 0, stream>>>(probsb, avgp, b0);
  }

  mha_ln<<<M, 256, 0, stream>>>(context, ln_g, ln_b, lnbuf);
  mha_fc1<<<M / 64, 256, 0, stream>>>(lnbuf, fc1_w, fc1_b, h1);
  mha_fc2<<<dim3(M / 64, 12), 256, 0, stream>>>(h1, fc2_w, fc2_b, context, attn2);
  mha_out<<<dim3(M / 64, 8), 256, 0, stream>>>(attn2, out_w, out_b, outp);
}

// Round 6
// 748.829 us; speedup vs baseline: 8.7201x; 1.9966x over previous
//
#include <hip/hip_runtime.h>
#include <hip/hip_bf16.h>

// ---------------- constants ----------------
constexpr int S = 197;
constexpr int B = 64;
constexpr int E = 768;
constexpr int H = 12;
constexpr int D = 64;
constexpr int M = S * B;                  // 12608 rows
constexpr size_t SBE = (size_t)M * E;     // 9,682,944 (= B*H*S*D too)

typedef short bf16x8 __attribute__((ext_vector_type(8)));
typedef float f32x4 __attribute__((ext_vector_type(4)));
typedef unsigned int u32x4 __attribute__((ext_vector_type(4)));

__device__ __forceinline__ unsigned short f2b(float x) {  // f32 -> bf16 (RNE)
  unsigned int u = __float_as_uint(x);
  return (unsigned short)((u + 0x7FFFu + ((u >> 16) & 1u)) >> 16);
}
__device__ __forceinline__ float b2f(unsigned short u) {
  return __uint_as_float((unsigned int)u << 16);
}

// ---------------- block reduction (ln) ----------------
__device__ __forceinline__ float bsum(float v, float* sm, int tid) {
#pragma unroll
  for (int off = 32; off > 0; off >>= 1) v += __shfl_down(v, off, 64);
  if ((tid & 63) == 0) sm[tid >> 6] = v;
  __syncthreads();
  float r = sm[0] + sm[1] + sm[2] + sm[3];
  __syncthreads();
  return r;
}

// ---------------- relb: bf16 rel rows (rel[196+s][d]), zero-padded to 256 ------
__global__ __launch_bounds__(256) void mha_relb(const float* __restrict__ rel,
                                                unsigned short* __restrict__ relb) {
  int idx = blockIdx.x * 256 + threadIdx.x;
  if (idx >= 256 * 64) return;
  int s2 = idx >> 6, d = idx & 63;
  float v = (s2 < S) ? rel[(size_t)(S - 1 + s2) * D + d] : 0.f;
  relb[idx] = f2b(v);
}

// ---------------- QKV grouped GEMM, pass A (f32, unchanged) --------------------
__global__ __launch_bounds__(256) void mha_qkv_gemm(const float* __restrict__ x,
                                                    const float* __restrict__ w,
                                                    const float* __restrict__ bias,
                                                    float* __restrict__ y,
                                                    int mbase, int rows) {
  __shared__ float Xt[96][68];
  __shared__ float Ws[96][98];
  const int m0 = mbase + blockIdx.x * 64;
  const int n0 = blockIdx.y * 96;
  const int g = n0 / 288;
  const int tid = threadIdx.x;
  for (int idx = tid; idx < 64 * 96; idx += 256) {
    int mm = idx / 96, k = idx - mm * 96;
    Xt[k][mm] = x[(size_t)(m0 + mm) * E + g * 96 + k];
  }
  for (int idx = tid; idx < 96 * 96; idx += 256) {
    int n = idx / 96, k = idx - n * 96;
    Ws[k][n] = w[(size_t)(n0 + n) * 96 + k];
  }
  __syncthreads();
  const int tx = tid & 15, ty = tid >> 4;
  float acc[4][6] = {};
  for (int k = 0; k < 96; ++k) {
    float4 a = *reinterpret_cast<const float4*>(&Xt[k][ty * 4]);
    float2 w0 = *reinterpret_cast<const float2*>(&Ws[k][tx * 6]);
    float2 w1 = *reinterpret_cast<const float2*>(&Ws[k][tx * 6 + 2]);
    float2 w2 = *reinterpret_cast<const float2*>(&Ws[k][tx * 6 + 4]);
    float av[4] = {a.x, a.y, a.z, a.w};
    float bv[6] = {w0.x, w0.y, w1.x, w1.y, w2.x, w2.y};
#pragma unroll
    for (int r = 0; r < 4; ++r)
#pragma unroll
      for (int c = 0; c < 6; ++c) acc[r][c] = fmaf(av[r], bv[c], acc[r][c]);
  }
  const int mloc = m0 - mbase + ty * 4;
#pragma unroll
  for (int r = 0; r < 4; ++r) {
#pragma unroll
    for (int c = 0; c < 6; ++c) {
      int p = n0 + tx * 6 + c;
      y[(size_t)(mloc + r) * 2304 + p] = acc[r][c] + bias[p];
    }
  }
}

// ---------------- QKV pass B: shuffle + head scatter + rel fold -> bf16 --------
__global__ __launch_bounds__(256) void mha_qkv_shuffle(const float* __restrict__ y,
                                                       const float* __restrict__ rel,
                                                       unsigned short* __restrict__ qb,
                                                       unsigned short* __restrict__ kb,
                                                       unsigned short* __restrict__ vb,
                                                       int mbase, int rows) {
  const int wh = blockIdx.y;
  const int which = wh / H, h = wh - which * H;
  const int basep = which * 96 + h * 8;
  const int tid = threadIdx.x;
  const int lane = tid & 63;
  const int g = lane >> 3, j = lane & 7;
  const int d = j * 8 + g;
  const int rbase = blockIdx.x * 32;
#pragma unroll
  for (int r8 = 0; r8 < 8; ++r8) {
    int rowl = rbase + r8 * 4 + (tid >> 6);
    if (rowl >= rows) continue;
    int m = mbase + rowl;
    int s = m >> 6, b = m & 63;
    float val = y[(size_t)rowl * 2304 + g * 288 + basep + j];
    size_t o = (((size_t)b * H + h) * S + s) * D + d;
    if (which == 0) {
      float rv = rel[(size_t)(S - 1 + s) * D + d];
      qb[o] = f2b(0.125f * val + rv);
    } else if (which == 1) {
      float rv = rel[(size_t)(S - 1 + s) * D + d];
      kb[o] = f2b(val + rv);
    } else {
      vb[o] = f2b(val);
    }
  }
}

// ---------------- fused MFMA attention ----------------------------------------
// grid: 1-D 4*nbh blocks, XCD-swizzled. block = (bh, stile of 64 s-rows),
// 4 waves, wave w owns s-frag rows 16w..16w+15.
// K-dim extended to 128: cols 0..63 = qhat/khat, 64..127 = rel_s / -rel_t
// (folds the R correction into the MFMA).
__global__ __launch_bounds__(256) void mha_fattn(
    const unsigned short* __restrict__ qb, const unsigned short* __restrict__ kb,
    const unsigned short* __restrict__ vb, const unsigned short* __restrict__ relb,
    float* __restrict__ context, unsigned short* __restrict__ probs, int bh0) {
  __shared__ __align__(16) unsigned short ldsA[64 * 136 * 2];  // Qt | Kt ; later Pt
  __shared__ __align__(16) unsigned short Vt[64 * 232];        // V^T [d][t]
  unsigned short* Qt = ldsA;
  unsigned short* Kt = ldsA + 64 * 136;
  unsigned short* Pt = ldsA;  // overlay: 64*232 = 14848 <= 17408

  const int id = blockIdx.x;
  const int xcd = id & 7;
  const int rr = id >> 3;
  const int stile = rr & 3;
  const int bhl = xcd + 8 * (rr >> 2);
  const int bh = bh0 + bhl;
  const int b_ = bh / H, h_ = bh - b_ * H;
  const int s0 = stile * 64;
  const int tid = threadIdx.x;
  const int lane = tid & 63, w = tid >> 6;
  const int l15 = lane & 15, l4 = lane >> 4;

  // ---- stage Qt [64][136] (q | rel) ----
#pragma unroll
  for (int ii = 0; ii < 2; ++ii) {
    int idx = tid + ii * 256;
    int r = idx >> 3, c = idx & 7;
    int sg = s0 + r;
    u32x4 qv = {0, 0, 0, 0}, rv = {0, 0, 0, 0};
    if (sg < S) {
      qv = *(const u32x4*)(qb + (((size_t)bh * S + sg) << 6) + c * 8);
      rv = *(const u32x4*)(relb + ((size_t)sg << 6) + c * 8);
    }
    *(u32x4*)(Qt + r * 136 + c * 8) = qv;
    *(u32x4*)(Qt + r * 136 + 64 + c * 8) = rv;
  }
  // ---- stage Vt [d][t] transposed, zero pad t>=197 ----
  for (int idx = tid; idx < 64 * 232; idx += 256) {
    int t = idx >> 6, d = idx & 63;
    unsigned short v = 0;
    if (t < S) v = vb[(((size_t)bh * S + t) << 6) + d];
    Vt[d * 232 + t] = v;
  }
  __syncthreads();

  // ---- preload Q A-frags (per wave: rows 16w+l15, k-blocks of 32) ----
  const unsigned short* qrow = Qt + (16 * w + l15) * 136 + l4 * 8;
  bf16x8 aq0 = *(const bf16x8*)(qrow);
  bf16x8 aq1 = *(const bf16x8*)(qrow + 32);
  bf16x8 aq2 = *(const bf16x8*)(qrow + 64);
  bf16x8 aq3 = *(const bf16x8*)(qrow + 96);

  f32x4 acc[13];
#pragma unroll
  for (int i = 0; i < 13; ++i) acc[i] = (f32x4){0.f, 0.f, 0.f, 0.f};

  // ---- QK^T over 4 t-chunks of 64 ----
#pragma unroll
  for (int tc = 0; tc < 4; ++tc) {
    if (tc) __syncthreads();
    const int t0 = tc * 64;
#pragma unroll
    for (int ii = 0; ii < 2; ++ii) {
      int idx = tid + ii * 256;
      int r = idx >> 3, c = idx & 7;
      int tg = t0 + r;
      u32x4 kv = {0, 0, 0, 0}, rv = {0, 0, 0, 0};
      if (tg < S) {
        kv = *(const u32x4*)(kb + (((size_t)bh * S + tg) << 6) + c * 8);
        rv = *(const u32x4*)(relb + ((size_t)tg << 6) + c * 8);
        rv ^= 0x80008000u;  // negate rel for K side
      }
      *(u32x4*)(Kt + r * 136 + c * 8) = kv;
      *(u32x4*)(Kt + r * 136 + 64 + c * 8) = rv;
    }
    __syncthreads();
#pragma unroll
    for (int tf = 0; tf < 4; ++tf) {
      if (tc == 3 && tf > 0) continue;  // only t<208 needed
      const unsigned short* kbse = Kt + (tf * 16 + l15) * 136 + l4 * 8;
      f32x4 a = acc[tc * 4 + tf];
      a = __builtin_amdgcn_mfma_f32_16x16x32_bf16(aq0, *(const bf16x8*)(kbse), a, 0, 0, 0);
      a = __builtin_amdgcn_mfma_f32_16x16x32_bf16(aq1, *(const bf16x8*)(kbse + 32), a, 0, 0, 0);
      a = __builtin_amdgcn_mfma_f32_16x16x32_bf16(aq2, *(const bf16x8*)(kbse + 64), a, 0, 0, 0);
      a = __builtin_amdgcn_mfma_f32_16x16x32_bf16(aq3, *(const bf16x8*)(kbse + 96), a, 0, 0, 0);
      acc[tc * 4 + tf] = a;
    }
  }

  // ---- softmax in registers (D layout: col=l15 -> t=16tf+l15, row=4*l4+r) ----
  if (l15 >= 5) acc[12] = (f32x4){-3.0e38f, -3.0e38f, -3.0e38f, -3.0e38f};
  float inv[4];
#pragma unroll
  for (int r = 0; r < 4; ++r) {
    float m = acc[0][r];
#pragma unroll
    for (int tf = 1; tf < 13; ++tf) m = fmaxf(m, acc[tf][r]);
#pragma unroll
    for (int off = 1; off < 16; off <<= 1) m = fmaxf(m, __shfl_xor(m, off, 64));
    float s = 0.f;
#pragma unroll
    for (int tf = 0; tf < 13; ++tf) {
      float e = __expf(acc[tf][r] - m);
      acc[tf][r] = e;
      s += e;
    }
#pragma unroll
    for (int off = 1; off < 16; off <<= 1) s += __shfl_xor(s, off, 64);
    inv[r] = 1.f / s;
  }

  __syncthreads();  // all QK reads of Qt/Kt done -> safe to overlay Pt

  // ---- write P (bf16) to Pt [64][232], zero pad cols 208..231 ----
#pragma unroll
  for (int tf = 0; tf < 13; ++tf)
#pragma unroll
    for (int r = 0; r < 4; ++r)
      Pt[(16 * w + 4 * l4 + r) * 232 + tf * 16 + l15] = f2b(acc[tf][r] * inv[r]);
  if (l15 < 12) {
#pragma unroll
    for (int r = 0; r < 4; ++r)
      *(unsigned int*)(Pt + (16 * w + 4 * l4 + r) * 232 + 208 + l15 * 2) = 0u;
  }
  __syncthreads();

  // ---- dump probs (bf16) to global for avg reduction ----
  for (int idx = tid; idx < 64 * 197; idx += 256) {
    int r2 = idx / 197;
    int t = idx - r2 * 197;
    int sg = s0 + r2;
    if (sg < S) probs[((size_t)bhl * S + sg) * S + t] = Pt[r2 * 232 + t];
  }

  // ---- PV: out[s][d] = sum_t P[s][t] V[t][d] ----
  bf16x8 ap[7];
#pragma unroll
  for (int kf = 0; kf < 7; ++kf)
    ap[kf] = *(const bf16x8*)(Pt + (16 * w + l15) * 232 + kf * 32 + l4 * 8);
  f32x4 ov[4];
#pragma unroll
  for (int df = 0; df < 4; ++df) {
    f32x4 o = (f32x4){0.f, 0.f, 0.f, 0.f};
    const unsigned short* vbse = Vt + (df * 16 + l15) * 232 + l4 * 8;
#pragma unroll
    for (int kf = 0; kf < 7; ++kf)
      o = __builtin_amdgcn_mfma_f32_16x16x32_bf16(ap[kf], *(const bf16x8*)(vbse + kf * 32), o, 0, 0, 0);
    ov[df] = o;
  }
#pragma unroll
  for (int df = 0; df < 4; ++df)
#pragma unroll
    for (int r = 0; r < 4; ++r) {
      int sg = s0 + 16 * w + 4 * l4 + r;
      if (sg < S)
        context[((size_t)b_ * S + sg) * E + h_ * 64 + df * 16 + l15] = ov[df][r];
    }
}

// ---------------- avg reduction over heads (streaming) -------------------------
__global__ __launch_bounds__(256) void mha_avgred(const unsigned short* __restrict__ probs,
                                                  float* __restrict__ avg, int b0) {
  const int bs = blockIdx.x;
  const int bl = bs / S, s = bs - bl * S;
  const int t = threadIdx.x;
  if (t >= S) return;
  float acc = 0.f;
#pragma unroll
  for (int h = 0; h < H; ++h)
    acc += b2f(probs[(((size_t)bl * H + h) * S + s) * S + t]);
  avg[(((size_t)(b0 + bl)) * S + s) * S + t] = acc * (1.f / H);
}

// ---------------- LayerNorm over E -------------------------------------------
__global__ __launch_bounds__(256) void mha_ln(const float* __restrict__ x,
                                              const float* __restrict__ g,
                                              const float* __restrict__ bb,
                                              float* __restrict__ y) {
  __shared__ float sm[4];
  const size_t r = blockIdx.x;
  const float* xr = x + r * E;
  const int tid = threadIdx.x;
  float s1 = 0.f, s2 = 0.f;
  for (int i = tid; i < E; i += 256) {
    float v = xr[i];
    s1 += v;
    s2 += v * v;
  }
  s1 = bsum(s1, sm, tid);
  s2 = bsum(s2, sm, tid);
  float mu = s1 * (1.f / E);
  float var = s2 * (1.f / E) - mu * mu;
  float inv = rsqrtf(var + 1e-5f);
  float* yr = y + r * E;
  for (int i = tid; i < E; i += 256) yr[i] = (xr[i] - mu) * inv * g[i] + bb[i];
}

// ---------------- fc1 (768->96) + tanh-gelu ------------------------------------
__global__ __launch_bounds__(256) void mha_fc1(const float* __restrict__ ln,
                                               const float* __restrict__ w,
                                               const float* __restrict__ bias,
                                               float* __restrict__ h1) {
  __shared__ float Ls2[64][33];
  __shared__ float Ws[32][97];
  const int m0 = blockIdx.x * 64;
  const int tid = threadIdx.x;
  const int tx = tid & 15, ty = tid >> 4;
  float acc[4][6] = {};
  for (int k0 = 0; k0 < E; k0 += 32) {
    for (int idx = tid; idx < 64 * 32; idx += 256) {
      int m = idx >> 5, k = idx & 31;
      Ls2[m][k] = ln[(size_t)(m0 + m) * E + k0 + k];
    }
    for (int idx = tid; idx < 32 * 96; idx += 256) {
      int k = idx / 96, n = idx - k * 96;
      Ws[k][n] = w[(size_t)(k0 + k) * 96 + n];
    }
    __syncthreads();
    for (int k = 0; k < 32; ++k) {
      float a[4], bb[6];
#pragma unroll
      for (int r = 0; r < 4; ++r) a[r] = Ls2[ty * 4 + r][k];
#pragma unroll
      for (int c = 0; c < 6; ++c) bb[c] = Ws[k][tx * 6 + c];
#pragma unroll
      for (int r = 0; r < 4; ++r)
#pragma unroll
        for (int c = 0; c < 6; ++c) acc[r][c] = fmaf(a[r], bb[c], acc[r][c]);
    }
    __syncthreads();
  }
#pragma unroll
  for (int r = 0; r < 4; ++r) {
    int m = m0 + ty * 4 + r;
#pragma unroll
    for (int c = 0; c < 6; ++c) {
      int n = tx * 6 + c;
      float u = acc[r][c] + bias[n];
      float gl = 0.5f * u * (1.f + tanhf(0.7978845608028654f * (u + 0.044715f * u * u * u)));
      h1[(size_t)m * 96 + n] = gl;
    }
  }
}

// ---------------- fc2 (96->768) + sigmoid, scale context -----------------------
__global__ __launch_bounds__(256) void mha_fc2(const float* __restrict__ h1,
                                               const float* __restrict__ w,
                                               const float* __restrict__ bias,
                                               const float* __restrict__ context,
                                               float* __restrict__ attn2) {
  __shared__ float Hs[64][97];
  __shared__ float Ws[96][65];
  const int m0 = blockIdx.x * 64;
  const int n0 = blockIdx.y * 64;
  const int tid = threadIdx.x;
  for (int idx = tid; idx < 64 * 96; idx += 256) {
    int m = idx / 96, k = idx - m * 96;
    Hs[m][k] = h1[(size_t)(m0 + m) * 96 + k];
  }
  for (int idx = tid; idx < 96 * 64; idx += 256) {
    int k = idx >> 6, n = idx & 63;
    Ws[k][n] = w[(size_t)k * E + n0 + n];
  }
  __syncthreads();
  const int tx = tid & 15, ty = tid >> 4;
  float acc[4][4] = {};
  for (int k = 0; k < 96; ++k) {
    float a[4], bb[4];
#pragma unroll
    for (int r = 0; r < 4; ++r) a[r] = Hs[ty * 4 + r][k];
#pragma unroll
    for (int c = 0; c < 4; ++c) bb[c] = Ws[k][tx * 4 + c];
#pragma unroll
    for (int r = 0; r < 4; ++r)
#pragma unroll
      for (int c = 0; c < 4; ++c) acc[r][c] = fmaf(a[r], bb[c], acc[r][c]);
  }
#pragma unroll
  for (int r = 0; r < 4; ++r) {
    int m = m0 + ty * 4 + r;
#pragma unroll
    for (int c = 0; c < 4; ++c) {
      int e = n0 + tx * 4 + c;
      float val = acc[r][c] + bias[e];
      float sg = 1.f / (1.f + __expf(-val));
      attn2[(size_t)m * E + e] = context[(size_t)m * E + e] * sg;
    }
  }
}

// ---------------- grouped out projection + bias + transpose to [S,B,E] ---------
__global__ __launch_bounds__(256) void mha_out(const float* __restrict__ attn2,
                                               const float* __restrict__ w,
                                               const float* __restrict__ bias,
                                               float* __restrict__ outp) {
  __shared__ float As[64][97];
  __shared__ float Ws[96][97];
  const int m0 = blockIdx.x * 64;
  const int g = blockIdx.y;
  const int n0 = g * 96;
  const int tid = threadIdx.x;
  for (int idx = tid; idx < 64 * 96; idx += 256) {
    int m = idx / 96, j = idx - m * 96;
    As[m][j] = attn2[(size_t)(m0 + m) * E + g * 96 + j];
  }
  for (int idx = tid; idx < 96 * 96; idx += 256) {
    int n = idx / 96, j = idx - n * 96;
    Ws[n][j] = w[(size_t)(n0 + n) * 96 + j];
  }
  __syncthreads();
  const int tx = tid & 15, ty = tid >> 4;
  float acc[4][6] = {};
  for (int j = 0; j < 96; ++j) {
    float a[4], bb[6];
#pragma unroll
    for (int r = 0; r < 4; ++r) a[r] = As[ty * 4 + r][j];
#pragma unroll
    for (int c = 0; c < 6; ++c) bb[c] = Ws[tx * 6 + c][j];
#pragma unroll
    for (int r = 0; r < 4; ++r)
#pragma unroll
      for (int c = 0; c < 6; ++c) acc[r][c] = fmaf(a[r], bb[c], acc[r][c]);
  }
#pragma unroll
  for (int r = 0; r < 4; ++r) {
    int m = m0 + ty * 4 + r;
    int b = m / S, s = m - b * S;
#pragma unroll
    for (int c = 0; c < 6; ++c) {
      int p = n0 + tx * 6 + c;
      outp[((size_t)s * B + b) * E + p] = acc[r][c] + bias[p];
    }
  }
}

// ---------------- host launcher ------------------------------------------------
extern "C" void kernel_launch(void* const* d_in, const int* in_sizes, int n_in,
                              void* d_out, int out_size, void* d_ws, size_t ws_size,
                              hipStream_t stream) {
  const float* query = (const float*)d_in[0];
  const float* qkv_w = (const float*)d_in[3];
  const float* qkv_b = (const float*)d_in[4];
  const float* out_w = (const float*)d_in[5];
  const float* out_b = (const float*)d_in[6];
  const float* rel   = (const float*)d_in[7];
  const float* ln_g  = (const float*)d_in[8];
  const float* ln_b  = (const float*)d_in[9];
  const float* fc1_w = (const float*)d_in[10];
  const float* fc1_b = (const float*)d_in[11];
  const float* fc2_w = (const float*)d_in[12];
  const float* fc2_b = (const float*)d_in[13];

  float* ws = (float*)d_ws;
  unsigned short* qb   = (unsigned short*)ws;      // SBE bf16
  unsigned short* kbuf = qb + SBE;                 // SBE bf16
  unsigned short* vbb  = kbuf + SBE;               // SBE bf16
  unsigned short* relb = vbb + SBE;                // 256*64 bf16
  size_t off = 3 * SBE / 2 + 8192;                 // floats consumed so far
  float* context = ws + off;                       // SBE f32 (ybuf aliases)
  float* ybuf    = context;
  float* lnbuf   = ws + off + SBE;                 // SBE f32 (attn2 aliases)
  float* attn2   = lnbuf;
  float* h1      = ws + off + 2 * SBE;             // M*96 f32
  unsigned short* probsb = (unsigned short*)(ws + off + 2 * SBE + (size_t)M * 96);
  float* outp = (float*)d_out;
  float* avgp = outp + SBE;

  // probs chunk size (bf16)
  size_t used_f = off + 2 * SBE + (size_t)M * 96;
  size_t avail_f = (ws_size / 4 > used_f) ? ws_size / 4 - used_f : 0;
  int Bc = 2;
  const int cand[6] = {64, 32, 16, 8, 4, 2};
  for (int i = 0; i < 6; ++i) {
    size_t need_f = ((size_t)cand[i] * H * S * S + 1) / 2;
    if (need_f <= avail_f) { Bc = cand[i]; break; }
  }

  mha_relb<<<64, 256, 0, stream>>>(rel, relb);

  const int CH = 3200;
  for (int mbase = 0; mbase < M; mbase += CH) {
    int rows = (M - mbase < CH) ? (M - mbase) : CH;
    mha_qkv_gemm<<<dim3(rows / 64, 24), 256, 0, stream>>>(query, qkv_w, qkv_b, ybuf,
                                                          mbase, rows);
    mha_qkv_shuffle<<<dim3(rows / 32, 36), 256, 0, stream>>>(ybuf, rel, qb, kbuf,
                                                             vbb, mbase, rows);
  }

  for (int b0 = 0; b0 < B; b0 += Bc) {
    int bc = (B - b0 < Bc) ? (B - b0) : Bc;
    int nbh = bc * H;  // multiple of 8 (bc even)
    mha_fattn<<<4 * nbh, 256, 0, stream>>>(qb, kbuf, vbb, relb, context, probsb,
                                           b0 * H);
    mha_avgred<<<bc * S, 256, 0, stream>>>(probsb, avgp, b0);
  }

  mha_ln<<<M, 256, 0, stream>>>(context, ln_g, ln_b, lnbuf);
  mha_fc1<<<M / 64, 256, 0, stream>>>(lnbuf, fc1_w, fc1_b, h1);
  mha_fc2<<<dim3(M / 64, 12), 256, 0, stream>>>(h1, fc2_w, fc2_b, context, attn2);
  mha_out<<<dim3(M / 64, 8), 256, 0, stream>>>(attn2, out_w, out_b, outp);
}

// Round 7
// 505.190 us; speedup vs baseline: 12.9255x; 1.4823x over previous
//
#include <hip/hip_runtime.h>
#include <hip/hip_bf16.h>

// ---------------- constants ----------------
constexpr int S = 197;
constexpr int B = 64;
constexpr int E = 768;
constexpr int H = 12;
constexpr int D = 64;
constexpr int M = S * B;                  // 12608 rows
constexpr size_t SBE = (size_t)M * E;     // 9,682,944 (= B*H*S*D too)

typedef short bf16x8 __attribute__((ext_vector_type(8)));
typedef float f32x4 __attribute__((ext_vector_type(4)));
typedef unsigned int u32x4 __attribute__((ext_vector_type(4)));

__device__ __forceinline__ unsigned short f2b(float x) {  // f32 -> bf16 (RNE)
  unsigned int u = __float_as_uint(x);
  return (unsigned short)((u + 0x7FFFu + ((u >> 16) & 1u)) >> 16);
}
__device__ __forceinline__ float b2f(unsigned short u) {
  return __uint_as_float((unsigned int)u << 16);
}

// ---------------- block reduction (ln) ----------------
__device__ __forceinline__ float bsum(float v, float* sm, int tid) {
#pragma unroll
  for (int off = 32; off > 0; off >>= 1) v += __shfl_down(v, off, 64);
  if ((tid & 63) == 0) sm[tid >> 6] = v;
  __syncthreads();
  float r = sm[0] + sm[1] + sm[2] + sm[3];
  __syncthreads();
  return r;
}

// ---------------- relb: bf16 rel rows (rel[196+s][d]), zero-padded to 256 ------
__global__ __launch_bounds__(256) void mha_relb(const float* __restrict__ rel,
                                                unsigned short* __restrict__ relb) {
  int idx = blockIdx.x * 256 + threadIdx.x;
  if (idx >= 256 * 64) return;
  int s2 = idx >> 6, d = idx & 63;
  float v = (s2 < S) ? rel[(size_t)(S - 1 + s2) * D + d] : 0.f;
  relb[idx] = f2b(v);
}

// ---------------- QKV grouped GEMM (MFMA bf16), y out bf16 ---------------------
// grid (rows/64, 24). n0 = by*96 covers one group slice; K = 96 (grouped).
// A = x rows (bf16), B = w rows (bf16, already [p][96] k-major). D: col = B-row,
// row = A-row (same verified mapping as fattn).
__global__ __launch_bounds__(256) void mha_qkv_gemm(const float* __restrict__ x,
                                                    const float* __restrict__ w,
                                                    const float* __restrict__ bias,
                                                    unsigned short* __restrict__ y,
                                                    int mbase, int rows) {
  __shared__ __align__(16) unsigned short Xs[64 * 104];
  __shared__ __align__(16) unsigned short Wsl[96 * 104];
  __shared__ float bias_s[96];
  const int m0 = mbase + blockIdx.x * 64;
  const int n0 = blockIdx.y * 96;
  const int g = blockIdx.y / 3;
  const int tid = threadIdx.x;

  // stage X tile [64][96] as bf16 (float4 global loads)
  for (int i = tid; i < 64 * 24; i += 256) {
    int r = i / 24, c4 = i - r * 24;
    float4 v = *reinterpret_cast<const float4*>(
        &x[(size_t)(m0 + r) * E + g * 96 + c4 * 4]);
    unsigned short* dst = Xs + r * 104 + c4 * 4;
    dst[0] = f2b(v.x); dst[1] = f2b(v.y); dst[2] = f2b(v.z); dst[3] = f2b(v.w);
  }
  // stage W tile [96][96] as bf16
  for (int i = tid; i < 96 * 24; i += 256) {
    int n = i / 24, c4 = i - n * 24;
    float4 v = *reinterpret_cast<const float4*>(&w[(size_t)(n0 + n) * 96 + c4 * 4]);
    unsigned short* dst = Wsl + n * 104 + c4 * 4;
    dst[0] = f2b(v.x); dst[1] = f2b(v.y); dst[2] = f2b(v.z); dst[3] = f2b(v.w);
  }
  if (tid < 96) bias_s[tid] = bias[n0 + tid];
  __syncthreads();

  const int lane = tid & 63, wv = tid >> 6;
  const int l15 = lane & 15, l4 = lane >> 4;

  const unsigned short* xrow = Xs + (16 * wv + l15) * 104 + l4 * 8;
  bf16x8 a0 = *(const bf16x8*)(xrow);
  bf16x8 a1 = *(const bf16x8*)(xrow + 32);
  bf16x8 a2 = *(const bf16x8*)(xrow + 64);

  f32x4 acc[6];
#pragma unroll
  for (int nf = 0; nf < 6; ++nf) acc[nf] = (f32x4){0.f, 0.f, 0.f, 0.f};
#pragma unroll
  for (int nf = 0; nf < 6; ++nf) {
    const unsigned short* wrow = Wsl + (nf * 16 + l15) * 104 + l4 * 8;
    f32x4 a = acc[nf];
    a = __builtin_amdgcn_mfma_f32_16x16x32_bf16(a0, *(const bf16x8*)(wrow), a, 0, 0, 0);
    a = __builtin_amdgcn_mfma_f32_16x16x32_bf16(a1, *(const bf16x8*)(wrow + 32), a, 0, 0, 0);
    a = __builtin_amdgcn_mfma_f32_16x16x32_bf16(a2, *(const bf16x8*)(wrow + 64), a, 0, 0, 0);
    acc[nf] = a;
  }

  const int mloc = (m0 - mbase) + 16 * wv + 4 * l4;
#pragma unroll
  for (int nf = 0; nf < 6; ++nf) {
    int p = nf * 16 + l15;
    float bv = bias_s[p];
#pragma unroll
    for (int r = 0; r < 4; ++r)
      y[(size_t)(mloc + r) * 2304 + n0 + p] = f2b(acc[nf][r] + bv);
  }
}

// ---------------- QKV pass B: shuffle + head scatter + rel fold (y bf16) -------
__global__ __launch_bounds__(256) void mha_qkv_shuffle(const unsigned short* __restrict__ y,
                                                       const float* __restrict__ rel,
                                                       unsigned short* __restrict__ qb,
                                                       unsigned short* __restrict__ kb,
                                                       unsigned short* __restrict__ vb,
                                                       int mbase, int rows) {
  const int wh = blockIdx.y;
  const int which = wh / H, h = wh - which * H;
  const int basep = which * 96 + h * 8;
  const int tid = threadIdx.x;
  const int lane = tid & 63;
  const int g = lane >> 3, j = lane & 7;
  const int d = j * 8 + g;
  const int rbase = blockIdx.x * 32;
#pragma unroll
  for (int r8 = 0; r8 < 8; ++r8) {
    int rowl = rbase + r8 * 4 + (tid >> 6);
    if (rowl >= rows) continue;
    int m = mbase + rowl;
    int s = m >> 6, b = m & 63;
    float val = b2f(y[(size_t)rowl * 2304 + g * 288 + basep + j]);
    size_t o = (((size_t)b * H + h) * S + s) * D + d;
    if (which == 0) {
      float rv = rel[(size_t)(S - 1 + s) * D + d];
      qb[o] = f2b(0.125f * val + rv);
    } else if (which == 1) {
      float rv = rel[(size_t)(S - 1 + s) * D + d];
      kb[o] = f2b(val + rv);
    } else {
      vb[o] = f2b(val);
    }
  }
}

// ---------------- fused MFMA attention (unchanged from R6) ---------------------
__global__ __launch_bounds__(256) void mha_fattn(
    const unsigned short* __restrict__ qb, const unsigned short* __restrict__ kb,
    const unsigned short* __restrict__ vb, const unsigned short* __restrict__ relb,
    float* __restrict__ context, unsigned short* __restrict__ probs, int bh0) {
  __shared__ __align__(16) unsigned short ldsA[64 * 136 * 2];
  __shared__ __align__(16) unsigned short Vt[64 * 232];
  unsigned short* Qt = ldsA;
  unsigned short* Kt = ldsA + 64 * 136;
  unsigned short* Pt = ldsA;

  const int id = blockIdx.x;
  const int xcd = id & 7;
  const int rr = id >> 3;
  const int stile = rr & 3;
  const int bhl = xcd + 8 * (rr >> 2);
  const int bh = bh0 + bhl;
  const int b_ = bh / H, h_ = bh - b_ * H;
  const int s0 = stile * 64;
  const int tid = threadIdx.x;
  const int lane = tid & 63, w = tid >> 6;
  const int l15 = lane & 15, l4 = lane >> 4;

#pragma unroll
  for (int ii = 0; ii < 2; ++ii) {
    int idx = tid + ii * 256;
    int r = idx >> 3, c = idx & 7;
    int sg = s0 + r;
    u32x4 qv = {0, 0, 0, 0}, rv = {0, 0, 0, 0};
    if (sg < S) {
      qv = *(const u32x4*)(qb + (((size_t)bh * S + sg) << 6) + c * 8);
      rv = *(const u32x4*)(relb + ((size_t)sg << 6) + c * 8);
    }
    *(u32x4*)(Qt + r * 136 + c * 8) = qv;
    *(u32x4*)(Qt + r * 136 + 64 + c * 8) = rv;
  }
  for (int idx = tid; idx < 64 * 232; idx += 256) {
    int t = idx >> 6, d = idx & 63;
    unsigned short v = 0;
    if (t < S) v = vb[(((size_t)bh * S + t) << 6) + d];
    Vt[d * 232 + t] = v;
  }
  __syncthreads();

  const unsigned short* qrow = Qt + (16 * w + l15) * 136 + l4 * 8;
  bf16x8 aq0 = *(const bf16x8*)(qrow);
  bf16x8 aq1 = *(const bf16x8*)(qrow + 32);
  bf16x8 aq2 = *(const bf16x8*)(qrow + 64);
  bf16x8 aq3 = *(const bf16x8*)(qrow + 96);

  f32x4 acc[13];
#pragma unroll
  for (int i = 0; i < 13; ++i) acc[i] = (f32x4){0.f, 0.f, 0.f, 0.f};

#pragma unroll
  for (int tc = 0; tc < 4; ++tc) {
    if (tc) __syncthreads();
    const int t0 = tc * 64;
#pragma unroll
    for (int ii = 0; ii < 2; ++ii) {
      int idx = tid + ii * 256;
      int r = idx >> 3, c = idx & 7;
      int tg = t0 + r;
      u32x4 kv = {0, 0, 0, 0}, rv = {0, 0, 0, 0};
      if (tg < S) {
        kv = *(const u32x4*)(kb + (((size_t)bh * S + tg) << 6) + c * 8);
        rv = *(const u32x4*)(relb + ((size_t)tg << 6) + c * 8);
        rv ^= 0x80008000u;
      }
      *(u32x4*)(Kt + r * 136 + c * 8) = kv;
      *(u32x4*)(Kt + r * 136 + 64 + c * 8) = rv;
    }
    __syncthreads();
#pragma unroll
    for (int tf = 0; tf < 4; ++tf) {
      if (tc == 3 && tf > 0) continue;
      const unsigned short* kbse = Kt + (tf * 16 + l15) * 136 + l4 * 8;
      f32x4 a = acc[tc * 4 + tf];
      a = __builtin_amdgcn_mfma_f32_16x16x32_bf16(aq0, *(const bf16x8*)(kbse), a, 0, 0, 0);
      a = __builtin_amdgcn_mfma_f32_16x16x32_bf16(aq1, *(const bf16x8*)(kbse + 32), a, 0, 0, 0);
      a = __builtin_amdgcn_mfma_f32_16x16x32_bf16(aq2, *(const bf16x8*)(kbse + 64), a, 0, 0, 0);
      a = __builtin_amdgcn_mfma_f32_16x16x32_bf16(aq3, *(const bf16x8*)(kbse + 96), a, 0, 0, 0);
      acc[tc * 4 + tf] = a;
    }
  }

  if (l15 >= 5) acc[12] = (f32x4){-3.0e38f, -3.0e38f, -3.0e38f, -3.0e38f};
  float inv[4];
#pragma unroll
  for (int r = 0; r < 4; ++r) {
    float m = acc[0][r];
#pragma unroll
    for (int tf = 1; tf < 13; ++tf) m = fmaxf(m, acc[tf][r]);
#pragma unroll
    for (int off = 1; off < 16; off <<= 1) m = fmaxf(m, __shfl_xor(m, off, 64));
    float s = 0.f;
#pragma unroll
    for (int tf = 0; tf < 13; ++tf) {
      float e = __expf(acc[tf][r] - m);
      acc[tf][r] = e;
      s += e;
    }
#pragma unroll
    for (int off = 1; off < 16; off <<= 1) s += __shfl_xor(s, off, 64);
    inv[r] = 1.f / s;
  }

  __syncthreads();

#pragma unroll
  for (int tf = 0; tf < 13; ++tf)
#pragma unroll
    for (int r = 0; r < 4; ++r)
      Pt[(16 * w + 4 * l4 + r) * 232 + tf * 16 + l15] = f2b(acc[tf][r] * inv[r]);
  if (l15 < 12) {
#pragma unroll
    for (int r = 0; r < 4; ++r)
      *(unsigned int*)(Pt + (16 * w + 4 * l4 + r) * 232 + 208 + l15 * 2) = 0u;
  }
  __syncthreads();

  for (int idx = tid; idx < 64 * 197; idx += 256) {
    int r2 = idx / 197;
    int t = idx - r2 * 197;
    int sg = s0 + r2;
    if (sg < S) probs[((size_t)bhl * S + sg) * S + t] = Pt[r2 * 232 + t];
  }

  bf16x8 ap[7];
#pragma unroll
  for (int kf = 0; kf < 7; ++kf)
    ap[kf] = *(const bf16x8*)(Pt + (16 * w + l15) * 232 + kf * 32 + l4 * 8);
  f32x4 ov[4];
#pragma unroll
  for (int df = 0; df < 4; ++df) {
    f32x4 o = (f32x4){0.f, 0.f, 0.f, 0.f};
    const unsigned short* vbse = Vt + (df * 16 + l15) * 232 + l4 * 8;
#pragma unroll
    for (int kf = 0; kf < 7; ++kf)
      o = __builtin_amdgcn_mfma_f32_16x16x32_bf16(ap[kf], *(const bf16x8*)(vbse + kf * 32), o, 0, 0, 0);
    ov[df] = o;
  }
#pragma unroll
  for (int df = 0; df < 4; ++df)
#pragma unroll
    for (int r = 0; r < 4; ++r) {
      int sg = s0 + 16 * w + 4 * l4 + r;
      if (sg < S)
        context[((size_t)b_ * S + sg) * E + h_ * 64 + df * 16 + l15] = ov[df][r];
    }
}

// ---------------- avg reduction over heads (streaming) -------------------------
__global__ __launch_bounds__(256) void mha_avgred(const unsigned short* __restrict__ probs,
                                                  float* __restrict__ avg, int b0) {
  const int bs = blockIdx.x;
  const int bl = bs / S, s = bs - bl * S;
  const int t = threadIdx.x;
  if (t >= S) return;
  float acc = 0.f;
#pragma unroll
  for (int h = 0; h < H; ++h)
    acc += b2f(probs[(((size_t)bl * H + h) * S + s) * S + t]);
  avg[(((size_t)(b0 + bl)) * S + s) * S + t] = acc * (1.f / H);
}

// ---------------- LayerNorm over E -------------------------------------------
__global__ __launch_bounds__(256) void mha_ln(const float* __restrict__ x,
                                              const float* __restrict__ g,
                                              const float* __restrict__ bb,
                                              float* __restrict__ y) {
  __shared__ float sm[4];
  const size_t r = blockIdx.x;
  const float* xr = x + r * E;
  const int tid = threadIdx.x;
  float s1 = 0.f, s2 = 0.f;
  for (int i = tid; i < E; i += 256) {
    float v = xr[i];
    s1 += v;
    s2 += v * v;
  }
  s1 = bsum(s1, sm, tid);
  s2 = bsum(s2, sm, tid);
  float mu = s1 * (1.f / E);
  float var = s2 * (1.f / E) - mu * mu;
  float inv = rsqrtf(var + 1e-5f);
  float* yr = y + r * E;
  for (int i = tid; i < E; i += 256) yr[i] = (xr[i] - mu) * inv * g[i] + bb[i];
}

// ---------------- fc1 (768->96) + tanh-gelu, split grid ------------------------
// grid (M/32, 2): 32 rows x 48 cols per block. tx=tid&7 (8 col groups of 6),
// ty=tid>>3 (32 rows). A-reads broadcast across the 8 col threads of a row.
__global__ __launch_bounds__(256) void mha_fc1(const float* __restrict__ ln,
                                               const float* __restrict__ w,
                                               const float* __restrict__ bias,
                                               float* __restrict__ h1) {
  __shared__ float As[32][68];
  __shared__ float Wc[64][52];
  const int m0 = blockIdx.x * 32;
  const int nh = blockIdx.y;       // 0 or 1 -> cols nh*48..nh*48+47
  const int tid = threadIdx.x;
  const int tx = tid & 7, ty = tid >> 3;
  float acc[6] = {};
  for (int k0 = 0; k0 < E; k0 += 64) {
    for (int i = tid; i < 32 * 16; i += 256) {   // 32 rows x 16 float4
      int r = i >> 4, c4 = i & 15;
      float4 v = *reinterpret_cast<const float4*>(&ln[(size_t)(m0 + r) * E + k0 + c4 * 4]);
      As[r][c4 * 4 + 0] = v.x; As[r][c4 * 4 + 1] = v.y;
      As[r][c4 * 4 + 2] = v.z; As[r][c4 * 4 + 3] = v.w;
    }
    for (int i = tid; i < 64 * 12; i += 256) {   // 64 k-rows x 12 float4
      int kk = i / 12, c4 = i - kk * 12;
      float4 v = *reinterpret_cast<const float4*>(
          &w[(size_t)(k0 + kk) * 96 + nh * 48 + c4 * 4]);
      Wc[kk][c4 * 4 + 0] = v.x; Wc[kk][c4 * 4 + 1] = v.y;
      Wc[kk][c4 * 4 + 2] = v.z; Wc[kk][c4 * 4 + 3] = v.w;
    }
    __syncthreads();
    for (int k = 0; k < 64; ++k) {
      float a = As[ty][k];
      float2 w0 = *reinterpret_cast<const float2*>(&Wc[k][tx * 6]);
      float2 w1 = *reinterpret_cast<const float2*>(&Wc[k][tx * 6 + 2]);
      float2 w2 = *reinterpret_cast<const float2*>(&Wc[k][tx * 6 + 4]);
      acc[0] = fmaf(a, w0.x, acc[0]); acc[1] = fmaf(a, w0.y, acc[1]);
      acc[2] = fmaf(a, w1.x, acc[2]); acc[3] = fmaf(a, w1.y, acc[3]);
      acc[4] = fmaf(a, w2.x, acc[4]); acc[5] = fmaf(a, w2.y, acc[5]);
    }
    __syncthreads();
  }
  const int m = m0 + ty;
#pragma unroll
  for (int c = 0; c < 6; ++c) {
    int n = nh * 48 + tx * 6 + c;
    float u = acc[c] + bias[n];
    float gl = 0.5f * u * (1.f + tanhf(0.7978845608028654f * (u + 0.044715f * u * u * u)));
    h1[(size_t)m * 96 + n] = gl;
  }
}

// ---------------- fc2 (96->768) + sigmoid, scale context -----------------------
__global__ __launch_bounds__(256) void mha_fc2(const float* __restrict__ h1,
                                               const float* __restrict__ w,
                                               const float* __restrict__ bias,
                                               const float* __restrict__ context,
                                               float* __restrict__ attn2) {
  __shared__ float Hs[64][97];
  __shared__ float Ws[96][65];
  const int m0 = blockIdx.x * 64;
  const int n0 = blockIdx.y * 64;
  const int tid = threadIdx.x;
  for (int idx = tid; idx < 64 * 96; idx += 256) {
    int m = idx / 96, k = idx - m * 96;
    Hs[m][k] = h1[(size_t)(m0 + m) * 96 + k];
  }
  for (int idx = tid; idx < 96 * 64; idx += 256) {
    int k = idx >> 6, n = idx & 63;
    Ws[k][n] = w[(size_t)k * E + n0 + n];
  }
  __syncthreads();
  const int tx = tid & 15, ty = tid >> 4;
  float acc[4][4] = {};
  for (int k = 0; k < 96; ++k) {
    float a[4], bb[4];
#pragma unroll
    for (int r = 0; r < 4; ++r) a[r] = Hs[ty * 4 + r][k];
#pragma unroll
    for (int c = 0; c < 4; ++c) bb[c] = Ws[k][tx * 4 + c];
#pragma unroll
    for (int r = 0; r < 4; ++r)
#pragma unroll
      for (int c = 0; c < 4; ++c) acc[r][c] = fmaf(a[r], bb[c], acc[r][c]);
  }
#pragma unroll
  for (int r = 0; r < 4; ++r) {
    int m = m0 + ty * 4 + r;
#pragma unroll
    for (int c = 0; c < 4; ++c) {
      int e = n0 + tx * 4 + c;
      float val = acc[r][c] + bias[e];
      float sg = 1.f / (1.f + __expf(-val));
      attn2[(size_t)m * E + e] = context[(size_t)m * E + e] * sg;
    }
  }
}

// ---------------- grouped out projection + bias + transpose to [S,B,E] ---------
__global__ __launch_bounds__(256) void mha_out(const float* __restrict__ attn2,
                                               const float* __restrict__ w,
                                               const float* __restrict__ bias,
                                               float* __restrict__ outp) {
  __shared__ float As[64][97];
  __shared__ float Ws[96][97];
  const int m0 = blockIdx.x * 64;
  const int g = blockIdx.y;
  const int n0 = g * 96;
  const int tid = threadIdx.x;
  for (int idx = tid; idx < 64 * 96; idx += 256) {
    int m = idx / 96, j = idx - m * 96;
    As[m][j] = attn2[(size_t)(m0 + m) * E + g * 96 + j];
  }
  for (int idx = tid; idx < 96 * 96; idx += 256) {
    int n = idx / 96, j = idx - n * 96;
    Ws[n][j] = w[(size_t)(n0 + n) * 96 + j];
  }
  __syncthreads();
  const int tx = tid & 15, ty = tid >> 4;
  float acc[4][6] = {};
  for (int j = 0; j < 96; ++j) {
    float a[4], bb[6];
#pragma unroll
    for (int r = 0; r < 4; ++r) a[r] = As[ty * 4 + r][j];
#pragma unroll
    for (int c = 0; c < 6; ++c) bb[c] = Ws[tx * 6 + c][j];
#pragma unroll
    for (int r = 0; r < 4; ++r)
#pragma unroll
      for (int c = 0; c < 6; ++c) acc[r][c] = fmaf(a[r], bb[c], acc[r][c]);
  }
#pragma unroll
  for (int r = 0; r < 4; ++r) {
    int m = m0 + ty * 4 + r;
    int b = m / S, s = m - b * S;
#pragma unroll
    for (int c = 0; c < 6; ++c) {
      int p = n0 + tx * 6 + c;
      outp[((size_t)s * B + b) * E + p] = acc[r][c] + bias[p];
    }
  }
}

// ---------------- host launcher ------------------------------------------------
extern "C" void kernel_launch(void* const* d_in, const int* in_sizes, int n_in,
                              void* d_out, int out_size, void* d_ws, size_t ws_size,
                              hipStream_t stream) {
  const float* query = (const float*)d_in[0];
  const float* qkv_w = (const float*)d_in[3];
  const float* qkv_b = (const float*)d_in[4];
  const float* out_w = (const float*)d_in[5];
  const float* out_b = (const float*)d_in[6];
  const float* rel   = (const float*)d_in[7];
  const float* ln_g  = (const float*)d_in[8];
  const float* ln_b  = (const float*)d_in[9];
  const float* fc1_w = (const float*)d_in[10];
  const float* fc1_b = (const float*)d_in[11];
  const float* fc2_w = (const float*)d_in[12];
  const float* fc2_b = (const float*)d_in[13];

  float* ws = (float*)d_ws;
  unsigned short* qb   = (unsigned short*)ws;      // SBE bf16
  unsigned short* kbuf = qb + SBE;                 // SBE bf16
  unsigned short* vbb  = kbuf + SBE;               // SBE bf16
  unsigned short* relb = vbb + SBE;                // 256*64 bf16
  size_t off = 3 * SBE / 2 + 8192;                 // floats consumed so far
  float* context = ws + off;                       // SBE f32 (y chunk aliases)
  unsigned short* ybuf = (unsigned short*)context; // bf16 chunk [CH][2304]
  float* lnbuf   = ws + off + SBE;                 // SBE f32 (attn2 aliases)
  float* attn2   = lnbuf;
  float* h1      = ws + off + 2 * SBE;             // M*96 f32
  unsigned short* probsb = (unsigned short*)(ws + off + 2 * SBE + (size_t)M * 96);
  float* outp = (float*)d_out;
  float* avgp = outp + SBE;

  // probs chunk size (bf16)
  size_t used_f = off + 2 * SBE + (size_t)M * 96;
  size_t avail_f = (ws_size / 4 > used_f) ? ws_size / 4 - used_f : 0;
  int Bc = 2;
  const int cand[6] = {64, 32, 16, 8, 4, 2};
  for (int i = 0; i < 6; ++i) {
    size_t need_f = ((size_t)cand[i] * H * S * S + 1) / 2;
    if (need_f <= avail_f) { Bc = cand[i]; break; }
  }

  mha_relb<<<64, 256, 0, stream>>>(rel, relb);

  const int CH = 6400;  // CH*2304 bf16 fits in the SBE f32 region
  for (int mbase = 0; mbase < M; mbase += CH) {
    int rows = (M - mbase < CH) ? (M - mbase) : CH;
    mha_qkv_gemm<<<dim3(rows / 64, 24), 256, 0, stream>>>(query, qkv_w, qkv_b, ybuf,
                                                          mbase, rows);
    mha_qkv_shuffle<<<dim3(rows / 32, 36), 256, 0, stream>>>(ybuf, rel, qb, kbuf,
                                                             vbb, mbase, rows);
  }

  for (int b0 = 0; b0 < B; b0 += Bc) {
    int bc = (B - b0 < Bc) ? (B - b0) : Bc;
    int nbh = bc * H;
    mha_fattn<<<4 * nbh, 256, 0, stream>>>(qb, kbuf, vbb, relb, context, probsb,
                                           b0 * H);
    mha_avgred<<<bc * S, 256, 0, stream>>>(probsb, avgp, b0);
  }

  mha_ln<<<M, 256, 0, stream>>>(context, ln_g, ln_b, lnbuf);
  mha_fc1<<<dim3(M / 32, 2), 256, 0, stream>>>(lnbuf, fc1_w, fc1_b, h1);
  mha_fc2<<<dim3(M / 64, 12), 256, 0, stream>>>(h1, fc2_w, fc2_b, context, attn2);
  mha_out<<<dim3(M / 64, 8), 256, 0, stream>>>(attn2, out_w, out_b, outp);
}

// Round 8
// 397.789 us; speedup vs baseline: 16.4153x; 1.2700x over previous
//
#include <hip/hip_runtime.h>
#include <hip/hip_bf16.h>

// ---------------- constants ----------------
constexpr int S = 197;
constexpr int B = 64;
constexpr int E = 768;
constexpr int H = 12;
constexpr int D = 64;
constexpr int M = S * B;                  // 12608 rows
constexpr size_t SBE = (size_t)M * E;     // 9,682,944 (= B*H*S*D too)
constexpr int PST = 208;                  // probs row stride (26 x 8)

typedef short bf16x8 __attribute__((ext_vector_type(8)));
typedef float f32x4 __attribute__((ext_vector_type(4)));
typedef unsigned int u32x4 __attribute__((ext_vector_type(4)));

__device__ __forceinline__ unsigned short f2b(float x) {  // f32 -> bf16 (RNE)
  unsigned int u = __float_as_uint(x);
  return (unsigned short)((u + 0x7FFFu + ((u >> 16) & 1u)) >> 16);
}
__device__ __forceinline__ float b2f(unsigned short u) {
  return __uint_as_float((unsigned int)u << 16);
}

// ---------------- relb: bf16 rel rows (rel[196+s][d]), zero-padded to 256 ------
__global__ __launch_bounds__(256) void mha_relb(const float* __restrict__ rel,
                                                unsigned short* __restrict__ relb) {
  int idx = blockIdx.x * 256 + threadIdx.x;
  if (idx >= 256 * 64) return;
  int s2 = idx >> 6, d = idx & 63;
  float v = (s2 < S) ? rel[(size_t)(S - 1 + s2) * D + d] : 0.f;
  relb[idx] = f2b(v);
}

// ---------------- QKV grouped GEMM (MFMA bf16), y out bf16 ---------------------
__global__ __launch_bounds__(256) void mha_qkv_gemm(const float* __restrict__ x,
                                                    const float* __restrict__ w,
                                                    const float* __restrict__ bias,
                                                    unsigned short* __restrict__ y,
                                                    int mbase, int rows) {
  __shared__ __align__(16) unsigned short Xs[64 * 104];
  __shared__ __align__(16) unsigned short Wsl[96 * 104];
  __shared__ float bias_s[96];
  const int m0 = mbase + blockIdx.x * 64;
  const int n0 = blockIdx.y * 96;
  const int g = blockIdx.y / 3;
  const int tid = threadIdx.x;

  for (int i = tid; i < 64 * 24; i += 256) {
    int r = i / 24, c4 = i - r * 24;
    float4 v = *reinterpret_cast<const float4*>(
        &x[(size_t)(m0 + r) * E + g * 96 + c4 * 4]);
    unsigned short* dst = Xs + r * 104 + c4 * 4;
    dst[0] = f2b(v.x); dst[1] = f2b(v.y); dst[2] = f2b(v.z); dst[3] = f2b(v.w);
  }
  for (int i = tid; i < 96 * 24; i += 256) {
    int n = i / 24, c4 = i - n * 24;
    float4 v = *reinterpret_cast<const float4*>(&w[(size_t)(n0 + n) * 96 + c4 * 4]);
    unsigned short* dst = Wsl + n * 104 + c4 * 4;
    dst[0] = f2b(v.x); dst[1] = f2b(v.y); dst[2] = f2b(v.z); dst[3] = f2b(v.w);
  }
  if (tid < 96) bias_s[tid] = bias[n0 + tid];
  __syncthreads();

  const int lane = tid & 63, wv = tid >> 6;
  const int l15 = lane & 15, l4 = lane >> 4;

  const unsigned short* xrow = Xs + (16 * wv + l15) * 104 + l4 * 8;
  bf16x8 a0 = *(const bf16x8*)(xrow);
  bf16x8 a1 = *(const bf16x8*)(xrow + 32);
  bf16x8 a2 = *(const bf16x8*)(xrow + 64);

  f32x4 acc[6];
#pragma unroll
  for (int nf = 0; nf < 6; ++nf) acc[nf] = (f32x4){0.f, 0.f, 0.f, 0.f};
#pragma unroll
  for (int nf = 0; nf < 6; ++nf) {
    const unsigned short* wrow = Wsl + (nf * 16 + l15) * 104 + l4 * 8;
    f32x4 a = acc[nf];
    a = __builtin_amdgcn_mfma_f32_16x16x32_bf16(a0, *(const bf16x8*)(wrow), a, 0, 0, 0);
    a = __builtin_amdgcn_mfma_f32_16x16x32_bf16(a1, *(const bf16x8*)(wrow + 32), a, 0, 0, 0);
    a = __builtin_amdgcn_mfma_f32_16x16x32_bf16(a2, *(const bf16x8*)(wrow + 64), a, 0, 0, 0);
    acc[nf] = a;
  }

  const int mloc = (m0 - mbase) + 16 * wv + 4 * l4;
#pragma unroll
  for (int nf = 0; nf < 6; ++nf) {
    int p = nf * 16 + l15;
    float bv = bias_s[p];
#pragma unroll
    for (int r = 0; r < 4; ++r)
      y[(size_t)(mloc + r) * 2304 + n0 + p] = f2b(acc[nf][r] + bv);
  }
}

// ---------------- QKV pass B: shuffle + head scatter + rel fold (y bf16) -------
__global__ __launch_bounds__(256) void mha_qkv_shuffle(const unsigned short* __restrict__ y,
                                                       const float* __restrict__ rel,
                                                       unsigned short* __restrict__ qb,
                                                       unsigned short* __restrict__ kb,
                                                       unsigned short* __restrict__ vb,
                                                       int mbase, int rows) {
  const int wh = blockIdx.y;
  const int which = wh / H, h = wh - which * H;
  const int basep = which * 96 + h * 8;
  const int tid = threadIdx.x;
  const int lane = tid & 63;
  const int g = lane >> 3, j = lane & 7;
  const int d = j * 8 + g;
  const int rbase = blockIdx.x * 32;
#pragma unroll
  for (int r8 = 0; r8 < 8; ++r8) {
    int rowl = rbase + r8 * 4 + (tid >> 6);
    if (rowl >= rows) continue;
    int m = mbase + rowl;
    int s = m >> 6, b = m & 63;
    float val = b2f(y[(size_t)rowl * 2304 + g * 288 + basep + j]);
    size_t o = (((size_t)b * H + h) * S + s) * D + d;
    if (which == 0) {
      float rv = rel[(size_t)(S - 1 + s) * D + d];
      qb[o] = f2b(0.125f * val + rv);
    } else if (which == 1) {
      float rv = rel[(size_t)(S - 1 + s) * D + d];
      kb[o] = f2b(val + rv);
    } else {
      vb[o] = f2b(val);
    }
  }
}

// ---------------- fused MFMA attention (streamlined) ---------------------------
// grid 4*nbh XCD-swizzled. No Qt staging (direct global A-frags; garbage rows
// >=S are row-contained in MFMA and masked at every consumer). Vectorized Vt
// staging and probs dump (stride PST=208).
__global__ __launch_bounds__(256) void mha_fattn(
    const unsigned short* __restrict__ qb, const unsigned short* __restrict__ kb,
    const unsigned short* __restrict__ vb, const unsigned short* __restrict__ relb,
    float* __restrict__ context, unsigned short* __restrict__ probs, int bh0) {
  __shared__ __align__(16) unsigned short KtPt[64 * 232];  // Kt (stride 136) / Pt (232)
  __shared__ __align__(16) unsigned short Vt[64 * 232];    // V^T [d][t]
  unsigned short* Kt = KtPt;
  unsigned short* Pt = KtPt;

  const int id = blockIdx.x;
  const int xcd = id & 7;
  const int rr = id >> 3;
  const int stile = rr & 3;
  const int bhl = xcd + 8 * (rr >> 2);
  const int bh = bh0 + bhl;
  const int b_ = bh / H, h_ = bh - b_ * H;
  const int s0 = stile * 64;
  const int tid = threadIdx.x;
  const int lane = tid & 63, w = tid >> 6;
  const int l15 = lane & 15, l4 = lane >> 4;

  // ---- stage Vt [d][t] (vector global loads, scalar transposed writes) ----
#pragma unroll
  for (int tt = 0; tt < 224; tt += 32) {
    int t = tt + (tid & 31);
    int d0 = (tid >> 5) * 8;
    u32x4 v = {0, 0, 0, 0};
    if (t < S) v = *(const u32x4*)(vb + (((size_t)bh * S + t) << 6) + d0);
    const unsigned short* vp = (const unsigned short*)&v;
#pragma unroll
    for (int j = 0; j < 8; ++j) Vt[(d0 + j) * 232 + t] = vp[j];
  }

  // ---- direct-global Q A-frags (row s0+16w+l15; rows >= S read garbage, safe) --
  const unsigned short* qg = qb + (((size_t)bh * S + (s0 + 16 * w + l15)) << 6) + l4 * 8;
  const unsigned short* rg = relb + (((size_t)(s0 + 16 * w + l15)) << 6) + l4 * 8;
  bf16x8 aq0 = *(const bf16x8*)(qg);
  bf16x8 aq1 = *(const bf16x8*)(qg + 32);
  bf16x8 aq2 = *(const bf16x8*)(rg);
  bf16x8 aq3 = *(const bf16x8*)(rg + 32);

  f32x4 acc[13];
#pragma unroll
  for (int i = 0; i < 13; ++i) acc[i] = (f32x4){0.f, 0.f, 0.f, 0.f};

  // ---- QK^T over 4 t-chunks of 64 ----
#pragma unroll
  for (int tc = 0; tc < 4; ++tc) {
    const int t0 = tc * 64;
#pragma unroll
    for (int ii = 0; ii < 2; ++ii) {
      int idx = tid + ii * 256;
      int r = idx >> 3, c = idx & 7;
      int tg = t0 + r;
      u32x4 kv = {0, 0, 0, 0}, rv = {0, 0, 0, 0};
      if (tg < S) {
        kv = *(const u32x4*)(kb + (((size_t)bh * S + tg) << 6) + c * 8);
        rv = *(const u32x4*)(relb + ((size_t)tg << 6) + c * 8);
        rv ^= 0x80008000u;  // negate rel on K side
      }
      *(u32x4*)(Kt + r * 136 + c * 8) = kv;
      *(u32x4*)(Kt + r * 136 + 64 + c * 8) = rv;
    }
    __syncthreads();
#pragma unroll
    for (int tf = 0; tf < 4; ++tf) {
      if (tc == 3 && tf > 0) continue;  // t >= 208 not needed
      const unsigned short* kbse = Kt + (tf * 16 + l15) * 136 + l4 * 8;
      f32x4 a = acc[tc * 4 + tf];
      a = __builtin_amdgcn_mfma_f32_16x16x32_bf16(aq0, *(const bf16x8*)(kbse), a, 0, 0, 0);
      a = __builtin_amdgcn_mfma_f32_16x16x32_bf16(aq1, *(const bf16x8*)(kbse + 32), a, 0, 0, 0);
      a = __builtin_amdgcn_mfma_f32_16x16x32_bf16(aq2, *(const bf16x8*)(kbse + 64), a, 0, 0, 0);
      a = __builtin_amdgcn_mfma_f32_16x16x32_bf16(aq3, *(const bf16x8*)(kbse + 96), a, 0, 0, 0);
      acc[tc * 4 + tf] = a;
    }
    __syncthreads();  // protect Kt restage (and, after tc=3, the Pt overlay)
  }

  // ---- softmax in registers (col=l15 -> t, row=4*l4+r -> s) ----
  if (l15 >= 5) acc[12] = (f32x4){-3.0e38f, -3.0e38f, -3.0e38f, -3.0e38f};
  float inv[4];
#pragma unroll
  for (int r = 0; r < 4; ++r) {
    float m = acc[0][r];
#pragma unroll
    for (int tf = 1; tf < 13; ++tf) m = fmaxf(m, acc[tf][r]);
#pragma unroll
    for (int off = 1; off < 16; off <<= 1) m = fmaxf(m, __shfl_xor(m, off, 64));
    float s = 0.f;
#pragma unroll
    for (int tf = 0; tf < 13; ++tf) {
      float e = __expf(acc[tf][r] - m);
      acc[tf][r] = e;
      s += e;
    }
#pragma unroll
    for (int off = 1; off < 16; off <<= 1) s += __shfl_xor(s, off, 64);
    inv[r] = 1.f / s;
  }

  // ---- write P (bf16) to Pt [64][232], zero pad cols 208..231 ----
#pragma unroll
  for (int tf = 0; tf < 13; ++tf)
#pragma unroll
    for (int r = 0; r < 4; ++r)
      Pt[(16 * w + 4 * l4 + r) * 232 + tf * 16 + l15] = f2b(acc[tf][r] * inv[r]);
  if (l15 < 12) {
#pragma unroll
    for (int r = 0; r < 4; ++r)
      *(unsigned int*)(Pt + (16 * w + 4 * l4 + r) * 232 + 208 + l15 * 2) = 0u;
  }
  __syncthreads();

  // ---- vectorized probs dump: rows tid>>2, col chunks (tid&3)+4j ----
  {
    const int r2 = tid >> 2;
    const int sg = s0 + r2;
#pragma unroll
    for (int j = 0; j < 7; ++j) {
      int c = (tid & 3) + 4 * j;
      if (c < 26 && sg < S) {
        u32x4 pv = *(const u32x4*)(Pt + r2 * 232 + c * 8);
        *(u32x4*)(probs + ((size_t)bhl * S + sg) * PST + c * 8) = pv;
      }
    }
  }

  // ---- PV ----
  bf16x8 ap[7];
#pragma unroll
  for (int kf = 0; kf < 7; ++kf)
    ap[kf] = *(const bf16x8*)(Pt + (16 * w + l15) * 232 + kf * 32 + l4 * 8);
  f32x4 ov[4];
#pragma unroll
  for (int df = 0; df < 4; ++df) {
    f32x4 o = (f32x4){0.f, 0.f, 0.f, 0.f};
    const unsigned short* vbse = Vt + (df * 16 + l15) * 232 + l4 * 8;
#pragma unroll
    for (int kf = 0; kf < 7; ++kf)
      o = __builtin_amdgcn_mfma_f32_16x16x32_bf16(ap[kf], *(const bf16x8*)(vbse + kf * 32), o, 0, 0, 0);
    ov[df] = o;
  }
#pragma unroll
  for (int df = 0; df < 4; ++df)
#pragma unroll
    for (int r = 0; r < 4; ++r) {
      int sg = s0 + 16 * w + 4 * l4 + r;
      if (sg < S)
        context[((size_t)b_ * S + sg) * E + h_ * 64 + df * 16 + l15] = ov[df][r];
    }
}

// ---------------- avg reduction over heads (streaming, stride PST) -------------
__global__ __launch_bounds__(256) void mha_avgred(const unsigned short* __restrict__ probs,
                                                  float* __restrict__ avg, int b0) {
  const int bs = blockIdx.x;
  const int bl = bs / S, s = bs - bl * S;
  const int t = threadIdx.x;
  if (t >= S) return;
  float acc = 0.f;
#pragma unroll
  for (int h = 0; h < H; ++h)
    acc += b2f(probs[(((size_t)bl * H + h) * S + s) * PST + t]);
  avg[(((size_t)(b0 + bl)) * S + s) * S + t] = acc * (1.f / H);
}

// ---------------- fused LayerNorm + fc1 (768->96) + tanh-gelu ------------------
// grid (M/32, 2). Phase 1: per-row stats (8 lanes/row, shfl reduce).
// Phase 2: GEMM with normalization applied while loading A to LDS.
__global__ __launch_bounds__(256) void mha_fc1ln(const float* __restrict__ ctx,
                                                 const float* __restrict__ lng,
                                                 const float* __restrict__ lnb,
                                                 const float* __restrict__ w,
                                                 const float* __restrict__ bias,
                                                 float* __restrict__ h1) {
  __shared__ float As[32][68];
  __shared__ float Wc[64][52];
  __shared__ float smu[32], sinv[32];
  const int m0 = blockIdx.x * 32;
  const int nh = blockIdx.y;
  const int tid = threadIdx.x;
  const int tx = tid & 7, ty = tid >> 3;

  // phase 1: stats
  {
    const float* xr = ctx + (size_t)(m0 + ty) * E + tx * 96;
    float s1 = 0.f, s2 = 0.f;
#pragma unroll
    for (int c4 = 0; c4 < 24; ++c4) {
      float4 v = *reinterpret_cast<const float4*>(xr + c4 * 4);
      s1 += v.x + v.y + v.z + v.w;
      s2 += v.x * v.x + v.y * v.y + v.z * v.z + v.w * v.w;
    }
#pragma unroll
    for (int off = 1; off < 8; off <<= 1) {
      s1 += __shfl_xor(s1, off, 64);
      s2 += __shfl_xor(s2, off, 64);
    }
    float mu = s1 * (1.f / E);
    float var = s2 * (1.f / E) - mu * mu;
    if (tx == 0) { smu[ty] = mu; sinv[ty] = rsqrtf(var + 1e-5f); }
  }
  __syncthreads();

  float acc[6] = {};
  for (int k0 = 0; k0 < E; k0 += 64) {
    for (int i = tid; i < 32 * 16; i += 256) {
      int r = i >> 4, c4 = i & 15;
      float4 v = *reinterpret_cast<const float4*>(&ctx[(size_t)(m0 + r) * E + k0 + c4 * 4]);
      float4 gg = *reinterpret_cast<const float4*>(&lng[k0 + c4 * 4]);
      float4 bb = *reinterpret_cast<const float4*>(&lnb[k0 + c4 * 4]);
      float mu = smu[r], iv = sinv[r];
      As[r][c4 * 4 + 0] = (v.x - mu) * iv * gg.x + bb.x;
      As[r][c4 * 4 + 1] = (v.y - mu) * iv * gg.y + bb.y;
      As[r][c4 * 4 + 2] = (v.z - mu) * iv * gg.z + bb.z;
      As[r][c4 * 4 + 3] = (v.w - mu) * iv * gg.w + bb.w;
    }
    for (int i = tid; i < 64 * 12; i += 256) {
      int kk = i / 12, c4 = i - kk * 12;
      float4 v = *reinterpret_cast<const float4*>(
          &w[(size_t)(k0 + kk) * 96 + nh * 48 + c4 * 4]);
      Wc[kk][c4 * 4 + 0] = v.x; Wc[kk][c4 * 4 + 1] = v.y;
      Wc[kk][c4 * 4 + 2] = v.z; Wc[kk][c4 * 4 + 3] = v.w;
    }
    __syncthreads();
    for (int k = 0; k < 64; ++k) {
      float a = As[ty][k];
      float2 w0 = *reinterpret_cast<const float2*>(&Wc[k][tx * 6]);
      float2 w1 = *reinterpret_cast<const float2*>(&Wc[k][tx * 6 + 2]);
      float2 w2 = *reinterpret_cast<const float2*>(&Wc[k][tx * 6 + 4]);
      acc[0] = fmaf(a, w0.x, acc[0]); acc[1] = fmaf(a, w0.y, acc[1]);
      acc[2] = fmaf(a, w1.x, acc[2]); acc[3] = fmaf(a, w1.y, acc[3]);
      acc[4] = fmaf(a, w2.x, acc[4]); acc[5] = fmaf(a, w2.y, acc[5]);
    }
    __syncthreads();
  }
  const int m = m0 + ty;
#pragma unroll
  for (int c = 0; c < 6; ++c) {
    int n = nh * 48 + tx * 6 + c;
    float u = acc[c] + bias[n];
    float gl = 0.5f * u * (1.f + tanhf(0.7978845608028654f * (u + 0.044715f * u * u * u)));
    h1[(size_t)m * 96 + n] = gl;
  }
}

// ---------------- fc2 (96->768) + sigmoid, scale context -----------------------
__global__ __launch_bounds__(256) void mha_fc2(const float* __restrict__ h1,
                                               const float* __restrict__ w,
                                               const float* __restrict__ bias,
                                               const float* __restrict__ context,
                                               float* __restrict__ attn2) {
  __shared__ float Hs[64][97];
  __shared__ float Ws[96][65];
  const int m0 = blockIdx.x * 64;
  const int n0 = blockIdx.y * 64;
  const int tid = threadIdx.x;
  for (int idx = tid; idx < 64 * 96; idx += 256) {
    int m = idx / 96, k = idx - m * 96;
    Hs[m][k] = h1[(size_t)(m0 + m) * 96 + k];
  }
  for (int idx = tid; idx < 96 * 64; idx += 256) {
    int k = idx >> 6, n = idx & 63;
    Ws[k][n] = w[(size_t)k * E + n0 + n];
  }
  __syncthreads();
  const int tx = tid & 15, ty = tid >> 4;
  float acc[4][4] = {};
  for (int k = 0; k < 96; ++k) {
    float a[4], bb[4];
#pragma unroll
    for (int r = 0; r < 4; ++r) a[r] = Hs[ty * 4 + r][k];
#pragma unroll
    for (int c = 0; c < 4; ++c) bb[c] = Ws[k][tx * 4 + c];
#pragma unroll
    for (int r = 0; r < 4; ++r)
#pragma unroll
      for (int c = 0; c < 4; ++c) acc[r][c] = fmaf(a[r], bb[c], acc[r][c]);
  }
#pragma unroll
  for (int r = 0; r < 4; ++r) {
    int m = m0 + ty * 4 + r;
#pragma unroll
    for (int c = 0; c < 4; ++c) {
      int e = n0 + tx * 4 + c;
      float val = acc[r][c] + bias[e];
      float sg = 1.f / (1.f + __expf(-val));
      attn2[(size_t)m * E + e] = context[(size_t)m * E + e] * sg;
    }
  }
}

// ---------------- grouped out projection + bias + transpose to [S,B,E] ---------
__global__ __launch_bounds__(256) void mha_out(const float* __restrict__ attn2,
                                               const float* __restrict__ w,
                                               const float* __restrict__ bias,
                                               float* __restrict__ outp) {
  __shared__ float As[64][97];
  __shared__ float Ws[96][97];
  const int m0 = blockIdx.x * 64;
  const int g = blockIdx.y;
  const int n0 = g * 96;
  const int tid = threadIdx.x;
  for (int idx = tid; idx < 64 * 96; idx += 256) {
    int m = idx / 96, j = idx - m * 96;
    As[m][j] = attn2[(size_t)(m0 + m) * E + g * 96 + j];
  }
  for (int idx = tid; idx < 96 * 96; idx += 256) {
    int n = idx / 96, j = idx - n * 96;
    Ws[n][j] = w[(size_t)(n0 + n) * 96 + j];
  }
  __syncthreads();
  const int tx = tid & 15, ty = tid >> 4;
  float acc[4][6] = {};
  for (int j = 0; j < 96; ++j) {
    float a[4], bb[6];
#pragma unroll
    for (int r = 0; r < 4; ++r) a[r] = As[ty * 4 + r][j];
#pragma unroll
    for (int c = 0; c < 6; ++c) bb[c] = Ws[tx * 6 + c][j];
#pragma unroll
    for (int r = 0; r < 4; ++r)
#pragma unroll
      for (int c = 0; c < 6; ++c) acc[r][c] = fmaf(a[r], bb[c], acc[r][c]);
  }
#pragma unroll
  for (int r = 0; r < 4; ++r) {
    int m = m0 + ty * 4 + r;
    int b = m / S, s = m - b * S;
#pragma unroll
    for (int c = 0; c < 6; ++c) {
      int p = n0 + tx * 6 + c;
      outp[((size_t)s * B + b) * E + p] = acc[r][c] + bias[p];
    }
  }
}

// ---------------- host launcher ------------------------------------------------
extern "C" void kernel_launch(void* const* d_in, const int* in_sizes, int n_in,
                              void* d_out, int out_size, void* d_ws, size_t ws_size,
                              hipStream_t stream) {
  const float* query = (const float*)d_in[0];
  const float* qkv_w = (const float*)d_in[3];
  const float* qkv_b = (const float*)d_in[4];
  const float* out_w = (const float*)d_in[5];
  const float* out_b = (const float*)d_in[6];
  const float* rel   = (const float*)d_in[7];
  const float* ln_g  = (const float*)d_in[8];
  const float* ln_b  = (const float*)d_in[9];
  const float* fc1_w = (const float*)d_in[10];
  const float* fc1_b = (const float*)d_in[11];
  const float* fc2_w = (const float*)d_in[12];
  const float* fc2_b = (const float*)d_in[13];

  float* ws = (float*)d_ws;
  unsigned short* qb   = (unsigned short*)ws;      // SBE bf16
  unsigned short* kbuf = qb + SBE;                 // SBE bf16
  unsigned short* vbb  = kbuf + SBE;               // SBE bf16
  unsigned short* relb = vbb + SBE;                // 256*64 bf16
  size_t off = 3 * SBE / 2 + 8192;                 // floats consumed so far
  float* context = ws + off;                       // SBE f32 (y chunk aliases)
  unsigned short* ybuf = (unsigned short*)context; // bf16 chunk [CH][2304]
  float* attn2   = ws + off + SBE;                 // SBE f32
  float* h1      = ws + off + 2 * SBE;             // M*96 f32
  unsigned short* probsb = (unsigned short*)(ws + off + 2 * SBE + (size_t)M * 96);
  float* outp = (float*)d_out;
  float* avgp = outp + SBE;

  // probs chunk size (bf16, row stride PST)
  size_t used_f = off + 2 * SBE + (size_t)M * 96;
  size_t avail_f = (ws_size / 4 > used_f) ? ws_size / 4 - used_f : 0;
  int Bc = 2;
  const int cand[6] = {64, 32, 16, 8, 4, 2};
  for (int i = 0; i < 6; ++i) {
    size_t need_f = ((size_t)cand[i] * H * S * PST + 1) / 2;
    if (need_f <= avail_f) { Bc = cand[i]; break; }
  }

  mha_relb<<<64, 256, 0, stream>>>(rel, relb);

  const int CH = 6400;  // CH*2304 bf16 fits in the SBE f32 region
  for (int mbase = 0; mbase < M; mbase += CH) {
    int rows = (M - mbase < CH) ? (M - mbase) : CH;
    mha_qkv_gemm<<<dim3(rows / 64, 24), 256, 0, stream>>>(query, qkv_w, qkv_b, ybuf,
                                                          mbase, rows);
    mha_qkv_shuffle<<<dim3(rows / 32, 36), 256, 0, stream>>>(ybuf, rel, qb, kbuf,
                                                             vbb, mbase, rows);
  }

  for (int b0 = 0; b0 < B; b0 += Bc) {
    int bc = (B - b0 < Bc) ? (B - b0) : Bc;
    int nbh = bc * H;
    mha_fattn<<<4 * nbh, 256, 0, stream>>>(qb, kbuf, vbb, relb, context, probsb,
                                           b0 * H);
    mha_avgred<<<bc * S, 256, 0, stream>>>(probsb, avgp, b0);
  }

  mha_fc1ln<<<dim3(M / 32, 2), 256, 0, stream>>>(context, ln_g, ln_b, fc1_w, fc1_b, h1);
  mha_fc2<<<dim3(M / 64, 12), 256, 0, stream>>>(h1, fc2_w, fc2_b, context, attn2);
  mha_out<<<dim3(M / 64, 8), 256, 0, stream>>>(attn2, out_w, out_b, outp);
}

// Round 9
// 304.114 us; speedup vs baseline: 21.4716x; 1.3080x over previous
//
#include <hip/hip_runtime.h>
#include <hip/hip_bf16.h>

// ---------------- constants ----------------
constexpr int S = 197;
constexpr int B = 64;
constexpr int E = 768;
constexpr int H = 12;
constexpr int D = 64;
constexpr int M = S * B;                  // 12608 rows
constexpr size_t SBE = (size_t)M * E;     // 9,682,944
constexpr int PST = 208;                  // probs row stride

typedef short bf16x8 __attribute__((ext_vector_type(8)));
typedef float f32x4 __attribute__((ext_vector_type(4)));
typedef unsigned int u32x4 __attribute__((ext_vector_type(4)));

__device__ __forceinline__ unsigned short f2b(float x) {  // f32 -> bf16 (RNE)
  unsigned int u = __float_as_uint(x);
  return (unsigned short)((u + 0x7FFFu + ((u >> 16) & 1u)) >> 16);
}
__device__ __forceinline__ float b2f(unsigned short u) {
  return __uint_as_float((unsigned int)u << 16);
}

// ---------------- relb: bf16 rel rows, zero-padded to 256 ----------------------
__global__ __launch_bounds__(256) void mha_relb(const float* __restrict__ rel,
                                                unsigned short* __restrict__ relb) {
  int idx = blockIdx.x * 256 + threadIdx.x;
  if (idx >= 256 * 64) return;
  int s2 = idx >> 6, d = idx & 63;
  float v = (s2 < S) ? rel[(size_t)(S - 1 + s2) * D + d] : 0.f;
  relb[idx] = f2b(v);
}

// ---------------- wprep: transposed bf16 weights + LN-fold constants -----------
// w1t[n][k] = g_k * fc1_w[k][n] (bf16, [96][768]); w2t[n][k] = fc2_w[k][n]
// ([768][96]); cg_n = sum_k g_k w1[k][n]; cb_n = sum_k beta_k w1[k][n] + b1_n.
__global__ __launch_bounds__(256) void mha_wprep(const float* __restrict__ w1,
                                                 const float* __restrict__ w2,
                                                 const float* __restrict__ lng,
                                                 const float* __restrict__ lnb,
                                                 const float* __restrict__ b1,
                                                 unsigned short* __restrict__ w1t,
                                                 unsigned short* __restrict__ w2t,
                                                 float* __restrict__ cgb,
                                                 float* __restrict__ cbb) {
  const int bid = blockIdx.x, tid = threadIdx.x;
  if (bid < 288) {
    int idx = bid * 256 + tid;
    int n = idx / 768, k = idx - n * 768;
    w1t[idx] = f2b(lng[k] * w1[(size_t)k * 96 + n]);
  } else if (bid < 576) {
    int idx = (bid - 288) * 256 + tid;
    int n = idx / 96, k = idx - n * 96;
    w2t[idx] = f2b(w2[(size_t)k * 768 + n]);
  } else if (tid < 96) {
    float cg = 0.f, cb = 0.f;
    for (int k = 0; k < 768; ++k) {
      float wv = w1[(size_t)k * 96 + tid];
      cg += lng[k] * wv;
      cb += lnb[k] * wv;
    }
    cgb[tid] = cg;
    cbb[tid] = cb + b1[tid];
  }
}

// ---------------- QKV grouped GEMM (MFMA bf16), y out bf16 ---------------------
__global__ __launch_bounds__(256) void mha_qkv_gemm(const float* __restrict__ x,
                                                    const float* __restrict__ w,
                                                    const float* __restrict__ bias,
                                                    unsigned short* __restrict__ y,
                                                    int mbase, int rows) {
  __shared__ __align__(16) unsigned short Xs[64 * 104];
  __shared__ __align__(16) unsigned short Wsl[96 * 104];
  __shared__ float bias_s[96];
  const int m0 = mbase + blockIdx.x * 64;
  const int n0 = blockIdx.y * 96;
  const int g = blockIdx.y / 3;
  const int tid = threadIdx.x;

  for (int i = tid; i < 64 * 24; i += 256) {
    int r = i / 24, c4 = i - r * 24;
    float4 v = *reinterpret_cast<const float4*>(
        &x[(size_t)(m0 + r) * E + g * 96 + c4 * 4]);
    unsigned short* dst = Xs + r * 104 + c4 * 4;
    dst[0] = f2b(v.x); dst[1] = f2b(v.y); dst[2] = f2b(v.z); dst[3] = f2b(v.w);
  }
  for (int i = tid; i < 96 * 24; i += 256) {
    int n = i / 24, c4 = i - n * 24;
    float4 v = *reinterpret_cast<const float4*>(&w[(size_t)(n0 + n) * 96 + c4 * 4]);
    unsigned short* dst = Wsl + n * 104 + c4 * 4;
    dst[0] = f2b(v.x); dst[1] = f2b(v.y); dst[2] = f2b(v.z); dst[3] = f2b(v.w);
  }
  if (tid < 96) bias_s[tid] = bias[n0 + tid];
  __syncthreads();

  const int lane = tid & 63, wv = tid >> 6;
  const int l15 = lane & 15, l4 = lane >> 4;

  const unsigned short* xrow = Xs + (16 * wv + l15) * 104 + l4 * 8;
  bf16x8 a0 = *(const bf16x8*)(xrow);
  bf16x8 a1 = *(const bf16x8*)(xrow + 32);
  bf16x8 a2 = *(const bf16x8*)(xrow + 64);

  f32x4 acc[6];
#pragma unroll
  for (int nf = 0; nf < 6; ++nf) acc[nf] = (f32x4){0.f, 0.f, 0.f, 0.f};
#pragma unroll
  for (int nf = 0; nf < 6; ++nf) {
    const unsigned short* wrow = Wsl + (nf * 16 + l15) * 104 + l4 * 8;
    f32x4 a = acc[nf];
    a = __builtin_amdgcn_mfma_f32_16x16x32_bf16(a0, *(const bf16x8*)(wrow), a, 0, 0, 0);
    a = __builtin_amdgcn_mfma_f32_16x16x32_bf16(a1, *(const bf16x8*)(wrow + 32), a, 0, 0, 0);
    a = __builtin_amdgcn_mfma_f32_16x16x32_bf16(a2, *(const bf16x8*)(wrow + 64), a, 0, 0, 0);
    acc[nf] = a;
  }

  const int mloc = (m0 - mbase) + 16 * wv + 4 * l4;
#pragma unroll
  for (int nf = 0; nf < 6; ++nf) {
    int p = nf * 16 + l15;
    float bv = bias_s[p];
#pragma unroll
    for (int r = 0; r < 4; ++r)
      y[(size_t)(mloc + r) * 2304 + n0 + p] = f2b(acc[nf][r] + bv);
  }
}

// ---------------- QKV pass B: shuffle + head scatter + rel fold ----------------
__global__ __launch_bounds__(256) void mha_qkv_shuffle(const unsigned short* __restrict__ y,
                                                       const float* __restrict__ rel,
                                                       unsigned short* __restrict__ qb,
                                                       unsigned short* __restrict__ kb,
                                                       unsigned short* __restrict__ vb,
                                                       int mbase, int rows) {
  const int wh = blockIdx.y;
  const int which = wh / H, h = wh - which * H;
  const int basep = which * 96 + h * 8;
  const int tid = threadIdx.x;
  const int lane = tid & 63;
  const int g = lane >> 3, j = lane & 7;
  const int d = j * 8 + g;
  const int rbase = blockIdx.x * 32;
#pragma unroll
  for (int r8 = 0; r8 < 8; ++r8) {
    int rowl = rbase + r8 * 4 + (tid >> 6);
    if (rowl >= rows) continue;
    int m = mbase + rowl;
    int s = m >> 6, b = m & 63;
    float val = b2f(y[(size_t)rowl * 2304 + g * 288 + basep + j]);
    size_t o = (((size_t)b * H + h) * S + s) * D + d;
    if (which == 0) {
      float rv = rel[(size_t)(S - 1 + s) * D + d];
      qb[o] = f2b(0.125f * val + rv);
    } else if (which == 1) {
      float rv = rel[(size_t)(S - 1 + s) * D + d];
      kb[o] = f2b(val + rv);
    } else {
      vb[o] = f2b(val);
    }
  }
}

// ---------------- fused MFMA attention (unchanged from R8) ---------------------
__global__ __launch_bounds__(256) void mha_fattn(
    const unsigned short* __restrict__ qb, const unsigned short* __restrict__ kb,
    const unsigned short* __restrict__ vb, const unsigned short* __restrict__ relb,
    float* __restrict__ context, unsigned short* __restrict__ probs, int bh0) {
  __shared__ __align__(16) unsigned short KtPt[64 * 232];
  __shared__ __align__(16) unsigned short Vt[64 * 232];
  unsigned short* Kt = KtPt;
  unsigned short* Pt = KtPt;

  const int id = blockIdx.x;
  const int xcd = id & 7;
  const int rr = id >> 3;
  const int stile = rr & 3;
  const int bhl = xcd + 8 * (rr >> 2);
  const int bh = bh0 + bhl;
  const int b_ = bh / H, h_ = bh - b_ * H;
  const int s0 = stile * 64;
  const int tid = threadIdx.x;
  const int lane = tid & 63, w = tid >> 6;
  const int l15 = lane & 15, l4 = lane >> 4;

#pragma unroll
  for (int tt = 0; tt < 224; tt += 32) {
    int t = tt + (tid & 31);
    int d0 = (tid >> 5) * 8;
    u32x4 v = {0, 0, 0, 0};
    if (t < S) v = *(const u32x4*)(vb + (((size_t)bh * S + t) << 6) + d0);
    const unsigned short* vp = (const unsigned short*)&v;
#pragma unroll
    for (int j = 0; j < 8; ++j) Vt[(d0 + j) * 232 + t] = vp[j];
  }

  const unsigned short* qg = qb + (((size_t)bh * S + (s0 + 16 * w + l15)) << 6) + l4 * 8;
  const unsigned short* rg = relb + (((size_t)(s0 + 16 * w + l15)) << 6) + l4 * 8;
  bf16x8 aq0 = *(const bf16x8*)(qg);
  bf16x8 aq1 = *(const bf16x8*)(qg + 32);
  bf16x8 aq2 = *(const bf16x8*)(rg);
  bf16x8 aq3 = *(const bf16x8*)(rg + 32);

  f32x4 acc[13];
#pragma unroll
  for (int i = 0; i < 13; ++i) acc[i] = (f32x4){0.f, 0.f, 0.f, 0.f};

#pragma unroll
  for (int tc = 0; tc < 4; ++tc) {
    const int t0 = tc * 64;
#pragma unroll
    for (int ii = 0; ii < 2; ++ii) {
      int idx = tid + ii * 256;
      int r = idx >> 3, c = idx & 7;
      int tg = t0 + r;
      u32x4 kv = {0, 0, 0, 0}, rv = {0, 0, 0, 0};
      if (tg < S) {
        kv = *(const u32x4*)(kb + (((size_t)bh * S + tg) << 6) + c * 8);
        rv = *(const u32x4*)(relb + ((size_t)tg << 6) + c * 8);
        rv ^= 0x80008000u;
      }
      *(u32x4*)(Kt + r * 136 + c * 8) = kv;
      *(u32x4*)(Kt + r * 136 + 64 + c * 8) = rv;
    }
    __syncthreads();
#pragma unroll
    for (int tf = 0; tf < 4; ++tf) {
      if (tc == 3 && tf > 0) continue;
      const unsigned short* kbse = Kt + (tf * 16 + l15) * 136 + l4 * 8;
      f32x4 a = acc[tc * 4 + tf];
      a = __builtin_amdgcn_mfma_f32_16x16x32_bf16(aq0, *(const bf16x8*)(kbse), a, 0, 0, 0);
      a = __builtin_amdgcn_mfma_f32_16x16x32_bf16(aq1, *(const bf16x8*)(kbse + 32), a, 0, 0, 0);
      a = __builtin_amdgcn_mfma_f32_16x16x32_bf16(aq2, *(const bf16x8*)(kbse + 64), a, 0, 0, 0);
      a = __builtin_amdgcn_mfma_f32_16x16x32_bf16(aq3, *(const bf16x8*)(kbse + 96), a, 0, 0, 0);
      acc[tc * 4 + tf] = a;
    }
    __syncthreads();
  }

  if (l15 >= 5) acc[12] = (f32x4){-3.0e38f, -3.0e38f, -3.0e38f, -3.0e38f};
  float inv[4];
#pragma unroll
  for (int r = 0; r < 4; ++r) {
    float m = acc[0][r];
#pragma unroll
    for (int tf = 1; tf < 13; ++tf) m = fmaxf(m, acc[tf][r]);
#pragma unroll
    for (int off = 1; off < 16; off <<= 1) m = fmaxf(m, __shfl_xor(m, off, 64));
    float s = 0.f;
#pragma unroll
    for (int tf = 0; tf < 13; ++tf) {
      float e = __expf(acc[tf][r] - m);
      acc[tf][r] = e;
      s += e;
    }
#pragma unroll
    for (int off = 1; off < 16; off <<= 1) s += __shfl_xor(s, off, 64);
    inv[r] = 1.f / s;
  }

#pragma unroll
  for (int tf = 0; tf < 13; ++tf)
#pragma unroll
    for (int r = 0; r < 4; ++r)
      Pt[(16 * w + 4 * l4 + r) * 232 + tf * 16 + l15] = f2b(acc[tf][r] * inv[r]);
  if (l15 < 12) {
#pragma unroll
    for (int r = 0; r < 4; ++r)
      *(unsigned int*)(Pt + (16 * w + 4 * l4 + r) * 232 + 208 + l15 * 2) = 0u;
  }
  __syncthreads();

  {
    const int r2 = tid >> 2;
    const int sg = s0 + r2;
#pragma unroll
    for (int j = 0; j < 7; ++j) {
      int c = (tid & 3) + 4 * j;
      if (c < 26 && sg < S) {
        u32x4 pv = *(const u32x4*)(Pt + r2 * 232 + c * 8);
        *(u32x4*)(probs + ((size_t)bhl * S + sg) * PST + c * 8) = pv;
      }
    }
  }

  bf16x8 ap[7];
#pragma unroll
  for (int kf = 0; kf < 7; ++kf)
    ap[kf] = *(const bf16x8*)(Pt + (16 * w + l15) * 232 + kf * 32 + l4 * 8);
  f32x4 ov[4];
#pragma unroll
  for (int df = 0; df < 4; ++df) {
    f32x4 o = (f32x4){0.f, 0.f, 0.f, 0.f};
    const unsigned short* vbse = Vt + (df * 16 + l15) * 232 + l4 * 8;
#pragma unroll
    for (int kf = 0; kf < 7; ++kf)
      o = __builtin_amdgcn_mfma_f32_16x16x32_bf16(ap[kf], *(const bf16x8*)(vbse + kf * 32), o, 0, 0, 0);
    ov[df] = o;
  }
#pragma unroll
  for (int df = 0; df < 4; ++df)
#pragma unroll
    for (int r = 0; r < 4; ++r) {
      int sg = s0 + 16 * w + 4 * l4 + r;
      if (sg < S)
        context[((size_t)b_ * S + sg) * E + h_ * 64 + df * 16 + l15] = ov[df][r];
    }
}

// ---------------- avg reduction over heads ------------------------------------
__global__ __launch_bounds__(256) void mha_avgred(const unsigned short* __restrict__ probs,
                                                  float* __restrict__ avg, int b0) {
  const int bs = blockIdx.x;
  const int bl = bs / S, s = bs - bl * S;
  const int t = threadIdx.x;
  if (t >= S) return;
  float acc = 0.f;
#pragma unroll
  for (int h = 0; h < H; ++h)
    acc += b2f(probs[(((size_t)bl * H + h) * S + s) * PST + t]);
  avg[(((size_t)(b0 + bl)) * S + s) * S + t] = acc * (1.f / H);
}

// ---------------- fused LN + fc1 (MFMA) + gelu, h1 bf16 ------------------------
// grid M/32, 128 threads (2 waves). LN folded linearly:
// h1 = inv_m*(acc_mn - mu_m*cg_n) + cb_n; acc = GEMM(x_bf16, (g.*w)^T).
__global__ __launch_bounds__(128) void mha_fc1ln(const float* __restrict__ ctx,
                                                 const unsigned short* __restrict__ w1t,
                                                 const float* __restrict__ cgb,
                                                 const float* __restrict__ cbb,
                                                 unsigned short* __restrict__ h1) {
  __shared__ __align__(16) unsigned short As[32 * 104];
  __shared__ __align__(16) unsigned short Wl[96 * 104];
  __shared__ float smu[32], sinv[32];
  const int m0 = blockIdx.x * 32;
  const int tid = threadIdx.x;
  const int lane = tid & 63, w = tid >> 6;
  const int l15 = lane & 15, l4 = lane >> 4;
  const int r = tid >> 2, q = tid & 3;

  float s1 = 0.f, s2 = 0.f;
  f32x4 acc[6];
#pragma unroll
  for (int nf = 0; nf < 6; ++nf) acc[nf] = (f32x4){0.f, 0.f, 0.f, 0.f};

  for (int c = 0; c < 8; ++c) {
    const int k0 = c * 96;
    // stage A (row r, cols q*24..+23) + accumulate stats
    {
      const float* xr = ctx + (size_t)(m0 + r) * E + k0 + q * 24;
      unsigned short* ar = As + r * 104 + q * 24;
#pragma unroll
      for (int j = 0; j < 6; ++j) {
        float4 v = *reinterpret_cast<const float4*>(xr + j * 4);
        s1 += v.x + v.y + v.z + v.w;
        s2 += v.x * v.x + v.y * v.y + v.z * v.z + v.w * v.w;
        ar[j * 4 + 0] = f2b(v.x); ar[j * 4 + 1] = f2b(v.y);
        ar[j * 4 + 2] = f2b(v.z); ar[j * 4 + 3] = f2b(v.w);
      }
    }
    // stage W' rows [96][96]
    for (int i = tid; i < 96 * 12; i += 128) {
      int n = i / 12, c8 = i - n * 12;
      *(u32x4*)(Wl + n * 104 + c8 * 8) =
          *(const u32x4*)(w1t + (size_t)n * E + k0 + c8 * 8);
    }
    __syncthreads();
    const unsigned short* arow = As + (16 * w + l15) * 104 + l4 * 8;
    bf16x8 a0 = *(const bf16x8*)(arow);
    bf16x8 a1 = *(const bf16x8*)(arow + 32);
    bf16x8 a2 = *(const bf16x8*)(arow + 64);
#pragma unroll
    for (int nf = 0; nf < 6; ++nf) {
      const unsigned short* wr = Wl + (nf * 16 + l15) * 104 + l4 * 8;
      f32x4 a = acc[nf];
      a = __builtin_amdgcn_mfma_f32_16x16x32_bf16(a0, *(const bf16x8*)(wr), a, 0, 0, 0);
      a = __builtin_amdgcn_mfma_f32_16x16x32_bf16(a1, *(const bf16x8*)(wr + 32), a, 0, 0, 0);
      a = __builtin_amdgcn_mfma_f32_16x16x32_bf16(a2, *(const bf16x8*)(wr + 64), a, 0, 0, 0);
      acc[nf] = a;
    }
    __syncthreads();
  }

  // finalize stats (lanes r*4+q adjacent in wave)
  s1 += __shfl_xor(s1, 1, 64); s1 += __shfl_xor(s1, 2, 64);
  s2 += __shfl_xor(s2, 1, 64); s2 += __shfl_xor(s2, 2, 64);
  if (q == 0) {
    float mu = s1 * (1.f / E);
    float var = s2 * (1.f / E) - mu * mu;
    smu[r] = mu;
    sinv[r] = rsqrtf(var + 1e-5f);
  }
  __syncthreads();

#pragma unroll
  for (int nf = 0; nf < 6; ++nf) {
    int n = nf * 16 + l15;
    float cg = cgb[n], cb = cbb[n];
#pragma unroll
    for (int rr = 0; rr < 4; ++rr) {
      int ml = 16 * w + 4 * l4 + rr;
      float u = sinv[ml] * (acc[nf][rr] - smu[ml] * cg) + cb;
      float gl = 0.5f * u * (1.f + tanhf(0.7978845608028654f * (u + 0.044715f * u * u * u)));
      h1[(size_t)(m0 + ml) * 96 + n] = f2b(gl);
    }
  }
}

// ---------------- fc2 (MFMA) + sigmoid gate, attn2 bf16 ------------------------
// grid (M/64, 4): n0 = by*192.
__global__ __launch_bounds__(256) void mha_fc2(const unsigned short* __restrict__ h1,
                                               const unsigned short* __restrict__ w2t,
                                               const float* __restrict__ bias,
                                               const float* __restrict__ ctx,
                                               unsigned short* __restrict__ attn2) {
  __shared__ __align__(16) unsigned short Hs[64 * 104];
  __shared__ __align__(16) unsigned short Wl[192 * 104];
  const int m0 = blockIdx.x * 64;
  const int n0 = blockIdx.y * 192;
  const int tid = threadIdx.x;
  const int lane = tid & 63, w = tid >> 6;
  const int l15 = lane & 15, l4 = lane >> 4;

  for (int i = tid; i < 64 * 12; i += 256) {
    int rr = i / 12, c8 = i - rr * 12;
    *(u32x4*)(Hs + rr * 104 + c8 * 8) =
        *(const u32x4*)(h1 + (size_t)(m0 + rr) * 96 + c8 * 8);
  }
  for (int i = tid; i < 192 * 12; i += 256) {
    int n = i / 12, c8 = i - n * 12;
    *(u32x4*)(Wl + n * 104 + c8 * 8) =
        *(const u32x4*)(w2t + (size_t)(n0 + n) * 96 + c8 * 8);
  }
  __syncthreads();

  const unsigned short* arow = Hs + (16 * w + l15) * 104 + l4 * 8;
  bf16x8 a0 = *(const bf16x8*)(arow);
  bf16x8 a1 = *(const bf16x8*)(arow + 32);
  bf16x8 a2 = *(const bf16x8*)(arow + 64);

#pragma unroll
  for (int nf = 0; nf < 12; ++nf) {
    const unsigned short* wr = Wl + (nf * 16 + l15) * 104 + l4 * 8;
    f32x4 a = (f32x4){0.f, 0.f, 0.f, 0.f};
    a = __builtin_amdgcn_mfma_f32_16x16x32_bf16(a0, *(const bf16x8*)(wr), a, 0, 0, 0);
    a = __builtin_amdgcn_mfma_f32_16x16x32_bf16(a1, *(const bf16x8*)(wr + 32), a, 0, 0, 0);
    a = __builtin_amdgcn_mfma_f32_16x16x32_bf16(a2, *(const bf16x8*)(wr + 64), a, 0, 0, 0);
    int n = n0 + nf * 16 + l15;
    float bv = bias[n];
#pragma unroll
    for (int rr = 0; rr < 4; ++rr) {
      int m = m0 + 16 * w + 4 * l4 + rr;
      float val = a[rr] + bv;
      float sg = 1.f / (1.f + __expf(-val));
      float cv = ctx[(size_t)m * E + n];
      attn2[(size_t)m * E + n] = f2b(cv * sg);
    }
  }
}

// ---------------- grouped out projection (MFMA) + transpose --------------------
// grid (M/64, 8).
__global__ __launch_bounds__(256) void mha_out(const unsigned short* __restrict__ attn2,
                                               const float* __restrict__ w,
                                               const float* __restrict__ bias,
                                               float* __restrict__ outp) {
  __shared__ __align__(16) unsigned short Asl[64 * 104];
  __shared__ __align__(16) unsigned short Wl[96 * 104];
  __shared__ float bias_s[96];
  const int m0 = blockIdx.x * 64;
  const int g = blockIdx.y;
  const int n0 = g * 96;
  const int tid = threadIdx.x;
  const int lane = tid & 63, w_ = tid >> 6;
  const int l15 = lane & 15, l4 = lane >> 4;

  for (int i = tid; i < 64 * 12; i += 256) {
    int rr = i / 12, c8 = i - rr * 12;
    *(u32x4*)(Asl + rr * 104 + c8 * 8) =
        *(const u32x4*)(attn2 + (size_t)(m0 + rr) * E + n0 + c8 * 8);
  }
  for (int i = tid; i < 96 * 24; i += 256) {
    int n = i / 24, c4 = i - n * 24;
    float4 v = *reinterpret_cast<const float4*>(&w[(size_t)(n0 + n) * 96 + c4 * 4]);
    unsigned short* dst = Wl + n * 104 + c4 * 4;
    dst[0] = f2b(v.x); dst[1] = f2b(v.y); dst[2] = f2b(v.z); dst[3] = f2b(v.w);
  }
  if (tid < 96) bias_s[tid] = bias[n0 + tid];
  __syncthreads();

  const unsigned short* arow = Asl + (16 * w_ + l15) * 104 + l4 * 8;
  bf16x8 a0 = *(const bf16x8*)(arow);
  bf16x8 a1 = *(const bf16x8*)(arow + 32);
  bf16x8 a2 = *(const bf16x8*)(arow + 64);

  // m -> (b,s) for the 4 D-rows this thread owns (context rows are b*S+s)
  int bb4[4], ss4[4];
#pragma unroll
  for (int rr = 0; rr < 4; ++rr) {
    int m = m0 + 16 * w_ + 4 * l4 + rr;
    bb4[rr] = m / S;
    ss4[rr] = m - bb4[rr] * S;
  }

#pragma unroll
  for (int nf = 0; nf < 6; ++nf) {
    const unsigned short* wr = Wl + (nf * 16 + l15) * 104 + l4 * 8;
    f32x4 a = (f32x4){0.f, 0.f, 0.f, 0.f};
    a = __builtin_amdgcn_mfma_f32_16x16x32_bf16(a0, *(const bf16x8*)(wr), a, 0, 0, 0);
    a = __builtin_amdgcn_mfma_f32_16x16x32_bf16(a1, *(const bf16x8*)(wr + 32), a, 0, 0, 0);
    a = __builtin_amdgcn_mfma_f32_16x16x32_bf16(a2, *(const bf16x8*)(wr + 64), a, 0, 0, 0);
    int p = n0 + nf * 16 + l15;
    float bv = bias_s[p - n0];
#pragma unroll
    for (int rr = 0; rr < 4; ++rr)
      outp[((size_t)ss4[rr] * B + bb4[rr]) * E + p] = a[rr] + bv;
  }
}

// ---------------- host launcher ------------------------------------------------
extern "C" void kernel_launch(void* const* d_in, const int* in_sizes, int n_in,
                              void* d_out, int out_size, void* d_ws, size_t ws_size,
                              hipStream_t stream) {
  const float* query = (const float*)d_in[0];
  const float* qkv_w = (const float*)d_in[3];
  const float* qkv_b = (const float*)d_in[4];
  const float* out_w = (const float*)d_in[5];
  const float* out_b = (const float*)d_in[6];
  const float* rel   = (const float*)d_in[7];
  const float* ln_g  = (const float*)d_in[8];
  const float* ln_b  = (const float*)d_in[9];
  const float* fc1_w = (const float*)d_in[10];
  const float* fc1_b = (const float*)d_in[11];
  const float* fc2_w = (const float*)d_in[12];
  const float* fc2_b = (const float*)d_in[13];

  float* ws = (float*)d_ws;
  unsigned short* qb   = (unsigned short*)ws;
  unsigned short* kbuf = qb + SBE;
  unsigned short* vbb  = kbuf + SBE;
  unsigned short* relb = vbb + SBE;                 // 16384 shorts
  size_t off = 3 * SBE / 2 + 8192;                  // floats consumed
  float* context = ws + off;                        // SBE f32 (ybuf aliases)
  unsigned short* ybuf = (unsigned short*)context;
  unsigned short* attn2b = (unsigned short*)(ws + off + SBE);  // SBE bf16
  unsigned short* h1b = attn2b + SBE;               // M*96 bf16
  unsigned short* w1t = h1b + (size_t)M * 96;       // 73728 bf16
  unsigned short* w2t = w1t + 73728;                // 73728 bf16
  float* cgb = (float*)(w2t + 73728);
  float* cbb = cgb + 96;
  unsigned short* probsb = (unsigned short*)(cbb + 96);
  float* outp = (float*)d_out;
  float* avgp = outp + SBE;

  size_t used_f = off + SBE + (SBE + (size_t)M * 96 + 147456) / 2 + 192;
  size_t avail_f = (ws_size / 4 > used_f) ? ws_size / 4 - used_f : 0;
  int Bc = 2;
  const int cand[6] = {64, 32, 16, 8, 4, 2};
  for (int i = 0; i < 6; ++i) {
    size_t need_f = ((size_t)cand[i] * H * S * PST + 1) / 2;
    if (need_f <= avail_f) { Bc = cand[i]; break; }
  }

  mha_relb<<<64, 256, 0, stream>>>(rel, relb);
  mha_wprep<<<577, 256, 0, stream>>>(fc1_w, fc2_w, ln_g, ln_b, fc1_b, w1t, w2t,
                                     cgb, cbb);

  const int CH = 6400;
  for (int mbase = 0; mbase < M; mbase += CH) {
    int rows = (M - mbase < CH) ? (M - mbase) : CH;
    mha_qkv_gemm<<<dim3(rows / 64, 24), 256, 0, stream>>>(query, qkv_w, qkv_b, ybuf,
                                                          mbase, rows);
    mha_qkv_shuffle<<<dim3(rows / 32, 36), 256, 0, stream>>>(ybuf, rel, qb, kbuf,
                                                             vbb, mbase, rows);
  }

  for (int b0 = 0; b0 < B; b0 += Bc) {
    int bc = (B - b0 < Bc) ? (B - b0) : Bc;
    int nbh = bc * H;
    mha_fattn<<<4 * nbh, 256, 0, stream>>>(qb, kbuf, vbb, relb, context, probsb,
                                           b0 * H);
    mha_avgred<<<bc * S, 256, 0, stream>>>(probsb, avgp, b0);
  }

  mha_fc1ln<<<M / 32, 128, 0, stream>>>(context, w1t, cgb, cbb, h1b);
  mha_fc2<<<dim3(M / 64, 4), 256, 0, stream>>>(h1b, w2t, fc2_b, context, attn2b);
  mha_out<<<dim3(M / 64, 8), 256, 0, stream>>>(attn2b, out_w, out_b, outp);
}

// Round 10
// 285.588 us; speedup vs baseline: 22.8645x; 1.0649x over previous
//
#include <hip/hip_runtime.h>
#include <hip/hip_bf16.h>

// ---------------- constants ----------------
constexpr int S = 197;
constexpr int B = 64;
constexpr int E = 768;
constexpr int H = 12;
constexpr int D = 64;
constexpr int M = S * B;                  // 12608 rows
constexpr size_t SBE = (size_t)M * E;     // 9,682,944
constexpr int PST = 208;                  // probs row stride

typedef short bf16x8 __attribute__((ext_vector_type(8)));
typedef float f32x4 __attribute__((ext_vector_type(4)));
typedef unsigned int u32x4 __attribute__((ext_vector_type(4)));

__device__ __forceinline__ unsigned short f2b(float x) {  // f32 -> bf16 (RNE)
  unsigned int u = __float_as_uint(x);
  return (unsigned short)((u + 0x7FFFu + ((u >> 16) & 1u)) >> 16);
}
__device__ __forceinline__ float b2f(unsigned short u) {
  return __uint_as_float((unsigned int)u << 16);
}

// ---------------- wprep: weights prep + relb (merged) --------------------------
// bid 0..287:   w1t[n][k] = g_k * fc1_w[k][n]  (bf16 [96][768])
// bid 288..575: w2t[n][k] = fc2_w[k][n]        (bf16 [768][96])
// bid 576:      cg_n, cb_n LN-fold constants
// bid 577..640: relb: bf16 rel rows rel[196+s][d], zero-padded to 256 rows
__global__ __launch_bounds__(256) void mha_wprep(const float* __restrict__ w1,
                                                 const float* __restrict__ w2,
                                                 const float* __restrict__ lng,
                                                 const float* __restrict__ lnb,
                                                 const float* __restrict__ b1,
                                                 const float* __restrict__ rel,
                                                 unsigned short* __restrict__ w1t,
                                                 unsigned short* __restrict__ w2t,
                                                 float* __restrict__ cgb,
                                                 float* __restrict__ cbb,
                                                 unsigned short* __restrict__ relb) {
  const int bid = blockIdx.x, tid = threadIdx.x;
  if (bid < 288) {
    int idx = bid * 256 + tid;
    int n = idx / 768, k = idx - n * 768;
    w1t[idx] = f2b(lng[k] * w1[(size_t)k * 96 + n]);
  } else if (bid < 576) {
    int idx = (bid - 288) * 256 + tid;
    int n = idx / 96, k = idx - n * 96;
    w2t[idx] = f2b(w2[(size_t)k * 768 + n]);
  } else if (bid == 576) {
    if (tid < 96) {
      float cg = 0.f, cb = 0.f;
      for (int k = 0; k < 768; ++k) {
        float wv = w1[(size_t)k * 96 + tid];
        cg += lng[k] * wv;
        cb += lnb[k] * wv;
      }
      cgb[tid] = cg;
      cbb[tid] = cb + b1[tid];
    }
  } else {
    int idx = (bid - 577) * 256 + tid;
    int s2 = idx >> 6, d = idx & 63;
    float v = (s2 < S) ? rel[(size_t)(S - 1 + s2) * D + d] : 0.f;
    relb[idx] = f2b(v);
  }
}

// ---------------- QKV grouped GEMM (MFMA bf16), y out bf16 ---------------------
__global__ __launch_bounds__(256) void mha_qkv_gemm(const float* __restrict__ x,
                                                    const float* __restrict__ w,
                                                    const float* __restrict__ bias,
                                                    unsigned short* __restrict__ y,
                                                    int mbase, int rows) {
  __shared__ __align__(16) unsigned short Xs[64 * 104];
  __shared__ __align__(16) unsigned short Wsl[96 * 104];
  __shared__ float bias_s[96];
  const int m0 = mbase + blockIdx.x * 64;
  const int n0 = blockIdx.y * 96;
  const int g = blockIdx.y / 3;
  const int tid = threadIdx.x;

  for (int i = tid; i < 64 * 24; i += 256) {
    int r = i / 24, c4 = i - r * 24;
    float4 v = *reinterpret_cast<const float4*>(
        &x[(size_t)(m0 + r) * E + g * 96 + c4 * 4]);
    unsigned short* dst = Xs + r * 104 + c4 * 4;
    dst[0] = f2b(v.x); dst[1] = f2b(v.y); dst[2] = f2b(v.z); dst[3] = f2b(v.w);
  }
  for (int i = tid; i < 96 * 24; i += 256) {
    int n = i / 24, c4 = i - n * 24;
    float4 v = *reinterpret_cast<const float4*>(&w[(size_t)(n0 + n) * 96 + c4 * 4]);
    unsigned short* dst = Wsl + n * 104 + c4 * 4;
    dst[0] = f2b(v.x); dst[1] = f2b(v.y); dst[2] = f2b(v.z); dst[3] = f2b(v.w);
  }
  if (tid < 96) bias_s[tid] = bias[n0 + tid];
  __syncthreads();

  const int lane = tid & 63, wv = tid >> 6;
  const int l15 = lane & 15, l4 = lane >> 4;

  const unsigned short* xrow = Xs + (16 * wv + l15) * 104 + l4 * 8;
  bf16x8 a0 = *(const bf16x8*)(xrow);
  bf16x8 a1 = *(const bf16x8*)(xrow + 32);
  bf16x8 a2 = *(const bf16x8*)(xrow + 64);

  f32x4 acc[6];
#pragma unroll
  for (int nf = 0; nf < 6; ++nf) acc[nf] = (f32x4){0.f, 0.f, 0.f, 0.f};
#pragma unroll
  for (int nf = 0; nf < 6; ++nf) {
    const unsigned short* wrow = Wsl + (nf * 16 + l15) * 104 + l4 * 8;
    f32x4 a = acc[nf];
    a = __builtin_amdgcn_mfma_f32_16x16x32_bf16(a0, *(const bf16x8*)(wrow), a, 0, 0, 0);
    a = __builtin_amdgcn_mfma_f32_16x16x32_bf16(a1, *(const bf16x8*)(wrow + 32), a, 0, 0, 0);
    a = __builtin_amdgcn_mfma_f32_16x16x32_bf16(a2, *(const bf16x8*)(wrow + 64), a, 0, 0, 0);
    acc[nf] = a;
  }

  const int mloc = (m0 - mbase) + 16 * wv + 4 * l4;
#pragma unroll
  for (int nf = 0; nf < 6; ++nf) {
    int p = nf * 16 + l15;
    float bv = bias_s[p];
#pragma unroll
    for (int r = 0; r < 4; ++r)
      y[(size_t)(mloc + r) * 2304 + n0 + p] = f2b(acc[nf][r] + bv);
  }
}

// ---------------- QKV pass B: shuffle + head scatter + rel fold ----------------
__global__ __launch_bounds__(256) void mha_qkv_shuffle(const unsigned short* __restrict__ y,
                                                       const float* __restrict__ rel,
                                                       unsigned short* __restrict__ qb,
                                                       unsigned short* __restrict__ kb,
                                                       unsigned short* __restrict__ vb,
                                                       int mbase, int rows) {
  const int wh = blockIdx.y;
  const int which = wh / H, h = wh - which * H;
  const int basep = which * 96 + h * 8;
  const int tid = threadIdx.x;
  const int lane = tid & 63;
  const int g = lane >> 3, j = lane & 7;
  const int d = j * 8 + g;
  const int rbase = blockIdx.x * 32;
#pragma unroll
  for (int r8 = 0; r8 < 8; ++r8) {
    int rowl = rbase + r8 * 4 + (tid >> 6);
    if (rowl >= rows) continue;
    int m = mbase + rowl;
    int s = m >> 6, b = m & 63;
    float val = b2f(y[(size_t)rowl * 2304 + g * 288 + basep + j]);
    size_t o = (((size_t)b * H + h) * S + s) * D + d;
    if (which == 0) {
      float rv = rel[(size_t)(S - 1 + s) * D + d];
      qb[o] = f2b(0.125f * val + rv);
    } else if (which == 1) {
      float rv = rel[(size_t)(S - 1 + s) * D + d];
      kb[o] = f2b(val + rv);
    } else {
      vb[o] = f2b(val);
    }
  }
}

// ---------------- fused MFMA attention (LDS 47104 B -> 3 blocks/CU) ------------
// Pt overlays Kt (stride 136); P/PV split into two k-halves. K chunks are
// register-prefetched one ahead so HBM/L2 latency hides under MFMA phases.
__global__ __launch_bounds__(256) void mha_fattn(
    const unsigned short* __restrict__ qb, const unsigned short* __restrict__ kb,
    const unsigned short* __restrict__ vb, const unsigned short* __restrict__ relb,
    float* __restrict__ context, unsigned short* __restrict__ probs, int bh0) {
  __shared__ __align__(16) unsigned short KtPt[64 * 136];  // 17408 B (Kt / Pt halves)
  __shared__ __align__(16) unsigned short Vt[64 * 232];    // 29696 B, V^T [d][t]
  unsigned short* Kt = KtPt;
  unsigned short* Pt = KtPt;

  const int id = blockIdx.x;
  const int xcd = id & 7;
  const int rr = id >> 3;
  const int stile = rr & 3;
  const int bhl = xcd + 8 * (rr >> 2);
  const int bh = bh0 + bhl;
  const int b_ = bh / H, h_ = bh - b_ * H;
  const int s0 = stile * 64;
  const int tid = threadIdx.x;
  const int lane = tid & 63, w = tid >> 6;
  const int l15 = lane & 15, l4 = lane >> 4;

  // ---- stage Vt [d][t] (vector global loads, scalar transposed writes) ----
#pragma unroll
  for (int tt = 0; tt < 224; tt += 32) {
    int t = tt + (tid & 31);
    int d0 = (tid >> 5) * 8;
    u32x4 v = {0, 0, 0, 0};
    if (t < S) v = *(const u32x4*)(vb + (((size_t)bh * S + t) << 6) + d0);
    const unsigned short* vp = (const unsigned short*)&v;
#pragma unroll
    for (int j = 0; j < 8; ++j) Vt[(d0 + j) * 232 + t] = vp[j];
  }

  // ---- direct-global Q A-frags (rows >= S read garbage, masked at consumers) --
  const unsigned short* qg = qb + (((size_t)bh * S + (s0 + 16 * w + l15)) << 6) + l4 * 8;
  const unsigned short* rg = relb + (((size_t)(s0 + 16 * w + l15)) << 6) + l4 * 8;
  bf16x8 aq0 = *(const bf16x8*)(qg);
  bf16x8 aq1 = *(const bf16x8*)(qg + 32);
  bf16x8 aq2 = *(const bf16x8*)(rg);
  bf16x8 aq3 = *(const bf16x8*)(rg + 32);

  // ---- K chunk loader (reg-prefetch) ----
  auto loadK = [&](int tc, u32x4* kv, u32x4* rv) {
#pragma unroll
    for (int ii = 0; ii < 2; ++ii) {
      int idx = tid + ii * 256;
      int r = idx >> 3, c = idx & 7;
      int tg = tc * 64 + r;
      kv[ii] = (u32x4){0, 0, 0, 0};
      rv[ii] = (u32x4){0, 0, 0, 0};
      if (tg < S) {
        kv[ii] = *(const u32x4*)(kb + (((size_t)bh * S + tg) << 6) + c * 8);
        u32x4 rvv = *(const u32x4*)(relb + ((size_t)tg << 6) + c * 8);
        rv[ii] = rvv ^ 0x80008000u;  // negate rel on K side
      }
    }
  };

  f32x4 acc[13];
#pragma unroll
  for (int i = 0; i < 13; ++i) acc[i] = (f32x4){0.f, 0.f, 0.f, 0.f};

  u32x4 kvA[2], rvA[2], kvB[2], rvB[2];
  loadK(0, kvA, rvA);

  // ---- QK^T over 4 t-chunks of 64, prefetched one ahead ----
#pragma unroll
  for (int tc = 0; tc < 4; ++tc) {
    u32x4* kvc = (tc & 1) ? kvB : kvA;
    u32x4* rvc = (tc & 1) ? rvB : rvA;
#pragma unroll
    for (int ii = 0; ii < 2; ++ii) {
      int idx = tid + ii * 256;
      int r = idx >> 3, c = idx & 7;
      *(u32x4*)(Kt + r * 136 + c * 8) = kvc[ii];
      *(u32x4*)(Kt + r * 136 + 64 + c * 8) = rvc[ii];
    }
    if (tc < 3) loadK(tc + 1, (tc & 1) ? kvA : kvB, (tc & 1) ? rvA : rvB);
    __syncthreads();
#pragma unroll
    for (int tf = 0; tf < 4; ++tf) {
      if (tc == 3 && tf > 0) continue;  // t >= 208 not needed
      const unsigned short* kbse = Kt + (tf * 16 + l15) * 136 + l4 * 8;
      f32x4 a = acc[tc * 4 + tf];
      a = __builtin_amdgcn_mfma_f32_16x16x32_bf16(aq0, *(const bf16x8*)(kbse), a, 0, 0, 0);
      a = __builtin_amdgcn_mfma_f32_16x16x32_bf16(aq1, *(const bf16x8*)(kbse + 32), a, 0, 0, 0);
      a = __builtin_amdgcn_mfma_f32_16x16x32_bf16(aq2, *(const bf16x8*)(kbse + 64), a, 0, 0, 0);
      a = __builtin_amdgcn_mfma_f32_16x16x32_bf16(aq3, *(const bf16x8*)(kbse + 96), a, 0, 0, 0);
      acc[tc * 4 + tf] = a;
    }
    __syncthreads();  // Kt restage safe; after tc=3 also gates the Pt overlay
  }

  // ---- softmax in registers (col=l15 -> t, row=4*l4+r -> s) ----
  if (l15 >= 5) acc[12] = (f32x4){-3.0e38f, -3.0e38f, -3.0e38f, -3.0e38f};
  float inv[4];
#pragma unroll
  for (int r = 0; r < 4; ++r) {
    float m = acc[0][r];
#pragma unroll
    for (int tf = 1; tf < 13; ++tf) m = fmaxf(m, acc[tf][r]);
#pragma unroll
    for (int off = 1; off < 16; off <<= 1) m = fmaxf(m, __shfl_xor(m, off, 64));
    float s = 0.f;
#pragma unroll
    for (int tf = 0; tf < 13; ++tf) {
      float e = __expf(acc[tf][r] - m);
      acc[tf][r] = e;
      s += e;
    }
#pragma unroll
    for (int off = 1; off < 16; off <<= 1) s += __shfl_xor(s, off, 64);
    inv[r] = 1.f / s;
  }

  f32x4 ov[4];
#pragma unroll
  for (int df = 0; df < 4; ++df) ov[df] = (f32x4){0.f, 0.f, 0.f, 0.f};

  // ================= half 1: t 0..127 =================
#pragma unroll
  for (int tf = 0; tf < 8; ++tf)
#pragma unroll
    for (int r = 0; r < 4; ++r)
      Pt[(16 * w + 4 * l4 + r) * 136 + tf * 16 + l15] = f2b(acc[tf][r] * inv[r]);
  __syncthreads();

  {  // probs dump t 0..127
    const int r2 = tid >> 2;
    const int sg = s0 + r2;
    if (sg < S) {
#pragma unroll
      for (int j = 0; j < 4; ++j) {
        int c = (tid & 3) + 4 * j;  // 0..15
        u32x4 pv = *(const u32x4*)(Pt + r2 * 136 + c * 8);
        *(u32x4*)(probs + ((size_t)bhl * S + sg) * PST + c * 8) = pv;
      }
    }
  }
  {  // PV pass 1 (k 0..127)
    bf16x8 ap[4];
#pragma unroll
    for (int kf = 0; kf < 4; ++kf)
      ap[kf] = *(const bf16x8*)(Pt + (16 * w + l15) * 136 + kf * 32 + l4 * 8);
#pragma unroll
    for (int df = 0; df < 4; ++df) {
      const unsigned short* vbse = Vt + (df * 16 + l15) * 232 + l4 * 8;
      f32x4 o = ov[df];
#pragma unroll
      for (int kf = 0; kf < 4; ++kf)
        o = __builtin_amdgcn_mfma_f32_16x16x32_bf16(ap[kf], *(const bf16x8*)(vbse + kf * 32), o, 0, 0, 0);
      ov[df] = o;
    }
  }
  __syncthreads();

  // ================= half 2: t 128..223 (cols 80..95 zeroed) =================
#pragma unroll
  for (int tf = 8; tf < 13; ++tf)
#pragma unroll
    for (int r = 0; r < 4; ++r)
      Pt[(16 * w + 4 * l4 + r) * 136 + (tf - 8) * 16 + l15] = f2b(acc[tf][r] * inv[r]);
#pragma unroll
  for (int r = 0; r < 4; ++r)
    Pt[(16 * w + 4 * l4 + r) * 136 + 80 + l15] = 0;
  __syncthreads();

  {  // probs dump t 128..207
    const int r2 = tid >> 2;
    const int sg = s0 + r2;
    if (sg < S) {
#pragma unroll
      for (int j = 0; j < 3; ++j) {
        int c = (tid & 3) + 4 * j;
        if (c < 10) {
          u32x4 pv = *(const u32x4*)(Pt + r2 * 136 + c * 8);
          *(u32x4*)(probs + ((size_t)bhl * S + sg) * PST + 128 + c * 8) = pv;
        }
      }
    }
  }
  {  // PV pass 2 (k 128..223)
    bf16x8 ap[3];
#pragma unroll
    for (int kf = 0; kf < 3; ++kf)
      ap[kf] = *(const bf16x8*)(Pt + (16 * w + l15) * 136 + kf * 32 + l4 * 8);
#pragma unroll
    for (int df = 0; df < 4; ++df) {
      const unsigned short* vbse = Vt + (df * 16 + l15) * 232 + 128 + l4 * 8;
      f32x4 o = ov[df];
#pragma unroll
      for (int kf = 0; kf < 3; ++kf)
        o = __builtin_amdgcn_mfma_f32_16x16x32_bf16(ap[kf], *(const bf16x8*)(vbse + kf * 32), o, 0, 0, 0);
      ov[df] = o;
    }
  }

#pragma unroll
  for (int df = 0; df < 4; ++df)
#pragma unroll
    for (int r = 0; r < 4; ++r) {
      int sg = s0 + 16 * w + 4 * l4 + r;
      if (sg < S)
        context[((size_t)b_ * S + sg) * E + h_ * 64 + df * 16 + l15] = ov[df][r];
    }
}

// ---------------- avg reduction over heads ------------------------------------
__global__ __launch_bounds__(256) void mha_avgred(const unsigned short* __restrict__ probs,
                                                  float* __restrict__ avg, int b0) {
  const int bs = blockIdx.x;
  const int bl = bs / S, s = bs - bl * S;
  const int t = threadIdx.x;
  if (t >= S) return;
  float acc = 0.f;
#pragma unroll
  for (int h = 0; h < H; ++h)
    acc += b2f(probs[(((size_t)bl * H + h) * S + s) * PST + t]);
  avg[(((size_t)(b0 + bl)) * S + s) * S + t] = acc * (1.f / H);
}

// ---------------- fused LN + fc1 (MFMA) + gelu, h1 bf16 ------------------------
__global__ __launch_bounds__(128) void mha_fc1ln(const float* __restrict__ ctx,
                                                 const unsigned short* __restrict__ w1t,
                                                 const float* __restrict__ cgb,
                                                 const float* __restrict__ cbb,
                                                 unsigned short* __restrict__ h1) {
  __shared__ __align__(16) unsigned short As[32 * 104];
  __shared__ __align__(16) unsigned short Wl[96 * 104];
  __shared__ float smu[32], sinv[32];
  const int m0 = blockIdx.x * 32;
  const int tid = threadIdx.x;
  const int lane = tid & 63, w = tid >> 6;
  const int l15 = lane & 15, l4 = lane >> 4;
  const int r = tid >> 2, q = tid & 3;

  float s1 = 0.f, s2 = 0.f;
  f32x4 acc[6];
#pragma unroll
  for (int nf = 0; nf < 6; ++nf) acc[nf] = (f32x4){0.f, 0.f, 0.f, 0.f};

  for (int c = 0; c < 8; ++c) {
    const int k0 = c * 96;
    {
      const float* xr = ctx + (size_t)(m0 + r) * E + k0 + q * 24;
      unsigned short* ar = As + r * 104 + q * 24;
#pragma unroll
      for (int j = 0; j < 6; ++j) {
        float4 v = *reinterpret_cast<const float4*>(xr + j * 4);
        s1 += v.x + v.y + v.z + v.w;
        s2 += v.x * v.x + v.y * v.y + v.z * v.z + v.w * v.w;
        ar[j * 4 + 0] = f2b(v.x); ar[j * 4 + 1] = f2b(v.y);
        ar[j * 4 + 2] = f2b(v.z); ar[j * 4 + 3] = f2b(v.w);
      }
    }
    for (int i = tid; i < 96 * 12; i += 128) {
      int n = i / 12, c8 = i - n * 12;
      *(u32x4*)(Wl + n * 104 + c8 * 8) =
          *(const u32x4*)(w1t + (size_t)n * E + k0 + c8 * 8);
    }
    __syncthreads();
    const unsigned short* arow = As + (16 * w + l15) * 104 + l4 * 8;
    bf16x8 a0 = *(const bf16x8*)(arow);
    bf16x8 a1 = *(const bf16x8*)(arow + 32);
    bf16x8 a2 = *(const bf16x8*)(arow + 64);
#pragma unroll
    for (int nf = 0; nf < 6; ++nf) {
      const unsigned short* wr = Wl + (nf * 16 + l15) * 104 + l4 * 8;
      f32x4 a = acc[nf];
      a = __builtin_amdgcn_mfma_f32_16x16x32_bf16(a0, *(const bf16x8*)(wr), a, 0, 0, 0);
      a = __builtin_amdgcn_mfma_f32_16x16x32_bf16(a1, *(const bf16x8*)(wr + 32), a, 0, 0, 0);
      a = __builtin_amdgcn_mfma_f32_16x16x32_bf16(a2, *(const bf16x8*)(wr + 64), a, 0, 0, 0);
      acc[nf] = a;
    }
    __syncthreads();
  }

  s1 += __shfl_xor(s1, 1, 64); s1 += __shfl_xor(s1, 2, 64);
  s2 += __shfl_xor(s2, 1, 64); s2 += __shfl_xor(s2, 2, 64);
  if (q == 0) {
    float mu = s1 * (1.f / E);
    float var = s2 * (1.f / E) - mu * mu;
    smu[r] = mu;
    sinv[r] = rsqrtf(var + 1e-5f);
  }
  __syncthreads();

#pragma unroll
  for (int nf = 0; nf < 6; ++nf) {
    int n = nf * 16 + l15;
    float cg = cgb[n], cb = cbb[n];
#pragma unroll
    for (int rr = 0; rr < 4; ++rr) {
      int ml = 16 * w + 4 * l4 + rr;
      float u = sinv[ml] * (acc[nf][rr] - smu[ml] * cg) + cb;
      float gl = 0.5f * u * (1.f + tanhf(0.7978845608028654f * (u + 0.044715f * u * u * u)));
      h1[(size_t)(m0 + ml) * 96 + n] = f2b(gl);
    }
  }
}

// ---------------- fc2 (MFMA) + sigmoid gate, attn2 bf16 ------------------------
__global__ __launch_bounds__(256) void mha_fc2(const unsigned short* __restrict__ h1,
                                               const unsigned short* __restrict__ w2t,
                                               const float* __restrict__ bias,
                                               const float* __restrict__ ctx,
                                               unsigned short* __restrict__ attn2) {
  __shared__ __align__(16) unsigned short Hs[64 * 104];
  __shared__ __align__(16) unsigned short Wl[192 * 104];
  const int m0 = blockIdx.x * 64;
  const int n0 = blockIdx.y * 192;
  const int tid = threadIdx.x;
  const int lane = tid & 63, w = tid >> 6;
  const int l15 = lane & 15, l4 = lane >> 4;

  for (int i = tid; i < 64 * 12; i += 256) {
    int rr = i / 12, c8 = i - rr * 12;
    *(u32x4*)(Hs + rr * 104 + c8 * 8) =
        *(const u32x4*)(h1 + (size_t)(m0 + rr) * 96 + c8 * 8);
  }
  for (int i = tid; i < 192 * 12; i += 256) {
    int n = i / 12, c8 = i - n * 12;
    *(u32x4*)(Wl + n * 104 + c8 * 8) =
        *(const u32x4*)(w2t + (size_t)(n0 + n) * 96 + c8 * 8);
  }
  __syncthreads();

  const unsigned short* arow = Hs + (16 * w + l15) * 104 + l4 * 8;
  bf16x8 a0 = *(const bf16x8*)(arow);
  bf16x8 a1 = *(const bf16x8*)(arow + 32);
  bf16x8 a2 = *(const bf16x8*)(arow + 64);

#pragma unroll
  for (int nf = 0; nf < 12; ++nf) {
    const unsigned short* wr = Wl + (nf * 16 + l15) * 104 + l4 * 8;
    f32x4 a = (f32x4){0.f, 0.f, 0.f, 0.f};
    a = __builtin_amdgcn_mfma_f32_16x16x32_bf16(a0, *(const bf16x8*)(wr), a, 0, 0, 0);
    a = __builtin_amdgcn_mfma_f32_16x16x32_bf16(a1, *(const bf16x8*)(wr + 32), a, 0, 0, 0);
    a = __builtin_amdgcn_mfma_f32_16x16x32_bf16(a2, *(const bf16x8*)(wr + 64), a, 0, 0, 0);
    int n = n0 + nf * 16 + l15;
    float bv = bias[n];
#pragma unroll
    for (int rr = 0; rr < 4; ++rr) {
      int m = m0 + 16 * w + 4 * l4 + rr;
      float val = a[rr] + bv;
      float sg = 1.f / (1.f + __expf(-val));
      float cv = ctx[(size_t)m * E + n];
      attn2[(size_t)m * E + n] = f2b(cv * sg);
    }
  }
}

// ---------------- grouped out projection (MFMA) + transpose --------------------
__global__ __launch_bounds__(256) void mha_out(const unsigned short* __restrict__ attn2,
                                               const float* __restrict__ w,
                                               const float* __restrict__ bias,
                                               float* __restrict__ outp) {
  __shared__ __align__(16) unsigned short Asl[64 * 104];
  __shared__ __align__(16) unsigned short Wl[96 * 104];
  __shared__ float bias_s[96];
  const int m0 = blockIdx.x * 64;
  const int g = blockIdx.y;
  const int n0 = g * 96;
  const int tid = threadIdx.x;
  const int lane = tid & 63, w_ = tid >> 6;
  const int l15 = lane & 15, l4 = lane >> 4;

  for (int i = tid; i < 64 * 12; i += 256) {
    int rr = i / 12, c8 = i - rr * 12;
    *(u32x4*)(Asl + rr * 104 + c8 * 8) =
        *(const u32x4*)(attn2 + (size_t)(m0 + rr) * E + n0 + c8 * 8);
  }
  for (int i = tid; i < 96 * 24; i += 256) {
    int n = i / 24, c4 = i - n * 24;
    float4 v = *reinterpret_cast<const float4*>(&w[(size_t)(n0 + n) * 96 + c4 * 4]);
    unsigned short* dst = Wl + n * 104 + c4 * 4;
    dst[0] = f2b(v.x); dst[1] = f2b(v.y); dst[2] = f2b(v.z); dst[3] = f2b(v.w);
  }
  if (tid < 96) bias_s[tid] = bias[n0 + tid];
  __syncthreads();

  const unsigned short* arow = Asl + (16 * w_ + l15) * 104 + l4 * 8;
  bf16x8 a0 = *(const bf16x8*)(arow);
  bf16x8 a1 = *(const bf16x8*)(arow + 32);
  bf16x8 a2 = *(const bf16x8*)(arow + 64);

  int bb4[4], ss4[4];
#pragma unroll
  for (int rr = 0; rr < 4; ++rr) {
    int m = m0 + 16 * w_ + 4 * l4 + rr;
    bb4[rr] = m / S;
    ss4[rr] = m - bb4[rr] * S;
  }

#pragma unroll
  for (int nf = 0; nf < 6; ++nf) {
    const unsigned short* wr = Wl + (nf * 16 + l15) * 104 + l4 * 8;
    f32x4 a = (f32x4){0.f, 0.f, 0.f, 0.f};
    a = __builtin_amdgcn_mfma_f32_16x16x32_bf16(a0, *(const bf16x8*)(wr), a, 0, 0, 0);
    a = __builtin_amdgcn_mfma_f32_16x16x32_bf16(a1, *(const bf16x8*)(wr + 32), a, 0, 0, 0);
    a = __builtin_amdgcn_mfma_f32_16x16x32_bf16(a2, *(const bf16x8*)(wr + 64), a, 0, 0, 0);
    int p = n0 + nf * 16 + l15;
    float bv = bias_s[p - n0];
#pragma unroll
    for (int rr = 0; rr < 4; ++rr)
      outp[((size_t)ss4[rr] * B + bb4[rr]) * E + p] = a[rr] + bv;
  }
}

// ---------------- host launcher ------------------------------------------------
extern "C" void kernel_launch(void* const* d_in, const int* in_sizes, int n_in,
                              void* d_out, int out_size, void* d_ws, size_t ws_size,
                              hipStream_t stream) {
  const float* query = (const float*)d_in[0];
  const float* qkv_w = (const float*)d_in[3];
  const float* qkv_b = (const float*)d_in[4];
  const float* out_w = (const float*)d_in[5];
  const float* out_b = (const float*)d_in[6];
  const float* rel   = (const float*)d_in[7];
  const float* ln_g  = (const float*)d_in[8];
  const float* ln_b  = (const float*)d_in[9];
  const float* fc1_w = (const float*)d_in[10];
  const float* fc1_b = (const float*)d_in[11];
  const float* fc2_w = (const float*)d_in[12];
  const float* fc2_b = (const float*)d_in[13];

  float* ws = (float*)d_ws;
  unsigned short* qb   = (unsigned short*)ws;
  unsigned short* kbuf = qb + SBE;
  unsigned short* vbb  = kbuf + SBE;
  unsigned short* relb = vbb + SBE;                 // 16384 shorts
  size_t off = 3 * SBE / 2 + 8192;                  // floats consumed
  float* context = ws + off;                        // SBE f32 (ybuf aliases)
  unsigned short* ybuf = (unsigned short*)context;
  unsigned short* attn2b = (unsigned short*)(ws + off + SBE);  // SBE bf16
  unsigned short* h1b = attn2b + SBE;               // M*96 bf16
  unsigned short* w1t = h1b + (size_t)M * 96;       // 73728 bf16
  unsigned short* w2t = w1t + 73728;                // 73728 bf16
  float* cgb = (float*)(w2t + 73728);
  float* cbb = cgb + 96;
  unsigned short* probsb = (unsigned short*)(cbb + 96);
  float* outp = (float*)d_out;
  float* avgp = outp + SBE;

  size_t used_f = off + SBE + (SBE + (size_t)M * 96 + 147456) / 2 + 192;
  size_t avail_f = (ws_size / 4 > used_f) ? ws_size / 4 - used_f : 0;
  int Bc = 2;
  const int cand[6] = {64, 32, 16, 8, 4, 2};
  for (int i = 0; i < 6; ++i) {
    size_t need_f = ((size_t)cand[i] * H * S * PST + 1) / 2;
    if (need_f <= avail_f) { Bc = cand[i]; break; }
  }

  mha_wprep<<<641, 256, 0, stream>>>(fc1_w, fc2_w, ln_g, ln_b, fc1_b, rel, w1t,
                                     w2t, cgb, cbb, relb);

  const int CH = 6400;
  for (int mbase = 0; mbase < M; mbase += CH) {
    int rows = (M - mbase < CH) ? (M - mbase) : CH;
    mha_qkv_gemm<<<dim3(rows / 64, 24), 256, 0, stream>>>(query, qkv_w, qkv_b, ybuf,
                                                          mbase, rows);
    mha_qkv_shuffle<<<dim3(rows / 32, 36), 256, 0, stream>>>(ybuf, rel, qb, kbuf,
                                                             vbb, mbase, rows);
  }

  for (int b0 = 0; b0 < B; b0 += Bc) {
    int bc = (B - b0 < Bc) ? (B - b0) : Bc;
    int nbh = bc * H;
    mha_fattn<<<4 * nbh, 256, 0, stream>>>(qb, kbuf, vbb, relb, context, probsb,
                                           b0 * H);
    mha_avgred<<<bc * S, 256, 0, stream>>>(probsb, avgp, b0);
  }

  mha_fc1ln<<<M / 32, 128, 0, stream>>>(context, w1t, cgb, cbb, h1b);
  mha_fc2<<<dim3(M / 64, 4), 256, 0, stream>>>(h1b, w2t, fc2_b, context, attn2b);
  mha_out<<<dim3(M / 64, 8), 256, 0, stream>>>(attn2b, out_w, out_b, outp);
}